// Round 1
// baseline (900.105 us; speedup 1.0000x reference)
//
#include <hip/hip_runtime.h>
#include <math.h>

#define BB 16
#define NTOK 4096
#define DIM 512
#define HID 2048
#define NGE 4
#define NPE 4
#define NFE 2
#define GIN 4096
#define PIN 1024
#define NCLS 4
#define EPS 1e-5f

// ---- workspace layout (float offsets) ----
// zero-initialized accumulator region [0, ZERO_TOT):
#define WS_SUMXN   0            // BB*PIN    = 16384
#define WS_Z       16384        // NPE*BB*PIN= 65536
#define WS_XG      81920        // 8192
#define WS_FG      90112        // 8192
#define WS_FP      98304        // 8192
#define WS_FIMMF   106496       // 8192
#define WS_POOLED  114688       // 32768  (pooled GEMM accum, no path_b)
#define WS_XPMEAN  147456       // 8192   (xp-mean GEMM accum, no path_b)
#define WS_FIN     155648       // 8192   (fused_in GEMM accum, no fin_b)
#define WS_HG      163840       // NGE*BB*HID = 131072 (pre-act accum)
#define WS_HP      294912       // 131072               (contiguous after HG!)
#define WS_HF      425984       // NFE*BB*HID = 65536
#define ZERO_TOT   491520       // 480 blocks x 1024 floats
// scratch (not zeroed):
#define WS_MEAN    491520       // BB*NTOK = 65536
#define WS_RSTD    557056       // 65536
#define WS_S       622592       // NPE*BB*NTOK = 262144
#define WS_QPROJ   884736       // NPE*PIN = 4096
#define WS_GMEAN   888832       // 16
#define WS_GRSTD   888848       // 16
#define WS_WG      888864       // 64
#define WS_WP      888928       // 64
#define WS_WF      888992       // 32
#define WS_UG      889024       // 32768
#define WS_UP      921792       // 32768
#define WS_UF      954560       // 16384
#define WS_TL      970944       // BB*2*DIM = 16384
#define WS_END     987328       // ~3.95 MB

__device__ __forceinline__ float wsum(float v) {
#pragma unroll
    for (int o = 32; o > 0; o >>= 1) v += __shfl_xor(v, o);
    return v;
}
__device__ __forceinline__ float wmax(float v) {
#pragma unroll
    for (int o = 32; o > 0; o >>= 1) v = fmaxf(v, __shfl_xor(v, o));
    return v;
}
__device__ __forceinline__ float gelu_exact(float x) {
    return 0.5f * x * (1.0f + erff(x * 0.70710678118654752f));
}

// ============ K0: zero accumulators | qproj (wave-per-row) | gene row stats ============
__global__ __launch_bounds__(256) void k0_init(const float* __restrict__ F_gene,
                                               const float* __restrict__ path_W,
                                               const float* __restrict__ p_q,
                                               const float* __restrict__ path_ln_g,
                                               float* __restrict__ ws) {
    int blk = blockIdx.x, t = threadIdx.x;
    if (blk < 480) {
        ((float4*)ws)[blk * 256 + t] = make_float4(0.f, 0.f, 0.f, 0.f);
    } else if (blk < 496) {
        // qproj[e,k] = path_ln_g[k] * sum_d path_W[k,d] * p_q[e,d]; wave per row k
        __shared__ __align__(16) float pq[NPE * DIM];
        for (int i = t; i < NPE * DIM; i += 256) pq[i] = p_q[i];
        __syncthreads();
        int w = t >> 6, lane = t & 63;
        const float4* pq4 = (const float4*)pq;  // 128 float4 per expert
        for (int i = 0; i < 16; i++) {
            int k = (blk - 480) * 64 + w * 16 + i;
            const float4* wp4 = (const float4*)(path_W + (size_t)k * DIM);
            float4 x0 = wp4[lane], x1 = wp4[lane + 64];
            float sc[NPE];
#pragma unroll
            for (int e = 0; e < NPE; e++) {
                float4 q0 = pq4[e * 128 + lane], q1 = pq4[e * 128 + lane + 64];
                float d = x0.x * q0.x + x0.y * q0.y + x0.z * q0.z + x0.w * q0.w +
                          x1.x * q1.x + x1.y * q1.y + x1.z * q1.z + x1.w * q1.w;
                sc[e] = wsum(d);
            }
            if (lane == 0) {
                float g = path_ln_g[k];
#pragma unroll
                for (int e = 0; e < NPE; e++) ws[WS_QPROJ + e * PIN + k] = g * sc[e];
            }
        }
    } else {
        // gene row stats (16 rows of 4096)
        int b = blk - 496;
        const float4* row = (const float4*)(F_gene + (size_t)b * GIN);
        float s1 = 0.f, s2 = 0.f;
        for (int i = t; i < GIN / 4; i += 256) {
            float4 v = row[i];
            s1 += v.x + v.y + v.z + v.w;
            s2 += v.x * v.x + v.y * v.y + v.z * v.z + v.w * v.w;
        }
        __shared__ float sc[8];
        s1 = wsum(s1); s2 = wsum(s2);
        int w = t >> 6;
        if ((t & 63) == 0) { sc[w] = s1; sc[4 + w] = s2; }
        __syncthreads();
        if (t == 0) {
            float S1 = sc[0] + sc[1] + sc[2] + sc[3];
            float S2 = sc[4] + sc[5] + sc[6] + sc[7];
            float m = S1 / GIN;
            float var = S2 / GIN - m * m;
            ws[WS_GMEAN + b] = m;
            ws[WS_GRSTD + b] = rsqrtf(var + EPS);
        }
    }
}

// ============ K1: F_path pass1 — LN stats, score dots, sum of xn ============
__global__ __launch_bounds__(256) void k1_pass1(const float* __restrict__ F_path,
                                                float* __restrict__ ws) {
    __shared__ __align__(16) float qlds[NPE * PIN];  // 16 KB
    __shared__ __align__(16) float comb[4 * PIN];    // 16 KB
    int t = threadIdx.x;
    for (int i = t; i < NPE * PIN; i += 256) qlds[i] = ws[WS_QPROJ + i];
    __syncthreads();
    int blk = blockIdx.x;
    int b = blk >> 6, chunk = blk & 63;
    int w = t >> 6, lane = t & 63;
    const float4* qp4 = (const float4*)qlds;
    float4 sxn[4];
#pragma unroll
    for (int j = 0; j < 4; j++) sxn[j] = make_float4(0.f, 0.f, 0.f, 0.f);
    for (int i = 0; i < 16; i++) {
        int n = chunk * 64 + w * 16 + i;
        const float4* rowp = (const float4*)(F_path + ((size_t)(b * NTOK + n)) * PIN);
        float4 x[4];
#pragma unroll
        for (int j = 0; j < 4; j++) x[j] = rowp[lane + 64 * j];
        float s1 = 0.f, s2 = 0.f;
#pragma unroll
        for (int j = 0; j < 4; j++) {
            s1 += x[j].x + x[j].y + x[j].z + x[j].w;
            s2 += x[j].x * x[j].x + x[j].y * x[j].y + x[j].z * x[j].z + x[j].w * x[j].w;
        }
        s1 = wsum(s1); s2 = wsum(s2);
        float m = s1 * (1.f / PIN);
        float var = s2 * (1.f / PIN) - m * m;
        float r = rsqrtf(var + EPS);
        float sc[NPE];
#pragma unroll
        for (int e = 0; e < NPE; e++) {
            float d = 0.f;
#pragma unroll
            for (int j = 0; j < 4; j++) {
                float4 q = qp4[e * (PIN / 4) + lane + 64 * j];
                d += (x[j].x - m) * q.x + (x[j].y - m) * q.y +
                     (x[j].z - m) * q.z + (x[j].w - m) * q.w;
            }
            sc[e] = wsum(d) * r;
        }
#pragma unroll
        for (int j = 0; j < 4; j++) {
            sxn[j].x += (x[j].x - m) * r;
            sxn[j].y += (x[j].y - m) * r;
            sxn[j].z += (x[j].z - m) * r;
            sxn[j].w += (x[j].w - m) * r;
        }
        if (lane == 0) {
            ws[WS_MEAN + b * NTOK + n] = m;
            ws[WS_RSTD + b * NTOK + n] = r;
#pragma unroll
            for (int e = 0; e < NPE; e++) ws[WS_S + (e * BB + b) * NTOK + n] = sc[e];
        }
    }
    float4* comb4 = (float4*)comb;
#pragma unroll
    for (int j = 0; j < 4; j++) comb4[w * (PIN / 4) + lane + 64 * j] = sxn[j];
    __syncthreads();
    {
        float4 a = comb4[t], bq = comb4[256 + t], c = comb4[512 + t], d = comb4[768 + t];
        atomicAdd(ws + WS_SUMXN + b * PIN + 4 * t + 0, a.x + bq.x + c.x + d.x);
        atomicAdd(ws + WS_SUMXN + b * PIN + 4 * t + 1, a.y + bq.y + c.y + d.y);
        atomicAdd(ws + WS_SUMXN + b * PIN + 4 * t + 2, a.z + bq.z + c.z + d.z);
        atomicAdd(ws + WS_SUMXN + b * PIN + 4 * t + 3, a.w + bq.w + c.w + d.w);
    }
}

// ============ K2: softmax over n for each (e,b) ============
__global__ __launch_bounds__(256) void k2_softmax(float* __restrict__ ws) {
    int row = blockIdx.x;
    float* s = ws + WS_S + (size_t)row * NTOK;
    int t = threadIdx.x, w = t >> 6, lane = t & 63;
    __shared__ float sc[4];
    float4 v[4];
    float mx = -1e30f;
#pragma unroll
    for (int j = 0; j < 4; j++) {
        v[j] = ((float4*)s)[t + j * 256];
        mx = fmaxf(mx, fmaxf(fmaxf(v[j].x, v[j].y), fmaxf(v[j].z, v[j].w)));
    }
    mx = wmax(mx);
    if (lane == 0) sc[w] = mx;
    __syncthreads();
    mx = fmaxf(fmaxf(sc[0], sc[1]), fmaxf(sc[2], sc[3]));
    __syncthreads();
    float sum = 0.f;
#pragma unroll
    for (int j = 0; j < 4; j++) {
        v[j].x = __expf(v[j].x - mx); v[j].y = __expf(v[j].y - mx);
        v[j].z = __expf(v[j].z - mx); v[j].w = __expf(v[j].w - mx);
        sum += v[j].x + v[j].y + v[j].z + v[j].w;
    }
    sum = wsum(sum);
    if (lane == 0) sc[w] = sum;
    __syncthreads();
    float inv = 1.f / (sc[0] + sc[1] + sc[2] + sc[3]);
#pragma unroll
    for (int j = 0; j < 4; j++) {
        v[j].x *= inv; v[j].y *= inv; v[j].z *= inv; v[j].w *= inv;
        ((float4*)s)[t + j * 256] = v[j];
    }
}

// ============ K3: F_path pass2 (z = attn-weighted sum of xn) + gene GEMM ============
__global__ __launch_bounds__(256) void k3_pass2(const float* __restrict__ F_path,
                                                const float* __restrict__ F_gene,
                                                const float* __restrict__ gene_W,
                                                const float* __restrict__ gene_ln_g,
                                                const float* __restrict__ gene_ln_b,
                                                float* __restrict__ ws) {
    __shared__ __align__(16) float lds[4096];
    int t = threadIdx.x, blk = blockIdx.x;
    if (blk < 1024) {
        int b = blk >> 6, chunk = blk & 63;
        int w = t >> 6, lane = t & 63;
        float4 zacc[NPE][4];
#pragma unroll
        for (int e = 0; e < NPE; e++)
#pragma unroll
            for (int j = 0; j < 4; j++) zacc[e][j] = make_float4(0.f, 0.f, 0.f, 0.f);
        for (int i = 0; i < 16; i++) {
            int n = chunk * 64 + w * 16 + i;
            const float4* rowp = (const float4*)(F_path + ((size_t)(b * NTOK + n)) * PIN);
            float4 x[4];
#pragma unroll
            for (int j = 0; j < 4; j++) x[j] = rowp[lane + 64 * j];
            float m = ws[WS_MEAN + b * NTOK + n];
            float r = ws[WS_RSTD + b * NTOK + n];
            float ar[NPE];
#pragma unroll
            for (int e = 0; e < NPE; e++) ar[e] = ws[WS_S + (e * BB + b) * NTOK + n] * r;
#pragma unroll
            for (int e = 0; e < NPE; e++) {
#pragma unroll
                for (int j = 0; j < 4; j++) {
                    zacc[e][j].x += ar[e] * (x[j].x - m);
                    zacc[e][j].y += ar[e] * (x[j].y - m);
                    zacc[e][j].z += ar[e] * (x[j].z - m);
                    zacc[e][j].w += ar[e] * (x[j].w - m);
                }
            }
        }
        float4* l4 = (float4*)lds;
#pragma unroll
        for (int e = 0; e < NPE; e++) {
            __syncthreads();
#pragma unroll
            for (int j = 0; j < 4; j++) l4[w * (PIN / 4) + lane + 64 * j] = zacc[e][j];
            __syncthreads();
            float4 a = l4[t], bq = l4[256 + t], c = l4[512 + t], d = l4[768 + t];
            atomicAdd(ws + WS_Z + (e * BB + b) * PIN + 4 * t + 0, a.x + bq.x + c.x + d.x);
            atomicAdd(ws + WS_Z + (e * BB + b) * PIN + 4 * t + 1, a.y + bq.y + c.y + d.y);
            atomicAdd(ws + WS_Z + (e * BB + b) * PIN + 4 * t + 2, a.z + bq.z + c.z + d.z);
            atomicAdd(ws + WS_Z + (e * BB + b) * PIN + 4 * t + 3, a.w + bq.w + c.w + d.w);
        }
    } else {
        // gene projection k-chunk of 256
        int k0 = (blk - 1024) * 256;
        for (int b = 0; b < BB; b++) {
            float x = F_gene[(size_t)b * GIN + k0 + t];
            float m = ws[WS_GMEAN + b], r = ws[WS_GRSTD + b];
            lds[b * 256 + t] = (x - m) * r * gene_ln_g[k0 + t] + gene_ln_b[k0 + t];
        }
        __syncthreads();
        float acc0[BB], acc1[BB];
#pragma unroll
        for (int b = 0; b < BB; b++) { acc0[b] = 0.f; acc1[b] = 0.f; }
        int d0 = t, d1 = t + 256;
#pragma unroll 8
        for (int kk = 0; kk < 256; kk++) {
            float w0 = gene_W[(size_t)(k0 + kk) * DIM + d0];
            float w1 = gene_W[(size_t)(k0 + kk) * DIM + d1];
#pragma unroll
            for (int b = 0; b < BB; b++) {
                float y = lds[b * 256 + kk];
                acc0[b] += y * w0; acc1[b] += y * w1;
            }
        }
#pragma unroll
        for (int b = 0; b < BB; b++) {
            atomicAdd(ws + WS_XG + b * DIM + d0, acc0[b]);
            atomicAdd(ws + WS_XG + b * DIM + d1, acc1[b]);
        }
    }
}

// ============ skinny GEMM: out[M,512] += A[M,1024] @ W[1024,512], k-split ============
// pool=1: A rows from Z/SUMXN with path affine (M=80, grid 80); pool=0: A = tl (M=16, grid 16)
__global__ __launch_bounds__(256) void k_skinny(const float* __restrict__ A,
                                                const float* __restrict__ W,
                                                float* __restrict__ out,
                                                const float* __restrict__ lng,
                                                const float* __restrict__ lnb,
                                                const float* __restrict__ ws,
                                                int pool) {
    __shared__ __align__(16) float a[16 * 64];
    int blk = blockIdx.x, t = threadIdx.x;
    int rg = blk >> 4, kc = blk & 15;
    for (int i = t; i < 1024; i += 256) {
        int r = rg * 16 + (i >> 6);
        int k = kc * 64 + (i & 63);
        float v;
        if (pool) {
            v = (r < 64) ? ws[WS_Z + (size_t)r * PIN + k]
                         : ws[WS_SUMXN + (size_t)(r - 64) * PIN + k] * (1.f / NTOK);
            v = v * lng[k] + lnb[k];
        } else {
            v = A[(size_t)r * PIN + k];
        }
        a[i] = v;
    }
    __syncthreads();
    float2 acc[16];
#pragma unroll
    for (int r = 0; r < 16; r++) acc[r] = make_float2(0.f, 0.f);
    int d2 = 2 * t;
#pragma unroll 4
    for (int k = 0; k < 64; k++) {
        float2 wv = *(const float2*)&W[(size_t)(kc * 64 + k) * DIM + d2];
#pragma unroll
        for (int r = 0; r < 16; r++) {
            float av = a[r * 64 + k];
            acc[r].x += av * wv.x;
            acc[r].y += av * wv.y;
        }
    }
#pragma unroll
    for (int r = 0; r < 16; r++) {
        int rr = rg * 16 + r;
        atomicAdd(out + (size_t)rr * DIM + d2 + 0, acc[r].x);
        atomicAdd(out + (size_t)rr * DIM + d2 + 1, acc[r].y);
    }
}

// ============ K5: row LN + gating + expert-input affine ============
__global__ __launch_bounds__(256) void k5_rows(const float* __restrict__ gene_b,
    const float* __restrict__ path_b,
    const float* __restrict__ gg_ln_g, const float* __restrict__ gg_ln_b,
    const float* __restrict__ gg_W, const float* __restrict__ gg_b,
    const float* __restrict__ pg_ln_g, const float* __restrict__ pg_ln_b,
    const float* __restrict__ pg_W, const float* __restrict__ pg_b,
    const float* __restrict__ g_ln_g, const float* __restrict__ g_ln_b,
    const float* __restrict__ p_ln_g, const float* __restrict__ p_ln_b,
    float* __restrict__ ws) {
    int blk = blockIdx.x, t = threadIdx.x;
    __shared__ float sc[8];
    __shared__ float sc2[16];
    int c0 = t, c1 = t + 256;
    int w = t >> 6, lane = t & 63;
    float v0, v1;
    int type, b = 0, r = 0;
    if (blk < 16) {
        type = 0; b = blk;
        v0 = ws[WS_XG + b * DIM + c0] + gene_b[c0];
        v1 = ws[WS_XG + b * DIM + c1] + gene_b[c1];
    } else if (blk < 32) {
        type = 1; b = blk - 16;
        v0 = ws[WS_XPMEAN + b * DIM + c0] + path_b[c0];
        v1 = ws[WS_XPMEAN + b * DIM + c1] + path_b[c1];
    } else {
        type = 2; r = blk - 32;
        v0 = ws[WS_POOLED + r * DIM + c0] + path_b[c0];
        v1 = ws[WS_POOLED + r * DIM + c1] + path_b[c1];
    }
    float s1 = wsum(v0 + v1), s2 = wsum(v0 * v0 + v1 * v1);
    if (lane == 0) { sc[w] = s1; sc[4 + w] = s2; }
    __syncthreads();
    s1 = sc[0] + sc[1] + sc[2] + sc[3];
    s2 = sc[4] + sc[5] + sc[6] + sc[7];
    float m = s1 / DIM, var = s2 / DIM - m * m, rs = rsqrtf(var + EPS);
    float xn0 = (v0 - m) * rs, xn1 = (v1 - m) * rs;
    if (type == 0) {
#pragma unroll
        for (int e = 0; e < NGE; e++) {
            ws[WS_UG + (e * BB + b) * DIM + c0] = xn0 * g_ln_g[e * DIM + c0] + g_ln_b[e * DIM + c0];
            ws[WS_UG + (e * BB + b) * DIM + c1] = xn1 * g_ln_g[e * DIM + c1] + g_ln_b[e * DIM + c1];
        }
        float t0 = xn0 * gg_ln_g[c0] + gg_ln_b[c0];
        float t1 = xn1 * gg_ln_g[c1] + gg_ln_b[c1];
        float l[4];
#pragma unroll
        for (int e = 0; e < 4; e++) l[e] = wsum(t0 * gg_W[c0 * 4 + e] + t1 * gg_W[c1 * 4 + e]);
        if (lane == 0)
#pragma unroll
            for (int e = 0; e < 4; e++) sc2[w * 4 + e] = l[e];
        __syncthreads();
        if (t == 0) {
            float lg[4], mx = -1e30f;
#pragma unroll
            for (int e = 0; e < 4; e++) {
                lg[e] = sc2[e] + sc2[4 + e] + sc2[8 + e] + sc2[12 + e] + gg_b[e];
                mx = fmaxf(mx, lg[e]);
            }
            float sum = 0.f;
#pragma unroll
            for (int e = 0; e < 4; e++) { lg[e] = __expf(lg[e] - mx); sum += lg[e]; }
#pragma unroll
            for (int e = 0; e < 4; e++) ws[WS_WG + b * NGE + e] = lg[e] / sum;
        }
    } else if (type == 1) {
        float t0 = xn0 * pg_ln_g[c0] + pg_ln_b[c0];
        float t1 = xn1 * pg_ln_g[c1] + pg_ln_b[c1];
        float l[4];
#pragma unroll
        for (int e = 0; e < 4; e++) l[e] = wsum(t0 * pg_W[c0 * 4 + e] + t1 * pg_W[c1 * 4 + e]);
        if (lane == 0)
#pragma unroll
            for (int e = 0; e < 4; e++) sc2[w * 4 + e] = l[e];
        __syncthreads();
        if (t == 0) {
            float lg[4], mx = -1e30f;
#pragma unroll
            for (int e = 0; e < 4; e++) {
                lg[e] = sc2[e] + sc2[4 + e] + sc2[8 + e] + sc2[12 + e] + pg_b[e];
                mx = fmaxf(mx, lg[e]);
            }
            float sum = 0.f;
#pragma unroll
            for (int e = 0; e < 4; e++) { lg[e] = __expf(lg[e] - mx); sum += lg[e]; }
#pragma unroll
            for (int e = 0; e < 4; e++) ws[WS_WP + b * NPE + e] = lg[e] / sum;
        }
    } else {
        int e = r >> 4;
        ws[WS_UP + r * DIM + c0] = xn0 * p_ln_g[e * DIM + c0] + p_ln_b[e * DIM + c0];
        ws[WS_UP + r * DIM + c1] = xn1 * p_ln_g[e * DIM + c1] + p_ln_b[e * DIM + c1];
    }
}

// ============ MLP layer1 pre-act: Hacc[e,b,h] += sum_k U[e,b,k] W1[e,k,h] ============
// per set: e x ht(4, 512h) x kc(8, 64k). thread owns 2 h (float2).
__global__ __launch_bounds__(256) void k_mlp1(const float* __restrict__ U0, const float* __restrict__ W10,
                                              float* __restrict__ H0,
                                              const float* __restrict__ U1, const float* __restrict__ W11,
                                              float* __restrict__ H1,
                                              int halfBlk) {
    __shared__ float a[16 * 64];
    int blk = blockIdx.x, t = threadIdx.x;
    const float* U; const float* W1; float* H;
    int lb;
    if (blk < halfBlk) { U = U0; W1 = W10; H = H0; lb = blk; }
    else               { U = U1; W1 = W11; H = H1; lb = blk - halfBlk; }
    int e = lb >> 5, ht = (lb >> 3) & 3, kc = lb & 7;
    const float* Ue = U + (size_t)e * BB * DIM;
    for (int i = t; i < 1024; i += 256) {
        int b = i >> 6, kk = i & 63;
        a[i] = Ue[b * DIM + kc * 64 + kk];
    }
    __syncthreads();
    float2 acc[BB];
#pragma unroll
    for (int b = 0; b < BB; b++) acc[b] = make_float2(0.f, 0.f);
    int h2 = ht * 512 + 2 * t;
#pragma unroll 4
    for (int kk = 0; kk < 64; kk++) {
        float2 wv = *(const float2*)&W1[((size_t)e * DIM + kc * 64 + kk) * HID + h2];
#pragma unroll
        for (int b = 0; b < BB; b++) {
            float av = a[b * 64 + kk];
            acc[b].x += av * wv.x;
            acc[b].y += av * wv.y;
        }
    }
#pragma unroll
    for (int b = 0; b < BB; b++) {
        atomicAdd(H + (size_t)(e * BB + b) * HID + h2 + 0, acc[b].x);
        atomicAdd(H + (size_t)(e * BB + b) * HID + h2 + 1, acc[b].y);
    }
}

// ============ GELU+bias in place: H = gelu(H + b1) ============
__global__ __launch_bounds__(256) void k_gelu(float* __restrict__ H,
                                              const float* __restrict__ b1a,
                                              const float* __restrict__ b1b,
                                              int eSplit) {
    int idx4 = (blockIdx.x * 256 + threadIdx.x) * 4;
    int e = idx4 >> 15;           // per-e block is 16*2048 = 32768
    int h = idx4 & (HID - 1);
    const float* bp = (e < eSplit) ? (b1a + (size_t)e * HID) : (b1b + (size_t)(e - eSplit) * HID);
    float4 v = *(float4*)&H[idx4];
    float4 bv = *(const float4*)&bp[h];
    v.x = gelu_exact(v.x + bv.x);
    v.y = gelu_exact(v.y + bv.y);
    v.z = gelu_exact(v.z + bv.z);
    v.w = gelu_exact(v.w + bv.w);
    *(float4*)&H[idx4] = v;
}

// ============ MLP layer2 + gate-weighted accumulate (bias b2 folded downstream) ============
// per set: e x kc(16, 128k). thread owns 2 d (float2).
__global__ __launch_bounds__(256) void k_mlp2(const float* __restrict__ H0, const float* __restrict__ W20,
                                              const float* __restrict__ gate0, int ng0, float* __restrict__ out0,
                                              const float* __restrict__ H1, const float* __restrict__ W21,
                                              const float* __restrict__ gate1, int ng1, float* __restrict__ out1,
                                              int halfBlk) {
    __shared__ float a[16 * 128];
    int blk = blockIdx.x, t = threadIdx.x;
    const float* H; const float* W2; const float* gate; float* outp;
    int ng, lb;
    if (blk < halfBlk) { H = H0; W2 = W20; gate = gate0; ng = ng0; outp = out0; lb = blk; }
    else               { H = H1; W2 = W21; gate = gate1; ng = ng1; outp = out1; lb = blk - halfBlk; }
    int e = lb >> 4, kc = lb & 15;
    for (int i = t; i < 2048; i += 256) {
        int b = i >> 7, kk = i & 127;
        a[i] = H[(size_t)(e * BB + b) * HID + kc * 128 + kk];
    }
    __syncthreads();
    float2 acc[BB];
#pragma unroll
    for (int b = 0; b < BB; b++) acc[b] = make_float2(0.f, 0.f);
    int d2 = 2 * t;
#pragma unroll 4
    for (int kk = 0; kk < 128; kk++) {
        float2 wv = *(const float2*)&W2[((size_t)e * HID + kc * 128 + kk) * DIM + d2];
#pragma unroll
        for (int b = 0; b < BB; b++) {
            float av = a[b * 128 + kk];
            acc[b].x += av * wv.x;
            acc[b].y += av * wv.y;
        }
    }
#pragma unroll
    for (int b = 0; b < BB; b++) {
        float g = gate[b * ng + e];
        atomicAdd(outp + (size_t)b * DIM + d2 + 0, g * acc[b].x);
        atomicAdd(outp + (size_t)b * DIM + d2 + 1, g * acc[b].y);
    }
}

// ============ K8a: fused = [FG+bias | FP+bias]; LN; wf gates; tl = affine(fin_ln) ============
__global__ __launch_bounds__(256) void k8a(const float* __restrict__ fg_ln_g, const float* __restrict__ fg_ln_b,
                                           const float* __restrict__ fg_W, const float* __restrict__ fg_b,
                                           const float* __restrict__ fin_ln_g, const float* __restrict__ fin_ln_b,
                                           const float* __restrict__ g_b2, const float* __restrict__ p_b2,
                                           float* __restrict__ ws) {
    __shared__ float sc[8];
    __shared__ float sc2[8];
    int b = blockIdx.x, t = threadIdx.x;
    int w = t >> 6, lane = t & 63;
    float wg[4], wp[4];
#pragma unroll
    for (int e = 0; e < 4; e++) { wg[e] = ws[WS_WG + b * 4 + e]; wp[e] = ws[WS_WP + b * 4 + e]; }
    float v[4];
    v[0] = ws[WS_FG + b * DIM + t]
         + wg[0] * g_b2[t] + wg[1] * g_b2[DIM + t] + wg[2] * g_b2[2 * DIM + t] + wg[3] * g_b2[3 * DIM + t];
    v[1] = ws[WS_FG + b * DIM + t + 256]
         + wg[0] * g_b2[t + 256] + wg[1] * g_b2[DIM + t + 256] + wg[2] * g_b2[2 * DIM + t + 256] + wg[3] * g_b2[3 * DIM + t + 256];
    v[2] = ws[WS_FP + b * DIM + t]
         + wp[0] * p_b2[t] + wp[1] * p_b2[DIM + t] + wp[2] * p_b2[2 * DIM + t] + wp[3] * p_b2[3 * DIM + t];
    v[3] = ws[WS_FP + b * DIM + t + 256]
         + wp[0] * p_b2[t + 256] + wp[1] * p_b2[DIM + t + 256] + wp[2] * p_b2[2 * DIM + t + 256] + wp[3] * p_b2[3 * DIM + t + 256];
    float s1 = wsum(v[0] + v[1] + v[2] + v[3]);
    float s2 = wsum(v[0] * v[0] + v[1] * v[1] + v[2] * v[2] + v[3] * v[3]);
    if (lane == 0) { sc[w] = s1; sc[4 + w] = s2; }
    __syncthreads();
    s1 = sc[0] + sc[1] + sc[2] + sc[3];
    s2 = sc[4] + sc[5] + sc[6] + sc[7];
    float m = s1 / (2 * DIM), var = s2 / (2 * DIM) - m * m, rs = rsqrtf(var + EPS);
    float l0 = 0.f, l1 = 0.f;
    int cols[4] = {t, t + 256, t + 512, t + 768};
#pragma unroll
    for (int j = 0; j < 4; j++) {
        int c = cols[j];
        float xn = (v[j] - m) * rs;
        float tf = xn * fg_ln_g[c] + fg_ln_b[c];
        l0 += tf * fg_W[c * 2 + 0];
        l1 += tf * fg_W[c * 2 + 1];
        ws[WS_TL + b * 1024 + c] = xn * fin_ln_g[c] + fin_ln_b[c];
    }
    l0 = wsum(l0); l1 = wsum(l1);
    if (lane == 0) { sc2[w] = l0; sc2[4 + w] = l1; }
    __syncthreads();
    if (t == 0) {
        float L0 = sc2[0] + sc2[1] + sc2[2] + sc2[3] + fg_b[0];
        float L1 = sc2[4] + sc2[5] + sc2[6] + sc2[7] + fg_b[1];
        float mx = fmaxf(L0, L1);
        float p0 = __expf(L0 - mx), p1 = __expf(L1 - mx);
        float inv = 1.f / (p0 + p1);
        ws[WS_WF + b * NFE + 0] = p0 * inv;
        ws[WS_WF + b * NFE + 1] = p1 * inv;
    }
}

// ============ K8b: LN(FIN + fin_b) -> UF (f-expert affine) ============
__global__ __launch_bounds__(256) void k8b(const float* __restrict__ fin_b,
                                           const float* __restrict__ f_ln_g, const float* __restrict__ f_ln_b,
                                           float* __restrict__ ws) {
    __shared__ float sc[8];
    int b = blockIdx.x, t = threadIdx.x;
    int w = t >> 6, lane = t & 63;
    int c0 = t, c1 = t + 256;
    float a0 = ws[WS_FIN + b * DIM + c0] + fin_b[c0];
    float a1 = ws[WS_FIN + b * DIM + c1] + fin_b[c1];
    float s1 = wsum(a0 + a1), s2 = wsum(a0 * a0 + a1 * a1);
    if (lane == 0) { sc[w] = s1; sc[4 + w] = s2; }
    __syncthreads();
    s1 = sc[0] + sc[1] + sc[2] + sc[3];
    s2 = sc[4] + sc[5] + sc[6] + sc[7];
    float m = s1 / DIM, var = s2 / DIM - m * m, rs = rsqrtf(var + EPS);
    float x0 = (a0 - m) * rs, x1 = (a1 - m) * rs;
#pragma unroll
    for (int e = 0; e < NFE; e++) {
        ws[WS_UF + (e * BB + b) * DIM + c0] = x0 * f_ln_g[e * DIM + c0] + f_ln_b[e * DIM + c0];
        ws[WS_UF + (e * BB + b) * DIM + c1] = x1 * f_ln_g[e * DIM + c1] + f_ln_b[e * DIM + c1];
    }
}

// ============ K11: classifier (+gate-weighted f_b2 bias) + sigmoid + cumprod ============
__global__ __launch_bounds__(256) void k11_out(const float* __restrict__ cls_W, const float* __restrict__ cls_b,
                                               const float* __restrict__ f_b2,
                                               const float* __restrict__ ws, float* __restrict__ out) {
    __shared__ float4 red[256];
    __shared__ float hz[64];
    int t = threadIdx.x;
    int b = t >> 4, g = t & 15;
    float wf0 = ws[WS_WF + b * 2 + 0], wf1 = ws[WS_WF + b * 2 + 1];
    float4 acc = make_float4(0.f, 0.f, 0.f, 0.f);
#pragma unroll 8
    for (int k = g; k < DIM; k += 16) {
        float x = ws[WS_FIMMF + b * DIM + k] + wf0 * f_b2[k] + wf1 * f_b2[DIM + k];
        float4 wv = *(const float4*)&cls_W[k * 4];
        acc.x += x * wv.x; acc.y += x * wv.y; acc.z += x * wv.z; acc.w += x * wv.w;
    }
    red[t] = acc;
    __syncthreads();
    if (t < 64) {
        int bb = t >> 2, c = t & 3;
        float s = cls_b[c];
#pragma unroll
        for (int j = 0; j < 16; j++) s += ((const float*)&red[bb * 16 + j])[c];
        hz[t] = 1.f / (1.f + __expf(-s));
    }
    __syncthreads();
    if (t < 64) {
        int bb = t >> 2, c = t & 3;
        float S = 1.f;
        for (int j = 0; j <= c; j++) S *= (1.f - hz[bb * 4 + j]);
        out[t] = hz[t];
        out[64 + t] = S;
    }
}

extern "C" void kernel_launch(void* const* d_in, const int* in_sizes, int n_in,
                              void* d_out, int out_size, void* d_ws, size_t ws_size,
                              hipStream_t stream) {
    (void)in_sizes; (void)n_in; (void)out_size; (void)ws_size;
    const float* F_gene    = (const float*)d_in[0];
    const float* F_path    = (const float*)d_in[1];
    const float* gene_ln_g = (const float*)d_in[2];
    const float* gene_ln_b = (const float*)d_in[3];
    const float* gene_W    = (const float*)d_in[4];
    const float* gene_b    = (const float*)d_in[5];
    const float* path_ln_g = (const float*)d_in[6];
    const float* path_ln_b = (const float*)d_in[7];
    const float* path_W    = (const float*)d_in[8];
    const float* path_b    = (const float*)d_in[9];
    const float* g_ln_g    = (const float*)d_in[10];
    const float* g_ln_b    = (const float*)d_in[11];
    const float* g_W1      = (const float*)d_in[12];
    const float* g_b1      = (const float*)d_in[13];
    const float* g_W2      = (const float*)d_in[14];
    const float* g_b2      = (const float*)d_in[15];
    const float* p_q       = (const float*)d_in[16];
    const float* p_ln_g    = (const float*)d_in[17];
    const float* p_ln_b    = (const float*)d_in[18];
    const float* p_W1      = (const float*)d_in[19];
    const float* p_b1      = (const float*)d_in[20];
    const float* p_W2      = (const float*)d_in[21];
    const float* p_b2      = (const float*)d_in[22];
    const float* f_ln_g    = (const float*)d_in[23];
    const float* f_ln_b    = (const float*)d_in[24];
    const float* f_W1      = (const float*)d_in[25];
    const float* f_b1      = (const float*)d_in[26];
    const float* f_W2      = (const float*)d_in[27];
    const float* f_b2      = (const float*)d_in[28];
    const float* gg_ln_g   = (const float*)d_in[29];
    const float* gg_ln_b   = (const float*)d_in[30];
    const float* gg_W      = (const float*)d_in[31];
    const float* gg_b      = (const float*)d_in[32];
    const float* pg_ln_g   = (const float*)d_in[33];
    const float* pg_ln_b   = (const float*)d_in[34];
    const float* pg_W      = (const float*)d_in[35];
    const float* pg_b      = (const float*)d_in[36];
    const float* fg_ln_g   = (const float*)d_in[37];
    const float* fg_ln_b   = (const float*)d_in[38];
    const float* fg_W      = (const float*)d_in[39];
    const float* fg_b      = (const float*)d_in[40];
    const float* fin_ln_g  = (const float*)d_in[41];
    const float* fin_ln_b  = (const float*)d_in[42];
    const float* fin_W     = (const float*)d_in[43];
    const float* fin_b     = (const float*)d_in[44];
    const float* cls_W     = (const float*)d_in[45];
    const float* cls_b     = (const float*)d_in[46];
    float* ws  = (float*)d_ws;
    float* out = (float*)d_out;

    k0_init<<<512, 256, 0, stream>>>(F_gene, path_W, p_q, path_ln_g, ws);
    k1_pass1<<<1024, 256, 0, stream>>>(F_path, ws);
    k2_softmax<<<64, 256, 0, stream>>>(ws);
    k3_pass2<<<1040, 256, 0, stream>>>(F_path, F_gene, gene_W, gene_ln_g, gene_ln_b, ws);
    k_skinny<<<80, 256, 0, stream>>>(nullptr, path_W, ws + WS_POOLED, path_ln_g, path_ln_b, ws, 1);
    k5_rows<<<96, 256, 0, stream>>>(gene_b, path_b, gg_ln_g, gg_ln_b, gg_W, gg_b,
                                    pg_ln_g, pg_ln_b, pg_W, pg_b,
                                    g_ln_g, g_ln_b, p_ln_g, p_ln_b, ws);
    k_mlp1<<<256, 256, 0, stream>>>(ws + WS_UG, g_W1, ws + WS_HG,
                                    ws + WS_UP, p_W1, ws + WS_HP, 128);
    k_gelu<<<256, 256, 0, stream>>>(ws + WS_HG, g_b1, p_b1, 4);
    k_mlp2<<<128, 256, 0, stream>>>(ws + WS_HG, g_W2, ws + WS_WG, NGE, ws + WS_FG,
                                    ws + WS_HP, p_W2, ws + WS_WP, NPE, ws + WS_FP, 64);
    k8a<<<16, 256, 0, stream>>>(fg_ln_g, fg_ln_b, fg_W, fg_b, fin_ln_g, fin_ln_b, g_b2, p_b2, ws);
    k_skinny<<<16, 256, 0, stream>>>(ws + WS_TL, fin_W, ws + WS_FIN, nullptr, nullptr, ws, 0);
    k8b<<<16, 256, 0, stream>>>(fin_b, f_ln_g, f_ln_b, ws);
    k_mlp1<<<64, 256, 0, stream>>>(ws + WS_UF, f_W1, ws + WS_HF,
                                   ws + WS_UF, f_W1, ws + WS_HF, 64);
    k_gelu<<<64, 256, 0, stream>>>(ws + WS_HF, f_b1, f_b1, 2);
    k_mlp2<<<32, 256, 0, stream>>>(ws + WS_HF, f_W2, ws + WS_WF, NFE, ws + WS_FIMMF,
                                   ws + WS_HF, f_W2, ws + WS_WF, NFE, ws + WS_FIMMF, 32);
    k11_out<<<1, 256, 0, stream>>>(cls_W, cls_b, f_b2, ws, out);
}

// Round 2
// 898.773 us; speedup vs baseline: 1.0015x; 1.0015x over previous
//
#include <hip/hip_runtime.h>
#include <math.h>

#define BB 16
#define NTOK 4096
#define DIM 512
#define HID 2048
#define NGE 4
#define NPE 4
#define NFE 2
#define GIN 4096
#define PIN 1024
#define NCLS 4
#define EPS 1e-5f

// ---- workspace layout (float offsets) ----
// zero-initialized accumulator region [0, ZERO_TOT):
#define WS_SUMXN   0            // BB*PIN    = 16384
#define WS_Z       16384        // NPE*BB*PIN= 65536
#define WS_XG      81920        // 8192
#define WS_FG      90112        // 8192
#define WS_FP      98304        // 8192
#define WS_FIMMF   106496       // 8192
#define WS_POOLED  114688       // 32768  (pooled GEMM accum, no path_b)
#define WS_XPMEAN  147456       // 8192   (xp-mean GEMM accum, no path_b)
#define WS_FIN     155648       // 8192   (fused_in GEMM accum, no fin_b)
#define WS_HG      163840       // NGE*BB*HID = 131072 (pre-act accum)
#define WS_HP      294912       // 131072               (contiguous after HG!)
#define WS_HF      425984       // NFE*BB*HID = 65536
#define ZERO_TOT   491520       // 480 blocks x 1024 floats
// scratch (not zeroed):
#define WS_MEAN    491520       // BB*NTOK = 65536
#define WS_RSTD    557056       // 65536
#define WS_S       622592       // NPE*BB*NTOK = 262144
#define WS_QPROJ   884736       // NPE*PIN = 4096
#define WS_GMEAN   888832       // 16
#define WS_GRSTD   888848       // 16
#define WS_WG      888864       // 64
#define WS_WP      888928       // 64
#define WS_WF      888992       // 32
#define WS_UG      889024       // 32768
#define WS_UP      921792       // 32768
#define WS_UF      954560       // 16384
#define WS_TL      970944       // BB*2*DIM = 16384
#define WS_END     987328       // ~3.95 MB

__device__ __forceinline__ float wsum(float v) {
#pragma unroll
    for (int o = 32; o > 0; o >>= 1) v += __shfl_xor(v, o);
    return v;
}
__device__ __forceinline__ float wmax(float v) {
#pragma unroll
    for (int o = 32; o > 0; o >>= 1) v = fmaxf(v, __shfl_xor(v, o));
    return v;
}
__device__ __forceinline__ float gelu_exact(float x) {
    return 0.5f * x * (1.0f + erff(x * 0.70710678118654752f));
}

// ============ K0: zero accumulators | qproj (wave-per-row) | gene row stats ============
__global__ __launch_bounds__(256) void k0_init(const float* __restrict__ F_gene,
                                               const float* __restrict__ path_W,
                                               const float* __restrict__ p_q,
                                               const float* __restrict__ path_ln_g,
                                               float* __restrict__ ws) {
    int blk = blockIdx.x, t = threadIdx.x;
    if (blk < 480) {
        ((float4*)ws)[blk * 256 + t] = make_float4(0.f, 0.f, 0.f, 0.f);
    } else if (blk < 496) {
        // qproj[e,k] = path_ln_g[k] * sum_d path_W[k,d] * p_q[e,d]; wave per row k
        __shared__ __align__(16) float pq[NPE * DIM];
        for (int i = t; i < NPE * DIM; i += 256) pq[i] = p_q[i];
        __syncthreads();
        int w = t >> 6, lane = t & 63;
        const float4* pq4 = (const float4*)pq;  // 128 float4 per expert
        for (int i = 0; i < 16; i++) {
            int k = (blk - 480) * 64 + w * 16 + i;
            const float4* wp4 = (const float4*)(path_W + (size_t)k * DIM);
            float4 x0 = wp4[lane], x1 = wp4[lane + 64];
            float sc[NPE];
#pragma unroll
            for (int e = 0; e < NPE; e++) {
                float4 q0 = pq4[e * 128 + lane], q1 = pq4[e * 128 + lane + 64];
                float d = x0.x * q0.x + x0.y * q0.y + x0.z * q0.z + x0.w * q0.w +
                          x1.x * q1.x + x1.y * q1.y + x1.z * q1.z + x1.w * q1.w;
                sc[e] = wsum(d);
            }
            if (lane == 0) {
                float g = path_ln_g[k];
#pragma unroll
                for (int e = 0; e < NPE; e++) ws[WS_QPROJ + e * PIN + k] = g * sc[e];
            }
        }
    } else {
        // gene row stats (16 rows of 4096)
        int b = blk - 496;
        const float4* row = (const float4*)(F_gene + (size_t)b * GIN);
        float s1 = 0.f, s2 = 0.f;
        for (int i = t; i < GIN / 4; i += 256) {
            float4 v = row[i];
            s1 += v.x + v.y + v.z + v.w;
            s2 += v.x * v.x + v.y * v.y + v.z * v.z + v.w * v.w;
        }
        __shared__ float sc[8];
        s1 = wsum(s1); s2 = wsum(s2);
        int w = t >> 6;
        if ((t & 63) == 0) { sc[w] = s1; sc[4 + w] = s2; }
        __syncthreads();
        if (t == 0) {
            float S1 = sc[0] + sc[1] + sc[2] + sc[3];
            float S2 = sc[4] + sc[5] + sc[6] + sc[7];
            float m = S1 / GIN;
            float var = S2 / GIN - m * m;
            ws[WS_GMEAN + b] = m;
            ws[WS_GRSTD + b] = rsqrtf(var + EPS);
        }
    }
}

// ============ K1: F_path pass1 — LN stats, score dots, sum of xn ============
__global__ __launch_bounds__(256) void k1_pass1(const float* __restrict__ F_path,
                                                float* __restrict__ ws) {
    __shared__ __align__(16) float qlds[NPE * PIN];  // 16 KB
    __shared__ __align__(16) float comb[4 * PIN];    // 16 KB
    int t = threadIdx.x;
    for (int i = t; i < NPE * PIN; i += 256) qlds[i] = ws[WS_QPROJ + i];
    __syncthreads();
    int blk = blockIdx.x;
    int b = blk >> 6, chunk = blk & 63;
    int w = t >> 6, lane = t & 63;
    const float4* qp4 = (const float4*)qlds;
    float4 sxn[4];
#pragma unroll
    for (int j = 0; j < 4; j++) sxn[j] = make_float4(0.f, 0.f, 0.f, 0.f);
    for (int i = 0; i < 16; i++) {
        int n = chunk * 64 + w * 16 + i;
        const float4* rowp = (const float4*)(F_path + ((size_t)(b * NTOK + n)) * PIN);
        float4 x[4];
#pragma unroll
        for (int j = 0; j < 4; j++) x[j] = rowp[lane + 64 * j];
        float s1 = 0.f, s2 = 0.f;
#pragma unroll
        for (int j = 0; j < 4; j++) {
            s1 += x[j].x + x[j].y + x[j].z + x[j].w;
            s2 += x[j].x * x[j].x + x[j].y * x[j].y + x[j].z * x[j].z + x[j].w * x[j].w;
        }
        s1 = wsum(s1); s2 = wsum(s2);
        float m = s1 * (1.f / PIN);
        float var = s2 * (1.f / PIN) - m * m;
        float r = rsqrtf(var + EPS);
        float sc[NPE];
#pragma unroll
        for (int e = 0; e < NPE; e++) {
            float d = 0.f;
#pragma unroll
            for (int j = 0; j < 4; j++) {
                float4 q = qp4[e * (PIN / 4) + lane + 64 * j];
                d += (x[j].x - m) * q.x + (x[j].y - m) * q.y +
                     (x[j].z - m) * q.z + (x[j].w - m) * q.w;
            }
            sc[e] = wsum(d) * r;
        }
#pragma unroll
        for (int j = 0; j < 4; j++) {
            sxn[j].x += (x[j].x - m) * r;
            sxn[j].y += (x[j].y - m) * r;
            sxn[j].z += (x[j].z - m) * r;
            sxn[j].w += (x[j].w - m) * r;
        }
        if (lane == 0) {
            ws[WS_MEAN + b * NTOK + n] = m;
            ws[WS_RSTD + b * NTOK + n] = r;
#pragma unroll
            for (int e = 0; e < NPE; e++) ws[WS_S + (e * BB + b) * NTOK + n] = sc[e];
        }
    }
    float4* comb4 = (float4*)comb;
#pragma unroll
    for (int j = 0; j < 4; j++) comb4[w * (PIN / 4) + lane + 64 * j] = sxn[j];
    __syncthreads();
    {
        float4 a = comb4[t], bq = comb4[256 + t], c = comb4[512 + t], d = comb4[768 + t];
        atomicAdd(ws + WS_SUMXN + b * PIN + 4 * t + 0, a.x + bq.x + c.x + d.x);
        atomicAdd(ws + WS_SUMXN + b * PIN + 4 * t + 1, a.y + bq.y + c.y + d.y);
        atomicAdd(ws + WS_SUMXN + b * PIN + 4 * t + 2, a.z + bq.z + c.z + d.z);
        atomicAdd(ws + WS_SUMXN + b * PIN + 4 * t + 3, a.w + bq.w + c.w + d.w);
    }
}

// ============ K2: softmax over n for each (e,b) ============
__global__ __launch_bounds__(256) void k2_softmax(float* __restrict__ ws) {
    int row = blockIdx.x;
    float* s = ws + WS_S + (size_t)row * NTOK;
    int t = threadIdx.x, w = t >> 6, lane = t & 63;
    __shared__ float sc[4];
    float4 v[4];
    float mx = -1e30f;
#pragma unroll
    for (int j = 0; j < 4; j++) {
        v[j] = ((float4*)s)[t + j * 256];
        mx = fmaxf(mx, fmaxf(fmaxf(v[j].x, v[j].y), fmaxf(v[j].z, v[j].w)));
    }
    mx = wmax(mx);
    if (lane == 0) sc[w] = mx;
    __syncthreads();
    mx = fmaxf(fmaxf(sc[0], sc[1]), fmaxf(sc[2], sc[3]));
    __syncthreads();
    float sum = 0.f;
#pragma unroll
    for (int j = 0; j < 4; j++) {
        v[j].x = __expf(v[j].x - mx); v[j].y = __expf(v[j].y - mx);
        v[j].z = __expf(v[j].z - mx); v[j].w = __expf(v[j].w - mx);
        sum += v[j].x + v[j].y + v[j].z + v[j].w;
    }
    sum = wsum(sum);
    if (lane == 0) sc[w] = sum;
    __syncthreads();
    float inv = 1.f / (sc[0] + sc[1] + sc[2] + sc[3]);
#pragma unroll
    for (int j = 0; j < 4; j++) {
        v[j].x *= inv; v[j].y *= inv; v[j].z *= inv; v[j].w *= inv;
        ((float4*)s)[t + j * 256] = v[j];
    }
}

// ============ K3: F_path pass2 (z = attn-weighted sum of xn) + gene GEMM ============
// Epilogue is HAND-UNROLLED via macro (literal expert index) because the loop
// unroller refuses loops containing __syncthreads(); runtime-indexed zacc was
// being demoted to scratch (VGPR=56, 217us). Four separately-named arrays with
// all-static indices guarantee register allocation.
#define K3_EPI(ZZ, e) do {                                                        \
    __syncthreads();                                                              \
    l4[w * (PIN / 4) + lane +   0] = ZZ[0];                                       \
    l4[w * (PIN / 4) + lane +  64] = ZZ[1];                                       \
    l4[w * (PIN / 4) + lane + 128] = ZZ[2];                                       \
    l4[w * (PIN / 4) + lane + 192] = ZZ[3];                                       \
    __syncthreads();                                                              \
    float4 ea = l4[t], eb = l4[256 + t], ec = l4[512 + t], ed = l4[768 + t];      \
    atomicAdd(ws + WS_Z + ((e) * BB + b) * PIN + 4 * t + 0, ea.x + eb.x + ec.x + ed.x); \
    atomicAdd(ws + WS_Z + ((e) * BB + b) * PIN + 4 * t + 1, ea.y + eb.y + ec.y + ed.y); \
    atomicAdd(ws + WS_Z + ((e) * BB + b) * PIN + 4 * t + 2, ea.z + eb.z + ec.z + ed.z); \
    atomicAdd(ws + WS_Z + ((e) * BB + b) * PIN + 4 * t + 3, ea.w + eb.w + ec.w + ed.w); \
} while (0)

__global__ __launch_bounds__(256) void k3_pass2(const float* __restrict__ F_path,
                                                const float* __restrict__ F_gene,
                                                const float* __restrict__ gene_W,
                                                const float* __restrict__ gene_ln_g,
                                                const float* __restrict__ gene_ln_b,
                                                float* __restrict__ ws) {
    __shared__ __align__(16) float lds[4096];
    int t = threadIdx.x, blk = blockIdx.x;
    if (blk < 1024) {
        int b = blk >> 6, chunk = blk & 63;
        int w = t >> 6, lane = t & 63;
        float4 z0[4], z1[4], z2[4], z3[4];
#pragma unroll
        for (int j = 0; j < 4; j++) {
            z0[j] = make_float4(0.f, 0.f, 0.f, 0.f);
            z1[j] = make_float4(0.f, 0.f, 0.f, 0.f);
            z2[j] = make_float4(0.f, 0.f, 0.f, 0.f);
            z3[j] = make_float4(0.f, 0.f, 0.f, 0.f);
        }
        for (int i = 0; i < 16; i++) {
            int n = chunk * 64 + w * 16 + i;
            const float4* rowp = (const float4*)(F_path + ((size_t)(b * NTOK + n)) * PIN);
            float4 x[4];
#pragma unroll
            for (int j = 0; j < 4; j++) x[j] = rowp[lane + 64 * j];
            float m = ws[WS_MEAN + b * NTOK + n];
            float r = ws[WS_RSTD + b * NTOK + n];
            float ar0 = ws[WS_S + (0 * BB + b) * NTOK + n] * r;
            float ar1 = ws[WS_S + (1 * BB + b) * NTOK + n] * r;
            float ar2 = ws[WS_S + (2 * BB + b) * NTOK + n] * r;
            float ar3 = ws[WS_S + (3 * BB + b) * NTOK + n] * r;
#pragma unroll
            for (int j = 0; j < 4; j++) {
                float dx = x[j].x - m, dy = x[j].y - m, dz = x[j].z - m, dw = x[j].w - m;
                z0[j].x += ar0 * dx; z0[j].y += ar0 * dy; z0[j].z += ar0 * dz; z0[j].w += ar0 * dw;
                z1[j].x += ar1 * dx; z1[j].y += ar1 * dy; z1[j].z += ar1 * dz; z1[j].w += ar1 * dw;
                z2[j].x += ar2 * dx; z2[j].y += ar2 * dy; z2[j].z += ar2 * dz; z2[j].w += ar2 * dw;
                z3[j].x += ar3 * dx; z3[j].y += ar3 * dy; z3[j].z += ar3 * dz; z3[j].w += ar3 * dw;
            }
        }
        float4* l4 = (float4*)lds;
        K3_EPI(z0, 0);
        K3_EPI(z1, 1);
        K3_EPI(z2, 2);
        K3_EPI(z3, 3);
    } else {
        // gene projection k-chunk of 256
        int k0 = (blk - 1024) * 256;
        for (int b = 0; b < BB; b++) {
            float x = F_gene[(size_t)b * GIN + k0 + t];
            float m = ws[WS_GMEAN + b], r = ws[WS_GRSTD + b];
            lds[b * 256 + t] = (x - m) * r * gene_ln_g[k0 + t] + gene_ln_b[k0 + t];
        }
        __syncthreads();
        float acc0[BB], acc1[BB];
#pragma unroll
        for (int b = 0; b < BB; b++) { acc0[b] = 0.f; acc1[b] = 0.f; }
        int d0 = t, d1 = t + 256;
#pragma unroll 8
        for (int kk = 0; kk < 256; kk++) {
            float w0 = gene_W[(size_t)(k0 + kk) * DIM + d0];
            float w1 = gene_W[(size_t)(k0 + kk) * DIM + d1];
#pragma unroll
            for (int b = 0; b < BB; b++) {
                float y = lds[b * 256 + kk];
                acc0[b] += y * w0; acc1[b] += y * w1;
            }
        }
#pragma unroll
        for (int b = 0; b < BB; b++) {
            atomicAdd(ws + WS_XG + b * DIM + d0, acc0[b]);
            atomicAdd(ws + WS_XG + b * DIM + d1, acc1[b]);
        }
    }
}

// ============ skinny GEMM: out[M,512] += A[M,1024] @ W[1024,512], k-split ============
// pool=1: A rows from Z/SUMXN with path affine (M=80, grid 80); pool=0: A = tl (M=16, grid 16)
__global__ __launch_bounds__(256) void k_skinny(const float* __restrict__ A,
                                                const float* __restrict__ W,
                                                float* __restrict__ out,
                                                const float* __restrict__ lng,
                                                const float* __restrict__ lnb,
                                                const float* __restrict__ ws,
                                                int pool) {
    __shared__ __align__(16) float a[16 * 64];
    int blk = blockIdx.x, t = threadIdx.x;
    int rg = blk >> 4, kc = blk & 15;
    for (int i = t; i < 1024; i += 256) {
        int r = rg * 16 + (i >> 6);
        int k = kc * 64 + (i & 63);
        float v;
        if (pool) {
            v = (r < 64) ? ws[WS_Z + (size_t)r * PIN + k]
                         : ws[WS_SUMXN + (size_t)(r - 64) * PIN + k] * (1.f / NTOK);
            v = v * lng[k] + lnb[k];
        } else {
            v = A[(size_t)r * PIN + k];
        }
        a[i] = v;
    }
    __syncthreads();
    float2 acc[16];
#pragma unroll
    for (int r = 0; r < 16; r++) acc[r] = make_float2(0.f, 0.f);
    int d2 = 2 * t;
#pragma unroll 4
    for (int k = 0; k < 64; k++) {
        float2 wv = *(const float2*)&W[(size_t)(kc * 64 + k) * DIM + d2];
#pragma unroll
        for (int r = 0; r < 16; r++) {
            float av = a[r * 64 + k];
            acc[r].x += av * wv.x;
            acc[r].y += av * wv.y;
        }
    }
#pragma unroll
    for (int r = 0; r < 16; r++) {
        int rr = rg * 16 + r;
        atomicAdd(out + (size_t)rr * DIM + d2 + 0, acc[r].x);
        atomicAdd(out + (size_t)rr * DIM + d2 + 1, acc[r].y);
    }
}

// ============ K5: row LN + gating + expert-input affine ============
__global__ __launch_bounds__(256) void k5_rows(const float* __restrict__ gene_b,
    const float* __restrict__ path_b,
    const float* __restrict__ gg_ln_g, const float* __restrict__ gg_ln_b,
    const float* __restrict__ gg_W, const float* __restrict__ gg_b,
    const float* __restrict__ pg_ln_g, const float* __restrict__ pg_ln_b,
    const float* __restrict__ pg_W, const float* __restrict__ pg_b,
    const float* __restrict__ g_ln_g, const float* __restrict__ g_ln_b,
    const float* __restrict__ p_ln_g, const float* __restrict__ p_ln_b,
    float* __restrict__ ws) {
    int blk = blockIdx.x, t = threadIdx.x;
    __shared__ float sc[8];
    __shared__ float sc2[16];
    int c0 = t, c1 = t + 256;
    int w = t >> 6, lane = t & 63;
    float v0, v1;
    int type, b = 0, r = 0;
    if (blk < 16) {
        type = 0; b = blk;
        v0 = ws[WS_XG + b * DIM + c0] + gene_b[c0];
        v1 = ws[WS_XG + b * DIM + c1] + gene_b[c1];
    } else if (blk < 32) {
        type = 1; b = blk - 16;
        v0 = ws[WS_XPMEAN + b * DIM + c0] + path_b[c0];
        v1 = ws[WS_XPMEAN + b * DIM + c1] + path_b[c1];
    } else {
        type = 2; r = blk - 32;
        v0 = ws[WS_POOLED + r * DIM + c0] + path_b[c0];
        v1 = ws[WS_POOLED + r * DIM + c1] + path_b[c1];
    }
    float s1 = wsum(v0 + v1), s2 = wsum(v0 * v0 + v1 * v1);
    if (lane == 0) { sc[w] = s1; sc[4 + w] = s2; }
    __syncthreads();
    s1 = sc[0] + sc[1] + sc[2] + sc[3];
    s2 = sc[4] + sc[5] + sc[6] + sc[7];
    float m = s1 / DIM, var = s2 / DIM - m * m, rs = rsqrtf(var + EPS);
    float xn0 = (v0 - m) * rs, xn1 = (v1 - m) * rs;
    if (type == 0) {
#pragma unroll
        for (int e = 0; e < NGE; e++) {
            ws[WS_UG + (e * BB + b) * DIM + c0] = xn0 * g_ln_g[e * DIM + c0] + g_ln_b[e * DIM + c0];
            ws[WS_UG + (e * BB + b) * DIM + c1] = xn1 * g_ln_g[e * DIM + c1] + g_ln_b[e * DIM + c1];
        }
        float t0 = xn0 * gg_ln_g[c0] + gg_ln_b[c0];
        float t1 = xn1 * gg_ln_g[c1] + gg_ln_b[c1];
        float l[4];
#pragma unroll
        for (int e = 0; e < 4; e++) l[e] = wsum(t0 * gg_W[c0 * 4 + e] + t1 * gg_W[c1 * 4 + e]);
        if (lane == 0)
#pragma unroll
            for (int e = 0; e < 4; e++) sc2[w * 4 + e] = l[e];
        __syncthreads();
        if (t == 0) {
            float lg[4], mx = -1e30f;
#pragma unroll
            for (int e = 0; e < 4; e++) {
                lg[e] = sc2[e] + sc2[4 + e] + sc2[8 + e] + sc2[12 + e] + gg_b[e];
                mx = fmaxf(mx, lg[e]);
            }
            float sum = 0.f;
#pragma unroll
            for (int e = 0; e < 4; e++) { lg[e] = __expf(lg[e] - mx); sum += lg[e]; }
#pragma unroll
            for (int e = 0; e < 4; e++) ws[WS_WG + b * NGE + e] = lg[e] / sum;
        }
    } else if (type == 1) {
        float t0 = xn0 * pg_ln_g[c0] + pg_ln_b[c0];
        float t1 = xn1 * pg_ln_g[c1] + pg_ln_b[c1];
        float l[4];
#pragma unroll
        for (int e = 0; e < 4; e++) l[e] = wsum(t0 * pg_W[c0 * 4 + e] + t1 * pg_W[c1 * 4 + e]);
        if (lane == 0)
#pragma unroll
            for (int e = 0; e < 4; e++) sc2[w * 4 + e] = l[e];
        __syncthreads();
        if (t == 0) {
            float lg[4], mx = -1e30f;
#pragma unroll
            for (int e = 0; e < 4; e++) {
                lg[e] = sc2[e] + sc2[4 + e] + sc2[8 + e] + sc2[12 + e] + pg_b[e];
                mx = fmaxf(mx, lg[e]);
            }
            float sum = 0.f;
#pragma unroll
            for (int e = 0; e < 4; e++) { lg[e] = __expf(lg[e] - mx); sum += lg[e]; }
#pragma unroll
            for (int e = 0; e < 4; e++) ws[WS_WP + b * NPE + e] = lg[e] / sum;
        }
    } else {
        int e = r >> 4;
        ws[WS_UP + r * DIM + c0] = xn0 * p_ln_g[e * DIM + c0] + p_ln_b[e * DIM + c0];
        ws[WS_UP + r * DIM + c1] = xn1 * p_ln_g[e * DIM + c1] + p_ln_b[e * DIM + c1];
    }
}

// ============ MLP layer1 pre-act: Hacc[e,b,h] += sum_k U[e,b,k] W1[e,k,h] ============
// per set: e x ht(4, 512h) x kc(8, 64k). thread owns 2 h (float2).
__global__ __launch_bounds__(256) void k_mlp1(const float* __restrict__ U0, const float* __restrict__ W10,
                                              float* __restrict__ H0,
                                              const float* __restrict__ U1, const float* __restrict__ W11,
                                              float* __restrict__ H1,
                                              int halfBlk) {
    __shared__ float a[16 * 64];
    int blk = blockIdx.x, t = threadIdx.x;
    const float* U; const float* W1; float* H;
    int lb;
    if (blk < halfBlk) { U = U0; W1 = W10; H = H0; lb = blk; }
    else               { U = U1; W1 = W11; H = H1; lb = blk - halfBlk; }
    int e = lb >> 5, ht = (lb >> 3) & 3, kc = lb & 7;
    const float* Ue = U + (size_t)e * BB * DIM;
    for (int i = t; i < 1024; i += 256) {
        int b = i >> 6, kk = i & 63;
        a[i] = Ue[b * DIM + kc * 64 + kk];
    }
    __syncthreads();
    float2 acc[BB];
#pragma unroll
    for (int b = 0; b < BB; b++) acc[b] = make_float2(0.f, 0.f);
    int h2 = ht * 512 + 2 * t;
#pragma unroll 4
    for (int kk = 0; kk < 64; kk++) {
        float2 wv = *(const float2*)&W1[((size_t)e * DIM + kc * 64 + kk) * HID + h2];
#pragma unroll
        for (int b = 0; b < BB; b++) {
            float av = a[b * 64 + kk];
            acc[b].x += av * wv.x;
            acc[b].y += av * wv.y;
        }
    }
#pragma unroll
    for (int b = 0; b < BB; b++) {
        atomicAdd(H + (size_t)(e * BB + b) * HID + h2 + 0, acc[b].x);
        atomicAdd(H + (size_t)(e * BB + b) * HID + h2 + 1, acc[b].y);
    }
}

// ============ GELU+bias in place: H = gelu(H + b1) ============
__global__ __launch_bounds__(256) void k_gelu(float* __restrict__ H,
                                              const float* __restrict__ b1a,
                                              const float* __restrict__ b1b,
                                              int eSplit) {
    int idx4 = (blockIdx.x * 256 + threadIdx.x) * 4;
    int e = idx4 >> 15;           // per-e block is 16*2048 = 32768
    int h = idx4 & (HID - 1);
    const float* bp = (e < eSplit) ? (b1a + (size_t)e * HID) : (b1b + (size_t)(e - eSplit) * HID);
    float4 v = *(float4*)&H[idx4];
    float4 bv = *(const float4*)&bp[h];
    v.x = gelu_exact(v.x + bv.x);
    v.y = gelu_exact(v.y + bv.y);
    v.z = gelu_exact(v.z + bv.z);
    v.w = gelu_exact(v.w + bv.w);
    *(float4*)&H[idx4] = v;
}

// ============ MLP layer2 + gate-weighted accumulate (bias b2 folded downstream) ============
// per set: e x kc(16, 128k). thread owns 2 d (float2).
__global__ __launch_bounds__(256) void k_mlp2(const float* __restrict__ H0, const float* __restrict__ W20,
                                              const float* __restrict__ gate0, int ng0, float* __restrict__ out0,
                                              const float* __restrict__ H1, const float* __restrict__ W21,
                                              const float* __restrict__ gate1, int ng1, float* __restrict__ out1,
                                              int halfBlk) {
    __shared__ float a[16 * 128];
    int blk = blockIdx.x, t = threadIdx.x;
    const float* H; const float* W2; const float* gate; float* outp;
    int ng, lb;
    if (blk < halfBlk) { H = H0; W2 = W20; gate = gate0; ng = ng0; outp = out0; lb = blk; }
    else               { H = H1; W2 = W21; gate = gate1; ng = ng1; outp = out1; lb = blk - halfBlk; }
    int e = lb >> 4, kc = lb & 15;
    for (int i = t; i < 2048; i += 256) {
        int b = i >> 7, kk = i & 127;
        a[i] = H[(size_t)(e * BB + b) * HID + kc * 128 + kk];
    }
    __syncthreads();
    float2 acc[BB];
#pragma unroll
    for (int b = 0; b < BB; b++) acc[b] = make_float2(0.f, 0.f);
    int d2 = 2 * t;
#pragma unroll 4
    for (int kk = 0; kk < 128; kk++) {
        float2 wv = *(const float2*)&W2[((size_t)e * HID + kc * 128 + kk) * DIM + d2];
#pragma unroll
        for (int b = 0; b < BB; b++) {
            float av = a[b * 128 + kk];
            acc[b].x += av * wv.x;
            acc[b].y += av * wv.y;
        }
    }
#pragma unroll
    for (int b = 0; b < BB; b++) {
        float g = gate[b * ng + e];
        atomicAdd(outp + (size_t)b * DIM + d2 + 0, g * acc[b].x);
        atomicAdd(outp + (size_t)b * DIM + d2 + 1, g * acc[b].y);
    }
}

// ============ K8a: fused = [FG+bias | FP+bias]; LN; wf gates; tl = affine(fin_ln) ============
__global__ __launch_bounds__(256) void k8a(const float* __restrict__ fg_ln_g, const float* __restrict__ fg_ln_b,
                                           const float* __restrict__ fg_W, const float* __restrict__ fg_b,
                                           const float* __restrict__ fin_ln_g, const float* __restrict__ fin_ln_b,
                                           const float* __restrict__ g_b2, const float* __restrict__ p_b2,
                                           float* __restrict__ ws) {
    __shared__ float sc[8];
    __shared__ float sc2[8];
    int b = blockIdx.x, t = threadIdx.x;
    int w = t >> 6, lane = t & 63;
    float wg[4], wp[4];
#pragma unroll
    for (int e = 0; e < 4; e++) { wg[e] = ws[WS_WG + b * 4 + e]; wp[e] = ws[WS_WP + b * 4 + e]; }
    float v[4];
    v[0] = ws[WS_FG + b * DIM + t]
         + wg[0] * g_b2[t] + wg[1] * g_b2[DIM + t] + wg[2] * g_b2[2 * DIM + t] + wg[3] * g_b2[3 * DIM + t];
    v[1] = ws[WS_FG + b * DIM + t + 256]
         + wg[0] * g_b2[t + 256] + wg[1] * g_b2[DIM + t + 256] + wg[2] * g_b2[2 * DIM + t + 256] + wg[3] * g_b2[3 * DIM + t + 256];
    v[2] = ws[WS_FP + b * DIM + t]
         + wp[0] * p_b2[t] + wp[1] * p_b2[DIM + t] + wp[2] * p_b2[2 * DIM + t] + wp[3] * p_b2[3 * DIM + t];
    v[3] = ws[WS_FP + b * DIM + t + 256]
         + wp[0] * p_b2[t + 256] + wp[1] * p_b2[DIM + t + 256] + wp[2] * p_b2[2 * DIM + t + 256] + wp[3] * p_b2[3 * DIM + t + 256];
    float s1 = wsum(v[0] + v[1] + v[2] + v[3]);
    float s2 = wsum(v[0] * v[0] + v[1] * v[1] + v[2] * v[2] + v[3] * v[3]);
    if (lane == 0) { sc[w] = s1; sc[4 + w] = s2; }
    __syncthreads();
    s1 = sc[0] + sc[1] + sc[2] + sc[3];
    s2 = sc[4] + sc[5] + sc[6] + sc[7];
    float m = s1 / (2 * DIM), var = s2 / (2 * DIM) - m * m, rs = rsqrtf(var + EPS);
    float l0 = 0.f, l1 = 0.f;
    int cols[4] = {t, t + 256, t + 512, t + 768};
#pragma unroll
    for (int j = 0; j < 4; j++) {
        int c = cols[j];
        float xn = (v[j] - m) * rs;
        float tf = xn * fg_ln_g[c] + fg_ln_b[c];
        l0 += tf * fg_W[c * 2 + 0];
        l1 += tf * fg_W[c * 2 + 1];
        ws[WS_TL + b * 1024 + c] = xn * fin_ln_g[c] + fin_ln_b[c];
    }
    l0 = wsum(l0); l1 = wsum(l1);
    if (lane == 0) { sc2[w] = l0; sc2[4 + w] = l1; }
    __syncthreads();
    if (t == 0) {
        float L0 = sc2[0] + sc2[1] + sc2[2] + sc2[3] + fg_b[0];
        float L1 = sc2[4] + sc2[5] + sc2[6] + sc2[7] + fg_b[1];
        float mx = fmaxf(L0, L1);
        float p0 = __expf(L0 - mx), p1 = __expf(L1 - mx);
        float inv = 1.f / (p0 + p1);
        ws[WS_WF + b * NFE + 0] = p0 * inv;
        ws[WS_WF + b * NFE + 1] = p1 * inv;
    }
}

// ============ K8b: LN(FIN + fin_b) -> UF (f-expert affine) ============
__global__ __launch_bounds__(256) void k8b(const float* __restrict__ fin_b,
                                           const float* __restrict__ f_ln_g, const float* __restrict__ f_ln_b,
                                           float* __restrict__ ws) {
    __shared__ float sc[8];
    int b = blockIdx.x, t = threadIdx.x;
    int w = t >> 6, lane = t & 63;
    int c0 = t, c1 = t + 256;
    float a0 = ws[WS_FIN + b * DIM + c0] + fin_b[c0];
    float a1 = ws[WS_FIN + b * DIM + c1] + fin_b[c1];
    float s1 = wsum(a0 + a1), s2 = wsum(a0 * a0 + a1 * a1);
    if (lane == 0) { sc[w] = s1; sc[4 + w] = s2; }
    __syncthreads();
    s1 = sc[0] + sc[1] + sc[2] + sc[3];
    s2 = sc[4] + sc[5] + sc[6] + sc[7];
    float m = s1 / DIM, var = s2 / DIM - m * m, rs = rsqrtf(var + EPS);
    float x0 = (a0 - m) * rs, x1 = (a1 - m) * rs;
#pragma unroll
    for (int e = 0; e < NFE; e++) {
        ws[WS_UF + (e * BB + b) * DIM + c0] = x0 * f_ln_g[e * DIM + c0] + f_ln_b[e * DIM + c0];
        ws[WS_UF + (e * BB + b) * DIM + c1] = x1 * f_ln_g[e * DIM + c1] + f_ln_b[e * DIM + c1];
    }
}

// ============ K11: classifier (+gate-weighted f_b2 bias) + sigmoid + cumprod ============
__global__ __launch_bounds__(256) void k11_out(const float* __restrict__ cls_W, const float* __restrict__ cls_b,
                                               const float* __restrict__ f_b2,
                                               const float* __restrict__ ws, float* __restrict__ out) {
    __shared__ float4 red[256];
    __shared__ float hz[64];
    int t = threadIdx.x;
    int b = t >> 4, g = t & 15;
    float wf0 = ws[WS_WF + b * 2 + 0], wf1 = ws[WS_WF + b * 2 + 1];
    float4 acc = make_float4(0.f, 0.f, 0.f, 0.f);
#pragma unroll 8
    for (int k = g; k < DIM; k += 16) {
        float x = ws[WS_FIMMF + b * DIM + k] + wf0 * f_b2[k] + wf1 * f_b2[DIM + k];
        float4 wv = *(const float4*)&cls_W[k * 4];
        acc.x += x * wv.x; acc.y += x * wv.y; acc.z += x * wv.z; acc.w += x * wv.w;
    }
    red[t] = acc;
    __syncthreads();
    if (t < 64) {
        int bb = t >> 2, c = t & 3;
        float s = cls_b[c];
#pragma unroll
        for (int j = 0; j < 16; j++) s += ((const float*)&red[bb * 16 + j])[c];
        hz[t] = 1.f / (1.f + __expf(-s));
    }
    __syncthreads();
    if (t < 64) {
        int bb = t >> 2, c = t & 3;
        float S = 1.f;
        for (int j = 0; j <= c; j++) S *= (1.f - hz[bb * 4 + j]);
        out[t] = hz[t];
        out[64 + t] = S;
    }
}

extern "C" void kernel_launch(void* const* d_in, const int* in_sizes, int n_in,
                              void* d_out, int out_size, void* d_ws, size_t ws_size,
                              hipStream_t stream) {
    (void)in_sizes; (void)n_in; (void)out_size; (void)ws_size;
    const float* F_gene    = (const float*)d_in[0];
    const float* F_path    = (const float*)d_in[1];
    const float* gene_ln_g = (const float*)d_in[2];
    const float* gene_ln_b = (const float*)d_in[3];
    const float* gene_W    = (const float*)d_in[4];
    const float* gene_b    = (const float*)d_in[5];
    const float* path_ln_g = (const float*)d_in[6];
    const float* path_ln_b = (const float*)d_in[7];
    const float* path_W    = (const float*)d_in[8];
    const float* path_b    = (const float*)d_in[9];
    const float* g_ln_g    = (const float*)d_in[10];
    const float* g_ln_b    = (const float*)d_in[11];
    const float* g_W1      = (const float*)d_in[12];
    const float* g_b1      = (const float*)d_in[13];
    const float* g_W2      = (const float*)d_in[14];
    const float* g_b2      = (const float*)d_in[15];
    const float* p_q       = (const float*)d_in[16];
    const float* p_ln_g    = (const float*)d_in[17];
    const float* p_ln_b    = (const float*)d_in[18];
    const float* p_W1      = (const float*)d_in[19];
    const float* p_b1      = (const float*)d_in[20];
    const float* p_W2      = (const float*)d_in[21];
    const float* p_b2      = (const float*)d_in[22];
    const float* f_ln_g    = (const float*)d_in[23];
    const float* f_ln_b    = (const float*)d_in[24];
    const float* f_W1      = (const float*)d_in[25];
    const float* f_b1      = (const float*)d_in[26];
    const float* f_W2      = (const float*)d_in[27];
    const float* f_b2      = (const float*)d_in[28];
    const float* gg_ln_g   = (const float*)d_in[29];
    const float* gg_ln_b   = (const float*)d_in[30];
    const float* gg_W      = (const float*)d_in[31];
    const float* gg_b      = (const float*)d_in[32];
    const float* pg_ln_g   = (const float*)d_in[33];
    const float* pg_ln_b   = (const float*)d_in[34];
    const float* pg_W      = (const float*)d_in[35];
    const float* pg_b      = (const float*)d_in[36];
    const float* fg_ln_g   = (const float*)d_in[37];
    const float* fg_ln_b   = (const float*)d_in[38];
    const float* fg_W      = (const float*)d_in[39];
    const float* fg_b      = (const float*)d_in[40];
    const float* fin_ln_g  = (const float*)d_in[41];
    const float* fin_ln_b  = (const float*)d_in[42];
    const float* fin_W     = (const float*)d_in[43];
    const float* fin_b     = (const float*)d_in[44];
    const float* cls_W     = (const float*)d_in[45];
    const float* cls_b     = (const float*)d_in[46];
    float* ws  = (float*)d_ws;
    float* out = (float*)d_out;

    k0_init<<<512, 256, 0, stream>>>(F_gene, path_W, p_q, path_ln_g, ws);
    k1_pass1<<<1024, 256, 0, stream>>>(F_path, ws);
    k2_softmax<<<64, 256, 0, stream>>>(ws);
    k3_pass2<<<1040, 256, 0, stream>>>(F_path, F_gene, gene_W, gene_ln_g, gene_ln_b, ws);
    k_skinny<<<80, 256, 0, stream>>>(nullptr, path_W, ws + WS_POOLED, path_ln_g, path_ln_b, ws, 1);
    k5_rows<<<96, 256, 0, stream>>>(gene_b, path_b, gg_ln_g, gg_ln_b, gg_W, gg_b,
                                    pg_ln_g, pg_ln_b, pg_W, pg_b,
                                    g_ln_g, g_ln_b, p_ln_g, p_ln_b, ws);
    k_mlp1<<<256, 256, 0, stream>>>(ws + WS_UG, g_W1, ws + WS_HG,
                                    ws + WS_UP, p_W1, ws + WS_HP, 128);
    k_gelu<<<256, 256, 0, stream>>>(ws + WS_HG, g_b1, p_b1, 4);
    k_mlp2<<<128, 256, 0, stream>>>(ws + WS_HG, g_W2, ws + WS_WG, NGE, ws + WS_FG,
                                    ws + WS_HP, p_W2, ws + WS_WP, NPE, ws + WS_FP, 64);
    k8a<<<16, 256, 0, stream>>>(fg_ln_g, fg_ln_b, fg_W, fg_b, fin_ln_g, fin_ln_b, g_b2, p_b2, ws);
    k_skinny<<<16, 256, 0, stream>>>(ws + WS_TL, fin_W, ws + WS_FIN, nullptr, nullptr, ws, 0);
    k8b<<<16, 256, 0, stream>>>(fin_b, f_ln_g, f_ln_b, ws);
    k_mlp1<<<64, 256, 0, stream>>>(ws + WS_UF, f_W1, ws + WS_HF,
                                   ws + WS_UF, f_W1, ws + WS_HF, 64);
    k_gelu<<<64, 256, 0, stream>>>(ws + WS_HF, f_b1, f_b1, 2);
    k_mlp2<<<32, 256, 0, stream>>>(ws + WS_HF, f_W2, ws + WS_WF, NFE, ws + WS_FIMMF,
                                   ws + WS_HF, f_W2, ws + WS_WF, NFE, ws + WS_FIMMF, 32);
    k11_out<<<1, 256, 0, stream>>>(cls_W, cls_b, f_b2, ws, out);
}

// Round 4
// 852.000 us; speedup vs baseline: 1.0565x; 1.0549x over previous
//
#include <hip/hip_runtime.h>
#include <math.h>

#define BB 16
#define NTOK 4096
#define DIM 512
#define HID 2048
#define NGE 4
#define NPE 4
#define NFE 2
#define GIN 4096
#define PIN 1024
#define NCLS 4
#define EPS 1e-5f

// ---- workspace layout (float offsets) ----
// zero-initialized accumulator region [0, ZERO_TOT):
#define WS_SUMXN   0            // BB*PIN    = 16384
#define WS_Z       16384        // NPE*BB*PIN= 65536
#define WS_XG      81920        // 8192
#define WS_FG      90112        // 8192
#define WS_FP      98304        // 8192
#define WS_FIMMF   106496       // 8192
#define WS_POOLED  114688       // 32768  (pooled GEMM accum, no path_b)
#define WS_XPMEAN  147456       // 8192   (xp-mean GEMM accum, no path_b)
#define WS_FIN     155648       // 8192   (fused_in GEMM accum, no fin_b)
#define WS_HG      163840       // NGE*BB*HID = 131072 (pre-act accum)
#define WS_HP      294912       // 131072               (contiguous after HG!)
#define WS_HF      425984       // NFE*BB*HID = 65536
#define ZERO_TOT   491520       // 480 blocks x 1024 floats
// scratch (not zeroed):
#define WS_MEAN    491520       // BB*NTOK = 65536
#define WS_RSTD    557056       // 65536
#define WS_S       622592       // NPE*BB*NTOK = 262144
#define WS_QPROJ   884736       // NPE*PIN = 4096
#define WS_GMEAN   888832       // 16
#define WS_GRSTD   888848       // 16
#define WS_WG      888864       // 64
#define WS_WP      888928       // 64
#define WS_WF      888992       // 32
#define WS_UG      889024       // 32768
#define WS_UP      921792       // 32768
#define WS_UF      954560       // 16384
#define WS_TL      970944       // BB*2*DIM = 16384
#define WS_END     987328       // ~3.95 MB

__device__ __forceinline__ float wsum(float v) {
#pragma unroll
    for (int o = 32; o > 0; o >>= 1) v += __shfl_xor(v, o);
    return v;
}
__device__ __forceinline__ float wmax(float v) {
#pragma unroll
    for (int o = 32; o > 0; o >>= 1) v = fmaxf(v, __shfl_xor(v, o));
    return v;
}
__device__ __forceinline__ float gelu_exact(float x) {
    return 0.5f * x * (1.0f + erff(x * 0.70710678118654752f));
}

// ============ K0: zero accumulators | qproj (wave-per-row) | gene row stats ============
__global__ __launch_bounds__(256) void k0_init(const float* __restrict__ F_gene,
                                               const float* __restrict__ path_W,
                                               const float* __restrict__ p_q,
                                               const float* __restrict__ path_ln_g,
                                               float* __restrict__ ws) {
    int blk = blockIdx.x, t = threadIdx.x;
    if (blk < 480) {
        ((float4*)ws)[blk * 256 + t] = make_float4(0.f, 0.f, 0.f, 0.f);
    } else if (blk < 496) {
        // qproj[e,k] = path_ln_g[k] * sum_d path_W[k,d] * p_q[e,d]; wave per row k
        __shared__ __align__(16) float pq[NPE * DIM];
        for (int i = t; i < NPE * DIM; i += 256) pq[i] = p_q[i];
        __syncthreads();
        int w = t >> 6, lane = t & 63;
        const float4* pq4 = (const float4*)pq;  // 128 float4 per expert
        for (int i = 0; i < 16; i++) {
            int k = (blk - 480) * 64 + w * 16 + i;
            const float4* wp4 = (const float4*)(path_W + (size_t)k * DIM);
            float4 x0 = wp4[lane], x1 = wp4[lane + 64];
            float sc[NPE];
#pragma unroll
            for (int e = 0; e < NPE; e++) {
                float4 q0 = pq4[e * 128 + lane], q1 = pq4[e * 128 + lane + 64];
                float d = x0.x * q0.x + x0.y * q0.y + x0.z * q0.z + x0.w * q0.w +
                          x1.x * q1.x + x1.y * q1.y + x1.z * q1.z + x1.w * q1.w;
                sc[e] = wsum(d);
            }
            if (lane == 0) {
                float g = path_ln_g[k];
#pragma unroll
                for (int e = 0; e < NPE; e++) ws[WS_QPROJ + e * PIN + k] = g * sc[e];
            }
        }
    } else {
        // gene row stats (16 rows of 4096)
        int b = blk - 496;
        const float4* row = (const float4*)(F_gene + (size_t)b * GIN);
        float s1 = 0.f, s2 = 0.f;
        for (int i = t; i < GIN / 4; i += 256) {
            float4 v = row[i];
            s1 += v.x + v.y + v.z + v.w;
            s2 += v.x * v.x + v.y * v.y + v.z * v.z + v.w * v.w;
        }
        __shared__ float sc[8];
        s1 = wsum(s1); s2 = wsum(s2);
        int w = t >> 6;
        if ((t & 63) == 0) { sc[w] = s1; sc[4 + w] = s2; }
        __syncthreads();
        if (t == 0) {
            float S1 = sc[0] + sc[1] + sc[2] + sc[3];
            float S2 = sc[4] + sc[5] + sc[6] + sc[7];
            float m = S1 / GIN;
            float var = S2 / GIN - m * m;
            ws[WS_GMEAN + b] = m;
            ws[WS_GRSTD + b] = rsqrtf(var + EPS);
        }
    }
}

// ============ K1: F_path pass1 — LN stats, score dots, sum of xn ============
__global__ __launch_bounds__(256) void k1_pass1(const float* __restrict__ F_path,
                                                float* __restrict__ ws) {
    __shared__ __align__(16) float qlds[NPE * PIN];  // 16 KB
    __shared__ __align__(16) float comb[4 * PIN];    // 16 KB
    int t = threadIdx.x;
    for (int i = t; i < NPE * PIN; i += 256) qlds[i] = ws[WS_QPROJ + i];
    __syncthreads();
    int blk = blockIdx.x;
    int b = blk >> 6, chunk = blk & 63;
    int w = t >> 6, lane = t & 63;
    const float4* qp4 = (const float4*)qlds;
    float4 sxn[4];
#pragma unroll
    for (int j = 0; j < 4; j++) sxn[j] = make_float4(0.f, 0.f, 0.f, 0.f);
    for (int i = 0; i < 16; i++) {
        int n = chunk * 64 + w * 16 + i;
        const float4* rowp = (const float4*)(F_path + ((size_t)(b * NTOK + n)) * PIN);
        float4 x[4];
#pragma unroll
        for (int j = 0; j < 4; j++) x[j] = rowp[lane + 64 * j];
        float s1 = 0.f, s2 = 0.f;
#pragma unroll
        for (int j = 0; j < 4; j++) {
            s1 += x[j].x + x[j].y + x[j].z + x[j].w;
            s2 += x[j].x * x[j].x + x[j].y * x[j].y + x[j].z * x[j].z + x[j].w * x[j].w;
        }
        s1 = wsum(s1); s2 = wsum(s2);
        float m = s1 * (1.f / PIN);
        float var = s2 * (1.f / PIN) - m * m;
        float r = rsqrtf(var + EPS);
        float sc[NPE];
#pragma unroll
        for (int e = 0; e < NPE; e++) {
            float d = 0.f;
#pragma unroll
            for (int j = 0; j < 4; j++) {
                float4 q = qp4[e * (PIN / 4) + lane + 64 * j];
                d += (x[j].x - m) * q.x + (x[j].y - m) * q.y +
                     (x[j].z - m) * q.z + (x[j].w - m) * q.w;
            }
            sc[e] = wsum(d) * r;
        }
#pragma unroll
        for (int j = 0; j < 4; j++) {
            sxn[j].x += (x[j].x - m) * r;
            sxn[j].y += (x[j].y - m) * r;
            sxn[j].z += (x[j].z - m) * r;
            sxn[j].w += (x[j].w - m) * r;
        }
        if (lane == 0) {
            ws[WS_MEAN + b * NTOK + n] = m;
            ws[WS_RSTD + b * NTOK + n] = r;
#pragma unroll
            for (int e = 0; e < NPE; e++) ws[WS_S + (e * BB + b) * NTOK + n] = sc[e];
        }
    }
    float4* comb4 = (float4*)comb;
#pragma unroll
    for (int j = 0; j < 4; j++) comb4[w * (PIN / 4) + lane + 64 * j] = sxn[j];
    __syncthreads();
    {
        float4 a = comb4[t], bq = comb4[256 + t], c = comb4[512 + t], d = comb4[768 + t];
        atomicAdd(ws + WS_SUMXN + b * PIN + 4 * t + 0, a.x + bq.x + c.x + d.x);
        atomicAdd(ws + WS_SUMXN + b * PIN + 4 * t + 1, a.y + bq.y + c.y + d.y);
        atomicAdd(ws + WS_SUMXN + b * PIN + 4 * t + 2, a.z + bq.z + c.z + d.z);
        atomicAdd(ws + WS_SUMXN + b * PIN + 4 * t + 3, a.w + bq.w + c.w + d.w);
    }
}

// ============ K2: softmax over n for each (e,b) ============
__global__ __launch_bounds__(256) void k2_softmax(float* __restrict__ ws) {
    int row = blockIdx.x;
    float* s = ws + WS_S + (size_t)row * NTOK;
    int t = threadIdx.x, w = t >> 6, lane = t & 63;
    __shared__ float sc[4];
    float4 v[4];
    float mx = -1e30f;
#pragma unroll
    for (int j = 0; j < 4; j++) {
        v[j] = ((float4*)s)[t + j * 256];
        mx = fmaxf(mx, fmaxf(fmaxf(v[j].x, v[j].y), fmaxf(v[j].z, v[j].w)));
    }
    mx = wmax(mx);
    if (lane == 0) sc[w] = mx;
    __syncthreads();
    mx = fmaxf(fmaxf(sc[0], sc[1]), fmaxf(sc[2], sc[3]));
    __syncthreads();
    float sum = 0.f;
#pragma unroll
    for (int j = 0; j < 4; j++) {
        v[j].x = __expf(v[j].x - mx); v[j].y = __expf(v[j].y - mx);
        v[j].z = __expf(v[j].z - mx); v[j].w = __expf(v[j].w - mx);
        sum += v[j].x + v[j].y + v[j].z + v[j].w;
    }
    sum = wsum(sum);
    if (lane == 0) sc[w] = sum;
    __syncthreads();
    float inv = 1.f / (sc[0] + sc[1] + sc[2] + sc[3]);
#pragma unroll
    for (int j = 0; j < 4; j++) {
        v[j].x *= inv; v[j].y *= inv; v[j].z *= inv; v[j].w *= inv;
        ((float4*)s)[t + j * 256] = v[j];
    }
}

// ============ K3: F_path pass2 (z = attn-weighted sum of xn) + gene GEMM ============
// Wave-per-expert decomposition: NPE==4 waves; wave w accumulates expert w's z
// over all 64 tokens of the chunk. Per-thread accumulator = 16 floats in four
// NAMED float4 scalars (no arrays, no runtime indices -> cannot be demoted to
// scratch). The 4 waves re-read the same rows; L1/L2 dedups, HBM unchanged.
// No LDS reduction, no __syncthreads in this branch: each wave's lanes hold
// the full 1024-dim partial z for its expert -> direct atomicAdd.
__global__ __launch_bounds__(256) void k3_pass2(const float* __restrict__ F_path,
                                                const float* __restrict__ F_gene,
                                                const float* __restrict__ gene_W,
                                                const float* __restrict__ gene_ln_g,
                                                const float* __restrict__ gene_ln_b,
                                                float* __restrict__ ws) {
    __shared__ __align__(16) float lds[4096];
    int t = threadIdx.x, blk = blockIdx.x;
    if (blk < 1024) {
        int b = blk >> 6, chunk = blk & 63;
        int w = t >> 6, lane = t & 63;   // w = expert index (NPE==4 waves)
        float4 za = make_float4(0.f, 0.f, 0.f, 0.f);
        float4 zb = make_float4(0.f, 0.f, 0.f, 0.f);
        float4 zc = make_float4(0.f, 0.f, 0.f, 0.f);
        float4 zd = make_float4(0.f, 0.f, 0.f, 0.f);
        const float* mrow = ws + WS_MEAN + (size_t)b * NTOK;
        const float* rrow = ws + WS_RSTD + (size_t)b * NTOK;
        const float* srow = ws + WS_S + ((size_t)(w * BB + b)) * NTOK;
        int n0 = chunk * 64;
        for (int i = 0; i < 64; i++) {
            int n = n0 + i;
            const float4* rowp = (const float4*)(F_path + ((size_t)(b * NTOK + n)) * PIN);
            float4 x0 = rowp[lane];
            float4 x1 = rowp[lane + 64];
            float4 x2 = rowp[lane + 128];
            float4 x3 = rowp[lane + 192];
            float m = mrow[n];
            float ar = srow[n] * rrow[n];
            za.x += ar * (x0.x - m); za.y += ar * (x0.y - m);
            za.z += ar * (x0.z - m); za.w += ar * (x0.w - m);
            zb.x += ar * (x1.x - m); zb.y += ar * (x1.y - m);
            zb.z += ar * (x1.z - m); zb.w += ar * (x1.w - m);
            zc.x += ar * (x2.x - m); zc.y += ar * (x2.y - m);
            zc.z += ar * (x2.z - m); zc.w += ar * (x2.w - m);
            zd.x += ar * (x3.x - m); zd.y += ar * (x3.y - m);
            zd.z += ar * (x3.z - m); zd.w += ar * (x3.w - m);
        }
        float* zp = ws + WS_Z + ((size_t)(w * BB + b)) * PIN;
        int k0 = 4 * lane;
        atomicAdd(zp + k0 +   0, za.x); atomicAdd(zp + k0 +   1, za.y);
        atomicAdd(zp + k0 +   2, za.z); atomicAdd(zp + k0 +   3, za.w);
        atomicAdd(zp + k0 + 256, zb.x); atomicAdd(zp + k0 + 257, zb.y);
        atomicAdd(zp + k0 + 258, zb.z); atomicAdd(zp + k0 + 259, zb.w);
        atomicAdd(zp + k0 + 512, zc.x); atomicAdd(zp + k0 + 513, zc.y);
        atomicAdd(zp + k0 + 514, zc.z); atomicAdd(zp + k0 + 515, zc.w);
        atomicAdd(zp + k0 + 768, zd.x); atomicAdd(zp + k0 + 769, zd.y);
        atomicAdd(zp + k0 + 770, zd.z); atomicAdd(zp + k0 + 771, zd.w);
    } else {
        // gene projection k-chunk of 256
        int k0 = (blk - 1024) * 256;
        for (int b = 0; b < BB; b++) {
            float x = F_gene[(size_t)b * GIN + k0 + t];
            float m = ws[WS_GMEAN + b], r = ws[WS_GRSTD + b];
            lds[b * 256 + t] = (x - m) * r * gene_ln_g[k0 + t] + gene_ln_b[k0 + t];
        }
        __syncthreads();
        float acc0[BB], acc1[BB];
#pragma unroll
        for (int b = 0; b < BB; b++) { acc0[b] = 0.f; acc1[b] = 0.f; }
        int d0 = t, d1 = t + 256;
#pragma unroll 8
        for (int kk = 0; kk < 256; kk++) {
            float w0 = gene_W[(size_t)(k0 + kk) * DIM + d0];
            float w1 = gene_W[(size_t)(k0 + kk) * DIM + d1];
#pragma unroll
            for (int b = 0; b < BB; b++) {
                float y = lds[b * 256 + kk];
                acc0[b] += y * w0; acc1[b] += y * w1;
            }
        }
#pragma unroll
        for (int b = 0; b < BB; b++) {
            atomicAdd(ws + WS_XG + b * DIM + d0, acc0[b]);
            atomicAdd(ws + WS_XG + b * DIM + d1, acc1[b]);
        }
    }
}

// ============ skinny GEMM: out[M,512] += A[M,1024] @ W[1024,512], k-split ============
// pool=1: A rows from Z/SUMXN with path affine (M=80, grid 80); pool=0: A = tl (M=16, grid 16)
__global__ __launch_bounds__(256) void k_skinny(const float* __restrict__ A,
                                                const float* __restrict__ W,
                                                float* __restrict__ out,
                                                const float* __restrict__ lng,
                                                const float* __restrict__ lnb,
                                                const float* __restrict__ ws,
                                                int pool) {
    __shared__ __align__(16) float a[16 * 64];
    int blk = blockIdx.x, t = threadIdx.x;
    int rg = blk >> 4, kc = blk & 15;
    for (int i = t; i < 1024; i += 256) {
        int r = rg * 16 + (i >> 6);
        int k = kc * 64 + (i & 63);
        float v;
        if (pool) {
            v = (r < 64) ? ws[WS_Z + (size_t)r * PIN + k]
                         : ws[WS_SUMXN + (size_t)(r - 64) * PIN + k] * (1.f / NTOK);
            v = v * lng[k] + lnb[k];
        } else {
            v = A[(size_t)r * PIN + k];
        }
        a[i] = v;
    }
    __syncthreads();
    float2 acc[16];
#pragma unroll
    for (int r = 0; r < 16; r++) acc[r] = make_float2(0.f, 0.f);
    int d2 = 2 * t;
#pragma unroll 4
    for (int k = 0; k < 64; k++) {
        float2 wv = *(const float2*)&W[(size_t)(kc * 64 + k) * DIM + d2];
#pragma unroll
        for (int r = 0; r < 16; r++) {
            float av = a[r * 64 + k];
            acc[r].x += av * wv.x;
            acc[r].y += av * wv.y;
        }
    }
#pragma unroll
    for (int r = 0; r < 16; r++) {
        int rr = rg * 16 + r;
        atomicAdd(out + (size_t)rr * DIM + d2 + 0, acc[r].x);
        atomicAdd(out + (size_t)rr * DIM + d2 + 1, acc[r].y);
    }
}

// ============ K5: row LN + gating + expert-input affine ============
__global__ __launch_bounds__(256) void k5_rows(const float* __restrict__ gene_b,
    const float* __restrict__ path_b,
    const float* __restrict__ gg_ln_g, const float* __restrict__ gg_ln_b,
    const float* __restrict__ gg_W, const float* __restrict__ gg_b,
    const float* __restrict__ pg_ln_g, const float* __restrict__ pg_ln_b,
    const float* __restrict__ pg_W, const float* __restrict__ pg_b,
    const float* __restrict__ g_ln_g, const float* __restrict__ g_ln_b,
    const float* __restrict__ p_ln_g, const float* __restrict__ p_ln_b,
    float* __restrict__ ws) {
    int blk = blockIdx.x, t = threadIdx.x;
    __shared__ float sc[8];
    __shared__ float sc2[16];
    int c0 = t, c1 = t + 256;
    int w = t >> 6, lane = t & 63;
    float v0, v1;
    int type, b = 0, r = 0;
    if (blk < 16) {
        type = 0; b = blk;
        v0 = ws[WS_XG + b * DIM + c0] + gene_b[c0];
        v1 = ws[WS_XG + b * DIM + c1] + gene_b[c1];
    } else if (blk < 32) {
        type = 1; b = blk - 16;
        v0 = ws[WS_XPMEAN + b * DIM + c0] + path_b[c0];
        v1 = ws[WS_XPMEAN + b * DIM + c1] + path_b[c1];
    } else {
        type = 2; r = blk - 32;
        v0 = ws[WS_POOLED + r * DIM + c0] + path_b[c0];
        v1 = ws[WS_POOLED + r * DIM + c1] + path_b[c1];
    }
    float s1 = wsum(v0 + v1), s2 = wsum(v0 * v0 + v1 * v1);
    if (lane == 0) { sc[w] = s1; sc[4 + w] = s2; }
    __syncthreads();
    s1 = sc[0] + sc[1] + sc[2] + sc[3];
    s2 = sc[4] + sc[5] + sc[6] + sc[7];
    float m = s1 / DIM, var = s2 / DIM - m * m, rs = rsqrtf(var + EPS);
    float xn0 = (v0 - m) * rs, xn1 = (v1 - m) * rs;
    if (type == 0) {
#pragma unroll
        for (int e = 0; e < NGE; e++) {
            ws[WS_UG + (e * BB + b) * DIM + c0] = xn0 * g_ln_g[e * DIM + c0] + g_ln_b[e * DIM + c0];
            ws[WS_UG + (e * BB + b) * DIM + c1] = xn1 * g_ln_g[e * DIM + c1] + g_ln_b[e * DIM + c1];
        }
        float t0 = xn0 * gg_ln_g[c0] + gg_ln_b[c0];
        float t1 = xn1 * gg_ln_g[c1] + gg_ln_b[c1];
        float l[4];
#pragma unroll
        for (int e = 0; e < 4; e++) l[e] = wsum(t0 * gg_W[c0 * 4 + e] + t1 * gg_W[c1 * 4 + e]);
        if (lane == 0)
#pragma unroll
            for (int e = 0; e < 4; e++) sc2[w * 4 + e] = l[e];
        __syncthreads();
        if (t == 0) {
            float lg[4], mx = -1e30f;
#pragma unroll
            for (int e = 0; e < 4; e++) {
                lg[e] = sc2[e] + sc2[4 + e] + sc2[8 + e] + sc2[12 + e] + gg_b[e];
                mx = fmaxf(mx, lg[e]);
            }
            float sum = 0.f;
#pragma unroll
            for (int e = 0; e < 4; e++) { lg[e] = __expf(lg[e] - mx); sum += lg[e]; }
#pragma unroll
            for (int e = 0; e < 4; e++) ws[WS_WG + b * NGE + e] = lg[e] / sum;
        }
    } else if (type == 1) {
        float t0 = xn0 * pg_ln_g[c0] + pg_ln_b[c0];
        float t1 = xn1 * pg_ln_g[c1] + pg_ln_b[c1];
        float l[4];
#pragma unroll
        for (int e = 0; e < 4; e++) l[e] = wsum(t0 * pg_W[c0 * 4 + e] + t1 * pg_W[c1 * 4 + e]);
        if (lane == 0)
#pragma unroll
            for (int e = 0; e < 4; e++) sc2[w * 4 + e] = l[e];
        __syncthreads();
        if (t == 0) {
            float lg[4], mx = -1e30f;
#pragma unroll
            for (int e = 0; e < 4; e++) {
                lg[e] = sc2[e] + sc2[4 + e] + sc2[8 + e] + sc2[12 + e] + pg_b[e];
                mx = fmaxf(mx, lg[e]);
            }
            float sum = 0.f;
#pragma unroll
            for (int e = 0; e < 4; e++) { lg[e] = __expf(lg[e] - mx); sum += lg[e]; }
#pragma unroll
            for (int e = 0; e < 4; e++) ws[WS_WP + b * NPE + e] = lg[e] / sum;
        }
    } else {
        int e = r >> 4;
        ws[WS_UP + r * DIM + c0] = xn0 * p_ln_g[e * DIM + c0] + p_ln_b[e * DIM + c0];
        ws[WS_UP + r * DIM + c1] = xn1 * p_ln_g[e * DIM + c1] + p_ln_b[e * DIM + c1];
    }
}

// ============ MLP layer1 pre-act: Hacc[e,b,h] += sum_k U[e,b,k] W1[e,k,h] ============
// per set: e x ht(4, 512h) x kc(8, 64k). thread owns 2 h (float2).
__global__ __launch_bounds__(256) void k_mlp1(const float* __restrict__ U0, const float* __restrict__ W10,
                                              float* __restrict__ H0,
                                              const float* __restrict__ U1, const float* __restrict__ W11,
                                              float* __restrict__ H1,
                                              int halfBlk) {
    __shared__ float a[16 * 64];
    int blk = blockIdx.x, t = threadIdx.x;
    const float* U; const float* W1; float* H;
    int lb;
    if (blk < halfBlk) { U = U0; W1 = W10; H = H0; lb = blk; }
    else               { U = U1; W1 = W11; H = H1; lb = blk - halfBlk; }
    int e = lb >> 5, ht = (lb >> 3) & 3, kc = lb & 7;
    const float* Ue = U + (size_t)e * BB * DIM;
    for (int i = t; i < 1024; i += 256) {
        int b = i >> 6, kk = i & 63;
        a[i] = Ue[b * DIM + kc * 64 + kk];
    }
    __syncthreads();
    float2 acc[BB];
#pragma unroll
    for (int b = 0; b < BB; b++) acc[b] = make_float2(0.f, 0.f);
    int h2 = ht * 512 + 2 * t;
#pragma unroll 4
    for (int kk = 0; kk < 64; kk++) {
        float2 wv = *(const float2*)&W1[((size_t)e * DIM + kc * 64 + kk) * HID + h2];
#pragma unroll
        for (int b = 0; b < BB; b++) {
            float av = a[b * 64 + kk];
            acc[b].x += av * wv.x;
            acc[b].y += av * wv.y;
        }
    }
#pragma unroll
    for (int b = 0; b < BB; b++) {
        atomicAdd(H + (size_t)(e * BB + b) * HID + h2 + 0, acc[b].x);
        atomicAdd(H + (size_t)(e * BB + b) * HID + h2 + 1, acc[b].y);
    }
}

// ============ GELU+bias in place: H = gelu(H + b1) ============
__global__ __launch_bounds__(256) void k_gelu(float* __restrict__ H,
                                              const float* __restrict__ b1a,
                                              const float* __restrict__ b1b,
                                              int eSplit) {
    int idx4 = (blockIdx.x * 256 + threadIdx.x) * 4;
    int e = idx4 >> 15;           // per-e block is 16*2048 = 32768
    int h = idx4 & (HID - 1);
    const float* bp = (e < eSplit) ? (b1a + (size_t)e * HID) : (b1b + (size_t)(e - eSplit) * HID);
    float4 v = *(float4*)&H[idx4];
    float4 bv = *(const float4*)&bp[h];
    v.x = gelu_exact(v.x + bv.x);
    v.y = gelu_exact(v.y + bv.y);
    v.z = gelu_exact(v.z + bv.z);
    v.w = gelu_exact(v.w + bv.w);
    *(float4*)&H[idx4] = v;
}

// ============ MLP layer2 + gate-weighted accumulate (bias b2 folded downstream) ============
// per set: e x kc(16, 128k). thread owns 2 d (float2).
__global__ __launch_bounds__(256) void k_mlp2(const float* __restrict__ H0, const float* __restrict__ W20,
                                              const float* __restrict__ gate0, int ng0, float* __restrict__ out0,
                                              const float* __restrict__ H1, const float* __restrict__ W21,
                                              const float* __restrict__ gate1, int ng1, float* __restrict__ out1,
                                              int halfBlk) {
    __shared__ float a[16 * 128];
    int blk = blockIdx.x, t = threadIdx.x;
    const float* H; const float* W2; const float* gate; float* outp;
    int ng, lb;
    if (blk < halfBlk) { H = H0; W2 = W20; gate = gate0; ng = ng0; outp = out0; lb = blk; }
    else               { H = H1; W2 = W21; gate = gate1; ng = ng1; outp = out1; lb = blk - halfBlk; }
    int e = lb >> 4, kc = lb & 15;
    for (int i = t; i < 2048; i += 256) {
        int b = i >> 7, kk = i & 127;
        a[i] = H[(size_t)(e * BB + b) * HID + kc * 128 + kk];
    }
    __syncthreads();
    float2 acc[BB];
#pragma unroll
    for (int b = 0; b < BB; b++) acc[b] = make_float2(0.f, 0.f);
    int d2 = 2 * t;
#pragma unroll 4
    for (int kk = 0; kk < 128; kk++) {
        float2 wv = *(const float2*)&W2[((size_t)e * HID + kc * 128 + kk) * DIM + d2];
#pragma unroll
        for (int b = 0; b < BB; b++) {
            float av = a[b * 128 + kk];
            acc[b].x += av * wv.x;
            acc[b].y += av * wv.y;
        }
    }
#pragma unroll
    for (int b = 0; b < BB; b++) {
        float g = gate[b * ng + e];
        atomicAdd(outp + (size_t)b * DIM + d2 + 0, g * acc[b].x);
        atomicAdd(outp + (size_t)b * DIM + d2 + 1, g * acc[b].y);
    }
}

// ============ K8a: fused = [FG+bias | FP+bias]; LN; wf gates; tl = affine(fin_ln) ============
__global__ __launch_bounds__(256) void k8a(const float* __restrict__ fg_ln_g, const float* __restrict__ fg_ln_b,
                                           const float* __restrict__ fg_W, const float* __restrict__ fg_b,
                                           const float* __restrict__ fin_ln_g, const float* __restrict__ fin_ln_b,
                                           const float* __restrict__ g_b2, const float* __restrict__ p_b2,
                                           float* __restrict__ ws) {
    __shared__ float sc[8];
    __shared__ float sc2[8];
    int b = blockIdx.x, t = threadIdx.x;
    int w = t >> 6, lane = t & 63;
    float wg[4], wp[4];
#pragma unroll
    for (int e = 0; e < 4; e++) { wg[e] = ws[WS_WG + b * 4 + e]; wp[e] = ws[WS_WP + b * 4 + e]; }
    float v[4];
    v[0] = ws[WS_FG + b * DIM + t]
         + wg[0] * g_b2[t] + wg[1] * g_b2[DIM + t] + wg[2] * g_b2[2 * DIM + t] + wg[3] * g_b2[3 * DIM + t];
    v[1] = ws[WS_FG + b * DIM + t + 256]
         + wg[0] * g_b2[t + 256] + wg[1] * g_b2[DIM + t + 256] + wg[2] * g_b2[2 * DIM + t + 256] + wg[3] * g_b2[3 * DIM + t + 256];
    v[2] = ws[WS_FP + b * DIM + t]
         + wp[0] * p_b2[t] + wp[1] * p_b2[DIM + t] + wp[2] * p_b2[2 * DIM + t] + wp[3] * p_b2[3 * DIM + t];
    v[3] = ws[WS_FP + b * DIM + t + 256]
         + wp[0] * p_b2[t + 256] + wp[1] * p_b2[DIM + t + 256] + wp[2] * p_b2[2 * DIM + t + 256] + wp[3] * p_b2[3 * DIM + t + 256];
    float s1 = wsum(v[0] + v[1] + v[2] + v[3]);
    float s2 = wsum(v[0] * v[0] + v[1] * v[1] + v[2] * v[2] + v[3] * v[3]);
    if (lane == 0) { sc[w] = s1; sc[4 + w] = s2; }
    __syncthreads();
    s1 = sc[0] + sc[1] + sc[2] + sc[3];
    s2 = sc[4] + sc[5] + sc[6] + sc[7];
    float m = s1 / (2 * DIM), var = s2 / (2 * DIM) - m * m, rs = rsqrtf(var + EPS);
    float l0 = 0.f, l1 = 0.f;
    int cols[4] = {t, t + 256, t + 512, t + 768};
#pragma unroll
    for (int j = 0; j < 4; j++) {
        int c = cols[j];
        float xn = (v[j] - m) * rs;
        float tf = xn * fg_ln_g[c] + fg_ln_b[c];
        l0 += tf * fg_W[c * 2 + 0];
        l1 += tf * fg_W[c * 2 + 1];
        ws[WS_TL + b * 1024 + c] = xn * fin_ln_g[c] + fin_ln_b[c];
    }
    l0 = wsum(l0); l1 = wsum(l1);
    if (lane == 0) { sc2[w] = l0; sc2[4 + w] = l1; }
    __syncthreads();
    if (t == 0) {
        float L0 = sc2[0] + sc2[1] + sc2[2] + sc2[3] + fg_b[0];
        float L1 = sc2[4] + sc2[5] + sc2[6] + sc2[7] + fg_b[1];
        float mx = fmaxf(L0, L1);
        float p0 = __expf(L0 - mx), p1 = __expf(L1 - mx);
        float inv = 1.f / (p0 + p1);
        ws[WS_WF + b * NFE + 0] = p0 * inv;
        ws[WS_WF + b * NFE + 1] = p1 * inv;
    }
}

// ============ K8b: LN(FIN + fin_b) -> UF (f-expert affine) ============
__global__ __launch_bounds__(256) void k8b(const float* __restrict__ fin_b,
                                           const float* __restrict__ f_ln_g, const float* __restrict__ f_ln_b,
                                           float* __restrict__ ws) {
    __shared__ float sc[8];
    int b = blockIdx.x, t = threadIdx.x;
    int w = t >> 6, lane = t & 63;
    int c0 = t, c1 = t + 256;
    float a0 = ws[WS_FIN + b * DIM + c0] + fin_b[c0];
    float a1 = ws[WS_FIN + b * DIM + c1] + fin_b[c1];
    float s1 = wsum(a0 + a1), s2 = wsum(a0 * a0 + a1 * a1);
    if (lane == 0) { sc[w] = s1; sc[4 + w] = s2; }
    __syncthreads();
    s1 = sc[0] + sc[1] + sc[2] + sc[3];
    s2 = sc[4] + sc[5] + sc[6] + sc[7];
    float m = s1 / DIM, var = s2 / DIM - m * m, rs = rsqrtf(var + EPS);
    float x0 = (a0 - m) * rs, x1 = (a1 - m) * rs;
#pragma unroll
    for (int e = 0; e < NFE; e++) {
        ws[WS_UF + (e * BB + b) * DIM + c0] = x0 * f_ln_g[e * DIM + c0] + f_ln_b[e * DIM + c0];
        ws[WS_UF + (e * BB + b) * DIM + c1] = x1 * f_ln_g[e * DIM + c1] + f_ln_b[e * DIM + c1];
    }
}

// ============ K11: classifier (+gate-weighted f_b2 bias) + sigmoid + cumprod ============
__global__ __launch_bounds__(256) void k11_out(const float* __restrict__ cls_W, const float* __restrict__ cls_b,
                                               const float* __restrict__ f_b2,
                                               const float* __restrict__ ws, float* __restrict__ out) {
    __shared__ float4 red[256];
    __shared__ float hz[64];
    int t = threadIdx.x;
    int b = t >> 4, g = t & 15;
    float wf0 = ws[WS_WF + b * 2 + 0], wf1 = ws[WS_WF + b * 2 + 1];
    float4 acc = make_float4(0.f, 0.f, 0.f, 0.f);
#pragma unroll 8
    for (int k = g; k < DIM; k += 16) {
        float x = ws[WS_FIMMF + b * DIM + k] + wf0 * f_b2[k] + wf1 * f_b2[DIM + k];
        float4 wv = *(const float4*)&cls_W[k * 4];
        acc.x += x * wv.x; acc.y += x * wv.y; acc.z += x * wv.z; acc.w += x * wv.w;
    }
    red[t] = acc;
    __syncthreads();
    if (t < 64) {
        int bb = t >> 2, c = t & 3;
        float s = cls_b[c];
#pragma unroll
        for (int j = 0; j < 16; j++) s += ((const float*)&red[bb * 16 + j])[c];
        hz[t] = 1.f / (1.f + __expf(-s));
    }
    __syncthreads();
    if (t < 64) {
        int bb = t >> 2, c = t & 3;
        float S = 1.f;
        for (int j = 0; j <= c; j++) S *= (1.f - hz[bb * 4 + j]);
        out[t] = hz[t];
        out[64 + t] = S;
    }
}

extern "C" void kernel_launch(void* const* d_in, const int* in_sizes, int n_in,
                              void* d_out, int out_size, void* d_ws, size_t ws_size,
                              hipStream_t stream) {
    (void)in_sizes; (void)n_in; (void)out_size; (void)ws_size;
    const float* F_gene    = (const float*)d_in[0];
    const float* F_path    = (const float*)d_in[1];
    const float* gene_ln_g = (const float*)d_in[2];
    const float* gene_ln_b = (const float*)d_in[3];
    const float* gene_W    = (const float*)d_in[4];
    const float* gene_b    = (const float*)d_in[5];
    const float* path_ln_g = (const float*)d_in[6];
    const float* path_ln_b = (const float*)d_in[7];
    const float* path_W    = (const float*)d_in[8];
    const float* path_b    = (const float*)d_in[9];
    const float* g_ln_g    = (const float*)d_in[10];
    const float* g_ln_b    = (const float*)d_in[11];
    const float* g_W1      = (const float*)d_in[12];
    const float* g_b1      = (const float*)d_in[13];
    const float* g_W2      = (const float*)d_in[14];
    const float* g_b2      = (const float*)d_in[15];
    const float* p_q       = (const float*)d_in[16];
    const float* p_ln_g    = (const float*)d_in[17];
    const float* p_ln_b    = (const float*)d_in[18];
    const float* p_W1      = (const float*)d_in[19];
    const float* p_b1      = (const float*)d_in[20];
    const float* p_W2      = (const float*)d_in[21];
    const float* p_b2      = (const float*)d_in[22];
    const float* f_ln_g    = (const float*)d_in[23];
    const float* f_ln_b    = (const float*)d_in[24];
    const float* f_W1      = (const float*)d_in[25];
    const float* f_b1      = (const float*)d_in[26];
    const float* f_W2      = (const float*)d_in[27];
    const float* f_b2      = (const float*)d_in[28];
    const float* gg_ln_g   = (const float*)d_in[29];
    const float* gg_ln_b   = (const float*)d_in[30];
    const float* gg_W      = (const float*)d_in[31];
    const float* gg_b      = (const float*)d_in[32];
    const float* pg_ln_g   = (const float*)d_in[33];
    const float* pg_ln_b   = (const float*)d_in[34];
    const float* pg_W      = (const float*)d_in[35];
    const float* pg_b      = (const float*)d_in[36];
    const float* fg_ln_g   = (const float*)d_in[37];
    const float* fg_ln_b   = (const float*)d_in[38];
    const float* fg_W      = (const float*)d_in[39];
    const float* fg_b      = (const float*)d_in[40];
    const float* fin_ln_g  = (const float*)d_in[41];
    const float* fin_ln_b  = (const float*)d_in[42];
    const float* fin_W     = (const float*)d_in[43];
    const float* fin_b     = (const float*)d_in[44];
    const float* cls_W     = (const float*)d_in[45];
    const float* cls_b     = (const float*)d_in[46];
    float* ws  = (float*)d_ws;
    float* out = (float*)d_out;

    k0_init<<<512, 256, 0, stream>>>(F_gene, path_W, p_q, path_ln_g, ws);
    k1_pass1<<<1024, 256, 0, stream>>>(F_path, ws);
    k2_softmax<<<64, 256, 0, stream>>>(ws);
    k3_pass2<<<1040, 256, 0, stream>>>(F_path, F_gene, gene_W, gene_ln_g, gene_ln_b, ws);
    k_skinny<<<80, 256, 0, stream>>>(nullptr, path_W, ws + WS_POOLED, path_ln_g, path_ln_b, ws, 1);
    k5_rows<<<96, 256, 0, stream>>>(gene_b, path_b, gg_ln_g, gg_ln_b, gg_W, gg_b,
                                    pg_ln_g, pg_ln_b, pg_W, pg_b,
                                    g_ln_g, g_ln_b, p_ln_g, p_ln_b, ws);
    k_mlp1<<<256, 256, 0, stream>>>(ws + WS_UG, g_W1, ws + WS_HG,
                                    ws + WS_UP, p_W1, ws + WS_HP, 128);
    k_gelu<<<256, 256, 0, stream>>>(ws + WS_HG, g_b1, p_b1, 4);
    k_mlp2<<<128, 256, 0, stream>>>(ws + WS_HG, g_W2, ws + WS_WG, NGE, ws + WS_FG,
                                    ws + WS_HP, p_W2, ws + WS_WP, NPE, ws + WS_FP, 64);
    k8a<<<16, 256, 0, stream>>>(fg_ln_g, fg_ln_b, fg_W, fg_b, fin_ln_g, fin_ln_b, g_b2, p_b2, ws);
    k_skinny<<<16, 256, 0, stream>>>(ws + WS_TL, fin_W, ws + WS_FIN, nullptr, nullptr, ws, 0);
    k8b<<<16, 256, 0, stream>>>(fin_b, f_ln_g, f_ln_b, ws);
    k_mlp1<<<64, 256, 0, stream>>>(ws + WS_UF, f_W1, ws + WS_HF,
                                   ws + WS_UF, f_W1, ws + WS_HF, 64);
    k_gelu<<<64, 256, 0, stream>>>(ws + WS_HF, f_b1, f_b1, 2);
    k_mlp2<<<32, 256, 0, stream>>>(ws + WS_HF, f_W2, ws + WS_WF, NFE, ws + WS_FIMMF,
                                   ws + WS_HF, f_W2, ws + WS_WF, NFE, ws + WS_FIMMF, 32);
    k11_out<<<1, 256, 0, stream>>>(cls_W, cls_b, f_b2, ws, out);
}

// Round 5
// 845.478 us; speedup vs baseline: 1.0646x; 1.0077x over previous
//
#include <hip/hip_runtime.h>
#include <math.h>

#define BB 16
#define NTOK 4096
#define DIM 512
#define HID 2048
#define NGE 4
#define NPE 4
#define NFE 2
#define GIN 4096
#define PIN 1024
#define NCLS 4
#define EPS 1e-5f

// ---- workspace layout (float offsets) ----
// zero-initialized accumulator region [0, ZERO_TOT):
#define WS_SUMXN   0            // BB*PIN    = 16384
#define WS_Z       16384        // NPE*BB*PIN= 65536
#define WS_XG      81920        // 8192
#define WS_FG      90112        // 8192
#define WS_FP      98304        // 8192
#define WS_FIMMF   106496       // 8192
#define WS_POOLED  114688       // 32768  (pooled GEMM accum, no path_b)
#define WS_XPMEAN  147456       // 8192   (xp-mean GEMM accum, no path_b)
#define WS_FIN     155648       // 8192   (fused_in GEMM accum, no fin_b)
#define WS_HG      163840       // NGE*BB*HID = 131072 (pre-act accum)
#define WS_HP      294912       // 131072               (contiguous after HG!)
#define WS_HF      425984       // NFE*BB*HID = 65536
#define ZERO_TOT   491520       // 480 blocks x 1024 floats
// scratch (not zeroed):
#define WS_MEAN    491520       // BB*NTOK = 65536
#define WS_RSTD    557056       // 65536
#define WS_S       622592       // NPE*BB*NTOK = 262144
#define WS_QPROJ   884736       // NPE*PIN = 4096
#define WS_GMEAN   888832       // 16
#define WS_GRSTD   888848       // 16
#define WS_WG      888864       // 64
#define WS_WP      888928       // 64
#define WS_WF      888992       // 32
#define WS_UG      889024       // 32768
#define WS_UP      921792       // 32768
#define WS_UF      954560       // 16384
#define WS_TL      970944       // BB*2*DIM = 16384
#define WS_END     987328       // ~3.95 MB

__device__ __forceinline__ float wsum(float v) {
#pragma unroll
    for (int o = 32; o > 0; o >>= 1) v += __shfl_xor(v, o);
    return v;
}
__device__ __forceinline__ float wmax(float v) {
#pragma unroll
    for (int o = 32; o > 0; o >>= 1) v = fmaxf(v, __shfl_xor(v, o));
    return v;
}
__device__ __forceinline__ float gelu_exact(float x) {
    return 0.5f * x * (1.0f + erff(x * 0.70710678118654752f));
}

// ============ K0: zero accumulators | qproj (wave-per-row) | gene row stats ============
__global__ __launch_bounds__(256) void k0_init(const float* __restrict__ F_gene,
                                               const float* __restrict__ path_W,
                                               const float* __restrict__ p_q,
                                               const float* __restrict__ path_ln_g,
                                               float* __restrict__ ws) {
    int blk = blockIdx.x, t = threadIdx.x;
    if (blk < 480) {
        ((float4*)ws)[blk * 256 + t] = make_float4(0.f, 0.f, 0.f, 0.f);
    } else if (blk < 496) {
        // qproj[e,k] = path_ln_g[k] * sum_d path_W[k,d] * p_q[e,d]; wave per row k
        __shared__ __align__(16) float pq[NPE * DIM];
        for (int i = t; i < NPE * DIM; i += 256) pq[i] = p_q[i];
        __syncthreads();
        int w = t >> 6, lane = t & 63;
        const float4* pq4 = (const float4*)pq;  // 128 float4 per expert
        for (int i = 0; i < 16; i++) {
            int k = (blk - 480) * 64 + w * 16 + i;
            const float4* wp4 = (const float4*)(path_W + (size_t)k * DIM);
            float4 x0 = wp4[lane], x1 = wp4[lane + 64];
            float sc[NPE];
#pragma unroll
            for (int e = 0; e < NPE; e++) {
                float4 q0 = pq4[e * 128 + lane], q1 = pq4[e * 128 + lane + 64];
                float d = x0.x * q0.x + x0.y * q0.y + x0.z * q0.z + x0.w * q0.w +
                          x1.x * q1.x + x1.y * q1.y + x1.z * q1.z + x1.w * q1.w;
                sc[e] = wsum(d);
            }
            if (lane == 0) {
                float g = path_ln_g[k];
#pragma unroll
                for (int e = 0; e < NPE; e++) ws[WS_QPROJ + e * PIN + k] = g * sc[e];
            }
        }
    } else {
        // gene row stats (16 rows of 4096)
        int b = blk - 496;
        const float4* row = (const float4*)(F_gene + (size_t)b * GIN);
        float s1 = 0.f, s2 = 0.f;
        for (int i = t; i < GIN / 4; i += 256) {
            float4 v = row[i];
            s1 += v.x + v.y + v.z + v.w;
            s2 += v.x * v.x + v.y * v.y + v.z * v.z + v.w * v.w;
        }
        __shared__ float sc[8];
        s1 = wsum(s1); s2 = wsum(s2);
        int w = t >> 6;
        if ((t & 63) == 0) { sc[w] = s1; sc[4 + w] = s2; }
        __syncthreads();
        if (t == 0) {
            float S1 = sc[0] + sc[1] + sc[2] + sc[3];
            float S2 = sc[4] + sc[5] + sc[6] + sc[7];
            float m = S1 / GIN;
            float var = S2 / GIN - m * m;
            ws[WS_GMEAN + b] = m;
            ws[WS_GRSTD + b] = rsqrtf(var + EPS);
        }
    }
}

// ============ K1: F_path pass1 — LN stats, score dots, sum of xn ============
__global__ __launch_bounds__(256) void k1_pass1(const float* __restrict__ F_path,
                                                float* __restrict__ ws) {
    __shared__ __align__(16) float qlds[NPE * PIN];  // 16 KB
    __shared__ __align__(16) float comb[4 * PIN];    // 16 KB
    int t = threadIdx.x;
    for (int i = t; i < NPE * PIN; i += 256) qlds[i] = ws[WS_QPROJ + i];
    __syncthreads();
    int blk = blockIdx.x;
    int b = blk >> 6, chunk = blk & 63;
    int w = t >> 6, lane = t & 63;
    const float4* qp4 = (const float4*)qlds;
    float4 sxn[4];
#pragma unroll
    for (int j = 0; j < 4; j++) sxn[j] = make_float4(0.f, 0.f, 0.f, 0.f);
    for (int i = 0; i < 16; i++) {
        int n = chunk * 64 + w * 16 + i;
        const float4* rowp = (const float4*)(F_path + ((size_t)(b * NTOK + n)) * PIN);
        float4 x[4];
#pragma unroll
        for (int j = 0; j < 4; j++) x[j] = rowp[lane + 64 * j];
        float s1 = 0.f, s2 = 0.f;
#pragma unroll
        for (int j = 0; j < 4; j++) {
            s1 += x[j].x + x[j].y + x[j].z + x[j].w;
            s2 += x[j].x * x[j].x + x[j].y * x[j].y + x[j].z * x[j].z + x[j].w * x[j].w;
        }
        s1 = wsum(s1); s2 = wsum(s2);
        float m = s1 * (1.f / PIN);
        float var = s2 * (1.f / PIN) - m * m;
        float r = rsqrtf(var + EPS);
        float sc[NPE];
#pragma unroll
        for (int e = 0; e < NPE; e++) {
            float d = 0.f;
#pragma unroll
            for (int j = 0; j < 4; j++) {
                float4 q = qp4[e * (PIN / 4) + lane + 64 * j];
                d += (x[j].x - m) * q.x + (x[j].y - m) * q.y +
                     (x[j].z - m) * q.z + (x[j].w - m) * q.w;
            }
            sc[e] = wsum(d) * r;
        }
#pragma unroll
        for (int j = 0; j < 4; j++) {
            sxn[j].x += (x[j].x - m) * r;
            sxn[j].y += (x[j].y - m) * r;
            sxn[j].z += (x[j].z - m) * r;
            sxn[j].w += (x[j].w - m) * r;
        }
        if (lane == 0) {
            ws[WS_MEAN + b * NTOK + n] = m;
            ws[WS_RSTD + b * NTOK + n] = r;
#pragma unroll
            for (int e = 0; e < NPE; e++) ws[WS_S + (e * BB + b) * NTOK + n] = sc[e];
        }
    }
    float4* comb4 = (float4*)comb;
#pragma unroll
    for (int j = 0; j < 4; j++) comb4[w * (PIN / 4) + lane + 64 * j] = sxn[j];
    __syncthreads();
    {
        float4 a = comb4[t], bq = comb4[256 + t], c = comb4[512 + t], d = comb4[768 + t];
        atomicAdd(ws + WS_SUMXN + b * PIN + 4 * t + 0, a.x + bq.x + c.x + d.x);
        atomicAdd(ws + WS_SUMXN + b * PIN + 4 * t + 1, a.y + bq.y + c.y + d.y);
        atomicAdd(ws + WS_SUMXN + b * PIN + 4 * t + 2, a.z + bq.z + c.z + d.z);
        atomicAdd(ws + WS_SUMXN + b * PIN + 4 * t + 3, a.w + bq.w + c.w + d.w);
    }
}

// ============ K2: softmax over n for each (e,b) ============
__global__ __launch_bounds__(256) void k2_softmax(float* __restrict__ ws) {
    int row = blockIdx.x;
    float* s = ws + WS_S + (size_t)row * NTOK;
    int t = threadIdx.x, w = t >> 6, lane = t & 63;
    __shared__ float sc[4];
    float4 v[4];
    float mx = -1e30f;
#pragma unroll
    for (int j = 0; j < 4; j++) {
        v[j] = ((float4*)s)[t + j * 256];
        mx = fmaxf(mx, fmaxf(fmaxf(v[j].x, v[j].y), fmaxf(v[j].z, v[j].w)));
    }
    mx = wmax(mx);
    if (lane == 0) sc[w] = mx;
    __syncthreads();
    mx = fmaxf(fmaxf(sc[0], sc[1]), fmaxf(sc[2], sc[3]));
    __syncthreads();
    float sum = 0.f;
#pragma unroll
    for (int j = 0; j < 4; j++) {
        v[j].x = __expf(v[j].x - mx); v[j].y = __expf(v[j].y - mx);
        v[j].z = __expf(v[j].z - mx); v[j].w = __expf(v[j].w - mx);
        sum += v[j].x + v[j].y + v[j].z + v[j].w;
    }
    sum = wsum(sum);
    if (lane == 0) sc[w] = sum;
    __syncthreads();
    float inv = 1.f / (sc[0] + sc[1] + sc[2] + sc[3]);
#pragma unroll
    for (int j = 0; j < 4; j++) {
        v[j].x *= inv; v[j].y *= inv; v[j].z *= inv; v[j].w *= inv;
        ((float4*)s)[t + j * 256] = v[j];
    }
}

// ============ K3: F_path pass2 (z = attn-weighted sum of xn) + gene GEMM ============
// Wave-per-expert (R4) + latency fixes (R5):
//  - m[64] and ar[4][64] staged in LDS once per block (coalesced), removing the
//    two dependent broadcast global loads from every inner iteration.
//  - token loop unrolled x2: 8 independent float4 loads issued per iteration
//    (8KB in flight per wave) to cover L2/HBM latency.
// Accumulator = 16 floats in four NAMED float4 scalars (no runtime indices).
__global__ __launch_bounds__(256) void k3_pass2(const float* __restrict__ F_path,
                                                const float* __restrict__ F_gene,
                                                const float* __restrict__ gene_W,
                                                const float* __restrict__ gene_ln_g,
                                                const float* __restrict__ gene_ln_b,
                                                float* __restrict__ ws) {
    __shared__ __align__(16) float lds[4096];
    int t = threadIdx.x, blk = blockIdx.x;
    if (blk < 1024) {
        int b = blk >> 6, chunk = blk & 63;
        int w = t >> 6, lane = t & 63;   // w = expert index (NPE==4 waves)
        int n0 = chunk * 64;
        // stage m and ar = s*rstd into LDS (aliased into lds[]):
        //   lds[0..63]   = m[i]
        //   lds[64+e*64+i] = ar[e][i]
        {
            int e = t >> 6, i = t & 63;
            float rv = ws[WS_RSTD + (size_t)b * NTOK + n0 + i];
            lds[64 + e * 64 + i] = ws[WS_S + ((size_t)(e * BB + b)) * NTOK + n0 + i] * rv;
            if (t < 64) lds[t] = ws[WS_MEAN + (size_t)b * NTOK + n0 + t];
        }
        __syncthreads();
        float4 za = make_float4(0.f, 0.f, 0.f, 0.f);
        float4 zb = make_float4(0.f, 0.f, 0.f, 0.f);
        float4 zc = make_float4(0.f, 0.f, 0.f, 0.f);
        float4 zd = make_float4(0.f, 0.f, 0.f, 0.f);
        const float* arw = lds + 64 + w * 64;
        const float4* base = (const float4*)(F_path + ((size_t)(b * NTOK + n0)) * PIN);
        for (int i = 0; i < 64; i += 2) {
            const float4* r0 = base + (size_t)i * 256;
            const float4* r1 = r0 + 256;
            float4 x0 = r0[lane];
            float4 x1 = r0[lane + 64];
            float4 x2 = r0[lane + 128];
            float4 x3 = r0[lane + 192];
            float4 y0 = r1[lane];
            float4 y1 = r1[lane + 64];
            float4 y2 = r1[lane + 128];
            float4 y3 = r1[lane + 192];
            float m0 = lds[i],     a0 = arw[i];
            float m1 = lds[i + 1], a1 = arw[i + 1];
            za.x += a0 * (x0.x - m0); za.y += a0 * (x0.y - m0);
            za.z += a0 * (x0.z - m0); za.w += a0 * (x0.w - m0);
            zb.x += a0 * (x1.x - m0); zb.y += a0 * (x1.y - m0);
            zb.z += a0 * (x1.z - m0); zb.w += a0 * (x1.w - m0);
            zc.x += a0 * (x2.x - m0); zc.y += a0 * (x2.y - m0);
            zc.z += a0 * (x2.z - m0); zc.w += a0 * (x2.w - m0);
            zd.x += a0 * (x3.x - m0); zd.y += a0 * (x3.y - m0);
            zd.z += a0 * (x3.z - m0); zd.w += a0 * (x3.w - m0);
            za.x += a1 * (y0.x - m1); za.y += a1 * (y0.y - m1);
            za.z += a1 * (y0.z - m1); za.w += a1 * (y0.w - m1);
            zb.x += a1 * (y1.x - m1); zb.y += a1 * (y1.y - m1);
            zb.z += a1 * (y1.z - m1); zb.w += a1 * (y1.w - m1);
            zc.x += a1 * (y2.x - m1); zc.y += a1 * (y2.y - m1);
            zc.z += a1 * (y2.z - m1); zc.w += a1 * (y2.w - m1);
            zd.x += a1 * (y3.x - m1); zd.y += a1 * (y3.y - m1);
            zd.z += a1 * (y3.z - m1); zd.w += a1 * (y3.w - m1);
        }
        float* zp = ws + WS_Z + ((size_t)(w * BB + b)) * PIN;
        int k0 = 4 * lane;
        atomicAdd(zp + k0 +   0, za.x); atomicAdd(zp + k0 +   1, za.y);
        atomicAdd(zp + k0 +   2, za.z); atomicAdd(zp + k0 +   3, za.w);
        atomicAdd(zp + k0 + 256, zb.x); atomicAdd(zp + k0 + 257, zb.y);
        atomicAdd(zp + k0 + 258, zb.z); atomicAdd(zp + k0 + 259, zb.w);
        atomicAdd(zp + k0 + 512, zc.x); atomicAdd(zp + k0 + 513, zc.y);
        atomicAdd(zp + k0 + 514, zc.z); atomicAdd(zp + k0 + 515, zc.w);
        atomicAdd(zp + k0 + 768, zd.x); atomicAdd(zp + k0 + 769, zd.y);
        atomicAdd(zp + k0 + 770, zd.z); atomicAdd(zp + k0 + 771, zd.w);
    } else {
        // gene projection k-chunk of 256
        int k0 = (blk - 1024) * 256;
        for (int b = 0; b < BB; b++) {
            float x = F_gene[(size_t)b * GIN + k0 + t];
            float m = ws[WS_GMEAN + b], r = ws[WS_GRSTD + b];
            lds[b * 256 + t] = (x - m) * r * gene_ln_g[k0 + t] + gene_ln_b[k0 + t];
        }
        __syncthreads();
        float acc0[BB], acc1[BB];
#pragma unroll
        for (int b = 0; b < BB; b++) { acc0[b] = 0.f; acc1[b] = 0.f; }
        int d0 = t, d1 = t + 256;
#pragma unroll 8
        for (int kk = 0; kk < 256; kk++) {
            float w0 = gene_W[(size_t)(k0 + kk) * DIM + d0];
            float w1 = gene_W[(size_t)(k0 + kk) * DIM + d1];
#pragma unroll
            for (int b = 0; b < BB; b++) {
                float y = lds[b * 256 + kk];
                acc0[b] += y * w0; acc1[b] += y * w1;
            }
        }
#pragma unroll
        for (int b = 0; b < BB; b++) {
            atomicAdd(ws + WS_XG + b * DIM + d0, acc0[b]);
            atomicAdd(ws + WS_XG + b * DIM + d1, acc1[b]);
        }
    }
}

// ============ skinny GEMM: out[M,512] += A[M,1024] @ W[1024,512], k-split ============
// pool=1: A rows from Z/SUMXN with path affine (M=80, grid 80); pool=0: A = tl (M=16, grid 16)
__global__ __launch_bounds__(256) void k_skinny(const float* __restrict__ A,
                                                const float* __restrict__ W,
                                                float* __restrict__ out,
                                                const float* __restrict__ lng,
                                                const float* __restrict__ lnb,
                                                const float* __restrict__ ws,
                                                int pool) {
    __shared__ __align__(16) float a[16 * 64];
    int blk = blockIdx.x, t = threadIdx.x;
    int rg = blk >> 4, kc = blk & 15;
    for (int i = t; i < 1024; i += 256) {
        int r = rg * 16 + (i >> 6);
        int k = kc * 64 + (i & 63);
        float v;
        if (pool) {
            v = (r < 64) ? ws[WS_Z + (size_t)r * PIN + k]
                         : ws[WS_SUMXN + (size_t)(r - 64) * PIN + k] * (1.f / NTOK);
            v = v * lng[k] + lnb[k];
        } else {
            v = A[(size_t)r * PIN + k];
        }
        a[i] = v;
    }
    __syncthreads();
    float2 acc[16];
#pragma unroll
    for (int r = 0; r < 16; r++) acc[r] = make_float2(0.f, 0.f);
    int d2 = 2 * t;
#pragma unroll 4
    for (int k = 0; k < 64; k++) {
        float2 wv = *(const float2*)&W[(size_t)(kc * 64 + k) * DIM + d2];
#pragma unroll
        for (int r = 0; r < 16; r++) {
            float av = a[r * 64 + k];
            acc[r].x += av * wv.x;
            acc[r].y += av * wv.y;
        }
    }
#pragma unroll
    for (int r = 0; r < 16; r++) {
        int rr = rg * 16 + r;
        atomicAdd(out + (size_t)rr * DIM + d2 + 0, acc[r].x);
        atomicAdd(out + (size_t)rr * DIM + d2 + 1, acc[r].y);
    }
}

// ============ K5: row LN + gating + expert-input affine ============
__global__ __launch_bounds__(256) void k5_rows(const float* __restrict__ gene_b,
    const float* __restrict__ path_b,
    const float* __restrict__ gg_ln_g, const float* __restrict__ gg_ln_b,
    const float* __restrict__ gg_W, const float* __restrict__ gg_b,
    const float* __restrict__ pg_ln_g, const float* __restrict__ pg_ln_b,
    const float* __restrict__ pg_W, const float* __restrict__ pg_b,
    const float* __restrict__ g_ln_g, const float* __restrict__ g_ln_b,
    const float* __restrict__ p_ln_g, const float* __restrict__ p_ln_b,
    float* __restrict__ ws) {
    int blk = blockIdx.x, t = threadIdx.x;
    __shared__ float sc[8];
    __shared__ float sc2[16];
    int c0 = t, c1 = t + 256;
    int w = t >> 6, lane = t & 63;
    float v0, v1;
    int type, b = 0, r = 0;
    if (blk < 16) {
        type = 0; b = blk;
        v0 = ws[WS_XG + b * DIM + c0] + gene_b[c0];
        v1 = ws[WS_XG + b * DIM + c1] + gene_b[c1];
    } else if (blk < 32) {
        type = 1; b = blk - 16;
        v0 = ws[WS_XPMEAN + b * DIM + c0] + path_b[c0];
        v1 = ws[WS_XPMEAN + b * DIM + c1] + path_b[c1];
    } else {
        type = 2; r = blk - 32;
        v0 = ws[WS_POOLED + r * DIM + c0] + path_b[c0];
        v1 = ws[WS_POOLED + r * DIM + c1] + path_b[c1];
    }
    float s1 = wsum(v0 + v1), s2 = wsum(v0 * v0 + v1 * v1);
    if (lane == 0) { sc[w] = s1; sc[4 + w] = s2; }
    __syncthreads();
    s1 = sc[0] + sc[1] + sc[2] + sc[3];
    s2 = sc[4] + sc[5] + sc[6] + sc[7];
    float m = s1 / DIM, var = s2 / DIM - m * m, rs = rsqrtf(var + EPS);
    float xn0 = (v0 - m) * rs, xn1 = (v1 - m) * rs;
    if (type == 0) {
#pragma unroll
        for (int e = 0; e < NGE; e++) {
            ws[WS_UG + (e * BB + b) * DIM + c0] = xn0 * g_ln_g[e * DIM + c0] + g_ln_b[e * DIM + c0];
            ws[WS_UG + (e * BB + b) * DIM + c1] = xn1 * g_ln_g[e * DIM + c1] + g_ln_b[e * DIM + c1];
        }
        float t0 = xn0 * gg_ln_g[c0] + gg_ln_b[c0];
        float t1 = xn1 * gg_ln_g[c1] + gg_ln_b[c1];
        float l[4];
#pragma unroll
        for (int e = 0; e < 4; e++) l[e] = wsum(t0 * gg_W[c0 * 4 + e] + t1 * gg_W[c1 * 4 + e]);
        if (lane == 0)
#pragma unroll
            for (int e = 0; e < 4; e++) sc2[w * 4 + e] = l[e];
        __syncthreads();
        if (t == 0) {
            float lg[4], mx = -1e30f;
#pragma unroll
            for (int e = 0; e < 4; e++) {
                lg[e] = sc2[e] + sc2[4 + e] + sc2[8 + e] + sc2[12 + e] + gg_b[e];
                mx = fmaxf(mx, lg[e]);
            }
            float sum = 0.f;
#pragma unroll
            for (int e = 0; e < 4; e++) { lg[e] = __expf(lg[e] - mx); sum += lg[e]; }
#pragma unroll
            for (int e = 0; e < 4; e++) ws[WS_WG + b * NGE + e] = lg[e] / sum;
        }
    } else if (type == 1) {
        float t0 = xn0 * pg_ln_g[c0] + pg_ln_b[c0];
        float t1 = xn1 * pg_ln_g[c1] + pg_ln_b[c1];
        float l[4];
#pragma unroll
        for (int e = 0; e < 4; e++) l[e] = wsum(t0 * pg_W[c0 * 4 + e] + t1 * pg_W[c1 * 4 + e]);
        if (lane == 0)
#pragma unroll
            for (int e = 0; e < 4; e++) sc2[w * 4 + e] = l[e];
        __syncthreads();
        if (t == 0) {
            float lg[4], mx = -1e30f;
#pragma unroll
            for (int e = 0; e < 4; e++) {
                lg[e] = sc2[e] + sc2[4 + e] + sc2[8 + e] + sc2[12 + e] + pg_b[e];
                mx = fmaxf(mx, lg[e]);
            }
            float sum = 0.f;
#pragma unroll
            for (int e = 0; e < 4; e++) { lg[e] = __expf(lg[e] - mx); sum += lg[e]; }
#pragma unroll
            for (int e = 0; e < 4; e++) ws[WS_WP + b * NPE + e] = lg[e] / sum;
        }
    } else {
        int e = r >> 4;
        ws[WS_UP + r * DIM + c0] = xn0 * p_ln_g[e * DIM + c0] + p_ln_b[e * DIM + c0];
        ws[WS_UP + r * DIM + c1] = xn1 * p_ln_g[e * DIM + c1] + p_ln_b[e * DIM + c1];
    }
}

// ============ MLP layer1 pre-act: Hacc[e,b,h] += sum_k U[e,b,k] W1[e,k,h] ============
// per set: e x ht(4, 512h) x kc(8, 64k). thread owns 2 h (float2).
__global__ __launch_bounds__(256) void k_mlp1(const float* __restrict__ U0, const float* __restrict__ W10,
                                              float* __restrict__ H0,
                                              const float* __restrict__ U1, const float* __restrict__ W11,
                                              float* __restrict__ H1,
                                              int halfBlk) {
    __shared__ float a[16 * 64];
    int blk = blockIdx.x, t = threadIdx.x;
    const float* U; const float* W1; float* H;
    int lb;
    if (blk < halfBlk) { U = U0; W1 = W10; H = H0; lb = blk; }
    else               { U = U1; W1 = W11; H = H1; lb = blk - halfBlk; }
    int e = lb >> 5, ht = (lb >> 3) & 3, kc = lb & 7;
    const float* Ue = U + (size_t)e * BB * DIM;
    for (int i = t; i < 1024; i += 256) {
        int b = i >> 6, kk = i & 63;
        a[i] = Ue[b * DIM + kc * 64 + kk];
    }
    __syncthreads();
    float2 acc[BB];
#pragma unroll
    for (int b = 0; b < BB; b++) acc[b] = make_float2(0.f, 0.f);
    int h2 = ht * 512 + 2 * t;
#pragma unroll 4
    for (int kk = 0; kk < 64; kk++) {
        float2 wv = *(const float2*)&W1[((size_t)e * DIM + kc * 64 + kk) * HID + h2];
#pragma unroll
        for (int b = 0; b < BB; b++) {
            float av = a[b * 64 + kk];
            acc[b].x += av * wv.x;
            acc[b].y += av * wv.y;
        }
    }
#pragma unroll
    for (int b = 0; b < BB; b++) {
        atomicAdd(H + (size_t)(e * BB + b) * HID + h2 + 0, acc[b].x);
        atomicAdd(H + (size_t)(e * BB + b) * HID + h2 + 1, acc[b].y);
    }
}

// ============ GELU+bias in place: H = gelu(H + b1) ============
__global__ __launch_bounds__(256) void k_gelu(float* __restrict__ H,
                                              const float* __restrict__ b1a,
                                              const float* __restrict__ b1b,
                                              int eSplit) {
    int idx4 = (blockIdx.x * 256 + threadIdx.x) * 4;
    int e = idx4 >> 15;           // per-e block is 16*2048 = 32768
    int h = idx4 & (HID - 1);
    const float* bp = (e < eSplit) ? (b1a + (size_t)e * HID) : (b1b + (size_t)(e - eSplit) * HID);
    float4 v = *(float4*)&H[idx4];
    float4 bv = *(const float4*)&bp[h];
    v.x = gelu_exact(v.x + bv.x);
    v.y = gelu_exact(v.y + bv.y);
    v.z = gelu_exact(v.z + bv.z);
    v.w = gelu_exact(v.w + bv.w);
    *(float4*)&H[idx4] = v;
}

// ============ MLP layer2 + gate-weighted accumulate (bias b2 folded downstream) ============
// per set: e x kc(16, 128k). thread owns 2 d (float2).
__global__ __launch_bounds__(256) void k_mlp2(const float* __restrict__ H0, const float* __restrict__ W20,
                                              const float* __restrict__ gate0, int ng0, float* __restrict__ out0,
                                              const float* __restrict__ H1, const float* __restrict__ W21,
                                              const float* __restrict__ gate1, int ng1, float* __restrict__ out1,
                                              int halfBlk) {
    __shared__ float a[16 * 128];
    int blk = blockIdx.x, t = threadIdx.x;
    const float* H; const float* W2; const float* gate; float* outp;
    int ng, lb;
    if (blk < halfBlk) { H = H0; W2 = W20; gate = gate0; ng = ng0; outp = out0; lb = blk; }
    else               { H = H1; W2 = W21; gate = gate1; ng = ng1; outp = out1; lb = blk - halfBlk; }
    int e = lb >> 4, kc = lb & 15;
    for (int i = t; i < 2048; i += 256) {
        int b = i >> 7, kk = i & 127;
        a[i] = H[(size_t)(e * BB + b) * HID + kc * 128 + kk];
    }
    __syncthreads();
    float2 acc[BB];
#pragma unroll
    for (int b = 0; b < BB; b++) acc[b] = make_float2(0.f, 0.f);
    int d2 = 2 * t;
#pragma unroll 4
    for (int kk = 0; kk < 128; kk++) {
        float2 wv = *(const float2*)&W2[((size_t)e * HID + kc * 128 + kk) * DIM + d2];
#pragma unroll
        for (int b = 0; b < BB; b++) {
            float av = a[b * 128 + kk];
            acc[b].x += av * wv.x;
            acc[b].y += av * wv.y;
        }
    }
#pragma unroll
    for (int b = 0; b < BB; b++) {
        float g = gate[b * ng + e];
        atomicAdd(outp + (size_t)b * DIM + d2 + 0, g * acc[b].x);
        atomicAdd(outp + (size_t)b * DIM + d2 + 1, g * acc[b].y);
    }
}

// ============ K8a: fused = [FG+bias | FP+bias]; LN; wf gates; tl = affine(fin_ln) ============
__global__ __launch_bounds__(256) void k8a(const float* __restrict__ fg_ln_g, const float* __restrict__ fg_ln_b,
                                           const float* __restrict__ fg_W, const float* __restrict__ fg_b,
                                           const float* __restrict__ fin_ln_g, const float* __restrict__ fin_ln_b,
                                           const float* __restrict__ g_b2, const float* __restrict__ p_b2,
                                           float* __restrict__ ws) {
    __shared__ float sc[8];
    __shared__ float sc2[8];
    int b = blockIdx.x, t = threadIdx.x;
    int w = t >> 6, lane = t & 63;
    float wg[4], wp[4];
#pragma unroll
    for (int e = 0; e < 4; e++) { wg[e] = ws[WS_WG + b * 4 + e]; wp[e] = ws[WS_WP + b * 4 + e]; }
    float v[4];
    v[0] = ws[WS_FG + b * DIM + t]
         + wg[0] * g_b2[t] + wg[1] * g_b2[DIM + t] + wg[2] * g_b2[2 * DIM + t] + wg[3] * g_b2[3 * DIM + t];
    v[1] = ws[WS_FG + b * DIM + t + 256]
         + wg[0] * g_b2[t + 256] + wg[1] * g_b2[DIM + t + 256] + wg[2] * g_b2[2 * DIM + t + 256] + wg[3] * g_b2[3 * DIM + t + 256];
    v[2] = ws[WS_FP + b * DIM + t]
         + wp[0] * p_b2[t] + wp[1] * p_b2[DIM + t] + wp[2] * p_b2[2 * DIM + t] + wp[3] * p_b2[3 * DIM + t];
    v[3] = ws[WS_FP + b * DIM + t + 256]
         + wp[0] * p_b2[t + 256] + wp[1] * p_b2[DIM + t + 256] + wp[2] * p_b2[2 * DIM + t + 256] + wp[3] * p_b2[3 * DIM + t + 256];
    float s1 = wsum(v[0] + v[1] + v[2] + v[3]);
    float s2 = wsum(v[0] * v[0] + v[1] * v[1] + v[2] * v[2] + v[3] * v[3]);
    if (lane == 0) { sc[w] = s1; sc[4 + w] = s2; }
    __syncthreads();
    s1 = sc[0] + sc[1] + sc[2] + sc[3];
    s2 = sc[4] + sc[5] + sc[6] + sc[7];
    float m = s1 / (2 * DIM), var = s2 / (2 * DIM) - m * m, rs = rsqrtf(var + EPS);
    float l0 = 0.f, l1 = 0.f;
    int cols[4] = {t, t + 256, t + 512, t + 768};
#pragma unroll
    for (int j = 0; j < 4; j++) {
        int c = cols[j];
        float xn = (v[j] - m) * rs;
        float tf = xn * fg_ln_g[c] + fg_ln_b[c];
        l0 += tf * fg_W[c * 2 + 0];
        l1 += tf * fg_W[c * 2 + 1];
        ws[WS_TL + b * 1024 + c] = xn * fin_ln_g[c] + fin_ln_b[c];
    }
    l0 = wsum(l0); l1 = wsum(l1);
    if (lane == 0) { sc2[w] = l0; sc2[4 + w] = l1; }
    __syncthreads();
    if (t == 0) {
        float L0 = sc2[0] + sc2[1] + sc2[2] + sc2[3] + fg_b[0];
        float L1 = sc2[4] + sc2[5] + sc2[6] + sc2[7] + fg_b[1];
        float mx = fmaxf(L0, L1);
        float p0 = __expf(L0 - mx), p1 = __expf(L1 - mx);
        float inv = 1.f / (p0 + p1);
        ws[WS_WF + b * NFE + 0] = p0 * inv;
        ws[WS_WF + b * NFE + 1] = p1 * inv;
    }
}

// ============ K8b: LN(FIN + fin_b) -> UF (f-expert affine) ============
__global__ __launch_bounds__(256) void k8b(const float* __restrict__ fin_b,
                                           const float* __restrict__ f_ln_g, const float* __restrict__ f_ln_b,
                                           float* __restrict__ ws) {
    __shared__ float sc[8];
    int b = blockIdx.x, t = threadIdx.x;
    int w = t >> 6, lane = t & 63;
    int c0 = t, c1 = t + 256;
    float a0 = ws[WS_FIN + b * DIM + c0] + fin_b[c0];
    float a1 = ws[WS_FIN + b * DIM + c1] + fin_b[c1];
    float s1 = wsum(a0 + a1), s2 = wsum(a0 * a0 + a1 * a1);
    if (lane == 0) { sc[w] = s1; sc[4 + w] = s2; }
    __syncthreads();
    s1 = sc[0] + sc[1] + sc[2] + sc[3];
    s2 = sc[4] + sc[5] + sc[6] + sc[7];
    float m = s1 / DIM, var = s2 / DIM - m * m, rs = rsqrtf(var + EPS);
    float x0 = (a0 - m) * rs, x1 = (a1 - m) * rs;
#pragma unroll
    for (int e = 0; e < NFE; e++) {
        ws[WS_UF + (e * BB + b) * DIM + c0] = x0 * f_ln_g[e * DIM + c0] + f_ln_b[e * DIM + c0];
        ws[WS_UF + (e * BB + b) * DIM + c1] = x1 * f_ln_g[e * DIM + c1] + f_ln_b[e * DIM + c1];
    }
}

// ============ K11: classifier (+gate-weighted f_b2 bias) + sigmoid + cumprod ============
__global__ __launch_bounds__(256) void k11_out(const float* __restrict__ cls_W, const float* __restrict__ cls_b,
                                               const float* __restrict__ f_b2,
                                               const float* __restrict__ ws, float* __restrict__ out) {
    __shared__ float4 red[256];
    __shared__ float hz[64];
    int t = threadIdx.x;
    int b = t >> 4, g = t & 15;
    float wf0 = ws[WS_WF + b * 2 + 0], wf1 = ws[WS_WF + b * 2 + 1];
    float4 acc = make_float4(0.f, 0.f, 0.f, 0.f);
#pragma unroll 8
    for (int k = g; k < DIM; k += 16) {
        float x = ws[WS_FIMMF + b * DIM + k] + wf0 * f_b2[k] + wf1 * f_b2[DIM + k];
        float4 wv = *(const float4*)&cls_W[k * 4];
        acc.x += x * wv.x; acc.y += x * wv.y; acc.z += x * wv.z; acc.w += x * wv.w;
    }
    red[t] = acc;
    __syncthreads();
    if (t < 64) {
        int bb = t >> 2, c = t & 3;
        float s = cls_b[c];
#pragma unroll
        for (int j = 0; j < 16; j++) s += ((const float*)&red[bb * 16 + j])[c];
        hz[t] = 1.f / (1.f + __expf(-s));
    }
    __syncthreads();
    if (t < 64) {
        int bb = t >> 2, c = t & 3;
        float S = 1.f;
        for (int j = 0; j <= c; j++) S *= (1.f - hz[bb * 4 + j]);
        out[t] = hz[t];
        out[64 + t] = S;
    }
}

extern "C" void kernel_launch(void* const* d_in, const int* in_sizes, int n_in,
                              void* d_out, int out_size, void* d_ws, size_t ws_size,
                              hipStream_t stream) {
    (void)in_sizes; (void)n_in; (void)out_size; (void)ws_size;
    const float* F_gene    = (const float*)d_in[0];
    const float* F_path    = (const float*)d_in[1];
    const float* gene_ln_g = (const float*)d_in[2];
    const float* gene_ln_b = (const float*)d_in[3];
    const float* gene_W    = (const float*)d_in[4];
    const float* gene_b    = (const float*)d_in[5];
    const float* path_ln_g = (const float*)d_in[6];
    const float* path_ln_b = (const float*)d_in[7];
    const float* path_W    = (const float*)d_in[8];
    const float* path_b    = (const float*)d_in[9];
    const float* g_ln_g    = (const float*)d_in[10];
    const float* g_ln_b    = (const float*)d_in[11];
    const float* g_W1      = (const float*)d_in[12];
    const float* g_b1      = (const float*)d_in[13];
    const float* g_W2      = (const float*)d_in[14];
    const float* g_b2      = (const float*)d_in[15];
    const float* p_q       = (const float*)d_in[16];
    const float* p_ln_g    = (const float*)d_in[17];
    const float* p_ln_b    = (const float*)d_in[18];
    const float* p_W1      = (const float*)d_in[19];
    const float* p_b1      = (const float*)d_in[20];
    const float* p_W2      = (const float*)d_in[21];
    const float* p_b2      = (const float*)d_in[22];
    const float* f_ln_g    = (const float*)d_in[23];
    const float* f_ln_b    = (const float*)d_in[24];
    const float* f_W1      = (const float*)d_in[25];
    const float* f_b1      = (const float*)d_in[26];
    const float* f_W2      = (const float*)d_in[27];
    const float* f_b2      = (const float*)d_in[28];
    const float* gg_ln_g   = (const float*)d_in[29];
    const float* gg_ln_b   = (const float*)d_in[30];
    const float* gg_W      = (const float*)d_in[31];
    const float* gg_b      = (const float*)d_in[32];
    const float* pg_ln_g   = (const float*)d_in[33];
    const float* pg_ln_b   = (const float*)d_in[34];
    const float* pg_W      = (const float*)d_in[35];
    const float* pg_b      = (const float*)d_in[36];
    const float* fg_ln_g   = (const float*)d_in[37];
    const float* fg_ln_b   = (const float*)d_in[38];
    const float* fg_W      = (const float*)d_in[39];
    const float* fg_b      = (const float*)d_in[40];
    const float* fin_ln_g  = (const float*)d_in[41];
    const float* fin_ln_b  = (const float*)d_in[42];
    const float* fin_W     = (const float*)d_in[43];
    const float* fin_b     = (const float*)d_in[44];
    const float* cls_W     = (const float*)d_in[45];
    const float* cls_b     = (const float*)d_in[46];
    float* ws  = (float*)d_ws;
    float* out = (float*)d_out;

    k0_init<<<512, 256, 0, stream>>>(F_gene, path_W, p_q, path_ln_g, ws);
    k1_pass1<<<1024, 256, 0, stream>>>(F_path, ws);
    k2_softmax<<<64, 256, 0, stream>>>(ws);
    k3_pass2<<<1040, 256, 0, stream>>>(F_path, F_gene, gene_W, gene_ln_g, gene_ln_b, ws);
    k_skinny<<<80, 256, 0, stream>>>(nullptr, path_W, ws + WS_POOLED, path_ln_g, path_ln_b, ws, 1);
    k5_rows<<<96, 256, 0, stream>>>(gene_b, path_b, gg_ln_g, gg_ln_b, gg_W, gg_b,
                                    pg_ln_g, pg_ln_b, pg_W, pg_b,
                                    g_ln_g, g_ln_b, p_ln_g, p_ln_b, ws);
    k_mlp1<<<256, 256, 0, stream>>>(ws + WS_UG, g_W1, ws + WS_HG,
                                    ws + WS_UP, p_W1, ws + WS_HP, 128);
    k_gelu<<<256, 256, 0, stream>>>(ws + WS_HG, g_b1, p_b1, 4);
    k_mlp2<<<128, 256, 0, stream>>>(ws + WS_HG, g_W2, ws + WS_WG, NGE, ws + WS_FG,
                                    ws + WS_HP, p_W2, ws + WS_WP, NPE, ws + WS_FP, 64);
    k8a<<<16, 256, 0, stream>>>(fg_ln_g, fg_ln_b, fg_W, fg_b, fin_ln_g, fin_ln_b, g_b2, p_b2, ws);
    k_skinny<<<16, 256, 0, stream>>>(ws + WS_TL, fin_W, ws + WS_FIN, nullptr, nullptr, ws, 0);
    k8b<<<16, 256, 0, stream>>>(fin_b, f_ln_g, f_ln_b, ws);
    k_mlp1<<<64, 256, 0, stream>>>(ws + WS_UF, f_W1, ws + WS_HF,
                                   ws + WS_UF, f_W1, ws + WS_HF, 64);
    k_gelu<<<64, 256, 0, stream>>>(ws + WS_HF, f_b1, f_b1, 2);
    k_mlp2<<<32, 256, 0, stream>>>(ws + WS_HF, f_W2, ws + WS_WF, NFE, ws + WS_FIMMF,
                                   ws + WS_HF, f_W2, ws + WS_WF, NFE, ws + WS_FIMMF, 32);
    k11_out<<<1, 256, 0, stream>>>(cls_W, cls_b, f_b2, ws, out);
}

// Round 6
// 838.882 us; speedup vs baseline: 1.0730x; 1.0079x over previous
//
#include <hip/hip_runtime.h>
#include <math.h>

#define BB 16
#define NTOK 4096
#define DIM 512
#define HID 2048
#define NGE 4
#define NPE 4
#define NFE 2
#define GIN 4096
#define PIN 1024
#define NCLS 4
#define EPS 1e-5f

// ---- workspace layout (float offsets) ----
// zero-initialized accumulator region [0, ZERO_TOT):
#define WS_SUMXN   0            // BB*PIN    = 16384
#define WS_Z       16384        // NPE*BB*PIN= 65536
#define WS_XG      81920        // 8192
#define WS_FG      90112        // 8192
#define WS_FP      98304        // 8192
#define WS_FIMMF   106496       // 8192
#define WS_POOLED  114688       // 32768  (pooled GEMM accum, no path_b)
#define WS_XPMEAN  147456       // 8192   (xp-mean GEMM accum, no path_b)
#define WS_FIN     155648       // 8192   (fused_in GEMM accum, no fin_b)
#define WS_HG      163840       // NGE*BB*HID = 131072 (pre-act accum)
#define WS_HP      294912       // 131072               (contiguous after HG!)
#define WS_HF      425984       // NFE*BB*HID = 65536
#define ZERO_TOT   491520       // 480 blocks x 1024 floats
// scratch (not zeroed):
#define WS_MEAN    491520       // BB*NTOK = 65536
#define WS_RSTD    557056       // 65536
#define WS_S       622592       // NPE*BB*NTOK = 262144
#define WS_QPROJ   884736       // NPE*PIN = 4096
#define WS_GMEAN   888832       // 16
#define WS_GRSTD   888848       // 16
#define WS_WG      888864       // 64
#define WS_WP      888928       // 64
#define WS_WF      888992       // 32
#define WS_UG      889024       // 32768
#define WS_UP      921792       // 32768
#define WS_UF      954560       // 16384
#define WS_TL      970944       // BB*2*DIM = 16384
#define WS_END     987328       // ~3.95 MB

__device__ __forceinline__ float wsum(float v) {
#pragma unroll
    for (int o = 32; o > 0; o >>= 1) v += __shfl_xor(v, o);
    return v;
}
__device__ __forceinline__ float wmax(float v) {
#pragma unroll
    for (int o = 32; o > 0; o >>= 1) v = fmaxf(v, __shfl_xor(v, o));
    return v;
}
__device__ __forceinline__ float gelu_exact(float x) {
    return 0.5f * x * (1.0f + erff(x * 0.70710678118654752f));
}

// ============ K0: zero accumulators | qproj (wave-per-row) | gene row stats ============
__global__ __launch_bounds__(256) void k0_init(const float* __restrict__ F_gene,
                                               const float* __restrict__ path_W,
                                               const float* __restrict__ p_q,
                                               const float* __restrict__ path_ln_g,
                                               float* __restrict__ ws) {
    int blk = blockIdx.x, t = threadIdx.x;
    if (blk < 480) {
        ((float4*)ws)[blk * 256 + t] = make_float4(0.f, 0.f, 0.f, 0.f);
    } else if (blk < 496) {
        // qproj[e,k] = path_ln_g[k] * sum_d path_W[k,d] * p_q[e,d]; wave per row k
        __shared__ __align__(16) float pq[NPE * DIM];
        for (int i = t; i < NPE * DIM; i += 256) pq[i] = p_q[i];
        __syncthreads();
        int w = t >> 6, lane = t & 63;
        const float4* pq4 = (const float4*)pq;  // 128 float4 per expert
        for (int i = 0; i < 16; i++) {
            int k = (blk - 480) * 64 + w * 16 + i;
            const float4* wp4 = (const float4*)(path_W + (size_t)k * DIM);
            float4 x0 = wp4[lane], x1 = wp4[lane + 64];
            float sc[NPE];
#pragma unroll
            for (int e = 0; e < NPE; e++) {
                float4 q0 = pq4[e * 128 + lane], q1 = pq4[e * 128 + lane + 64];
                float d = x0.x * q0.x + x0.y * q0.y + x0.z * q0.z + x0.w * q0.w +
                          x1.x * q1.x + x1.y * q1.y + x1.z * q1.z + x1.w * q1.w;
                sc[e] = wsum(d);
            }
            if (lane == 0) {
                float g = path_ln_g[k];
#pragma unroll
                for (int e = 0; e < NPE; e++) ws[WS_QPROJ + e * PIN + k] = g * sc[e];
            }
        }
    } else {
        // gene row stats (16 rows of 4096)
        int b = blk - 496;
        const float4* row = (const float4*)(F_gene + (size_t)b * GIN);
        float s1 = 0.f, s2 = 0.f;
        for (int i = t; i < GIN / 4; i += 256) {
            float4 v = row[i];
            s1 += v.x + v.y + v.z + v.w;
            s2 += v.x * v.x + v.y * v.y + v.z * v.z + v.w * v.w;
        }
        __shared__ float sc[8];
        s1 = wsum(s1); s2 = wsum(s2);
        int w = t >> 6;
        if ((t & 63) == 0) { sc[w] = s1; sc[4 + w] = s2; }
        __syncthreads();
        if (t == 0) {
            float S1 = sc[0] + sc[1] + sc[2] + sc[3];
            float S2 = sc[4] + sc[5] + sc[6] + sc[7];
            float m = S1 / GIN;
            float var = S2 / GIN - m * m;
            ws[WS_GMEAN + b] = m;
            ws[WS_GRSTD + b] = rsqrtf(var + EPS);
        }
    }
}

// ============ K1: F_path pass1 — LN stats, score dots, sum of xn ============
__global__ __launch_bounds__(256) void k1_pass1(const float* __restrict__ F_path,
                                                float* __restrict__ ws) {
    __shared__ __align__(16) float qlds[NPE * PIN];  // 16 KB
    __shared__ __align__(16) float comb[4 * PIN];    // 16 KB
    int t = threadIdx.x;
    for (int i = t; i < NPE * PIN; i += 256) qlds[i] = ws[WS_QPROJ + i];
    __syncthreads();
    int blk = blockIdx.x;
    int b = blk >> 6, chunk = blk & 63;
    int w = t >> 6, lane = t & 63;
    const float4* qp4 = (const float4*)qlds;
    float4 sxn[4];
#pragma unroll
    for (int j = 0; j < 4; j++) sxn[j] = make_float4(0.f, 0.f, 0.f, 0.f);
    for (int i = 0; i < 16; i++) {
        int n = chunk * 64 + w * 16 + i;
        const float4* rowp = (const float4*)(F_path + ((size_t)(b * NTOK + n)) * PIN);
        float4 x[4];
#pragma unroll
        for (int j = 0; j < 4; j++) x[j] = rowp[lane + 64 * j];
        float s1 = 0.f, s2 = 0.f;
#pragma unroll
        for (int j = 0; j < 4; j++) {
            s1 += x[j].x + x[j].y + x[j].z + x[j].w;
            s2 += x[j].x * x[j].x + x[j].y * x[j].y + x[j].z * x[j].z + x[j].w * x[j].w;
        }
        s1 = wsum(s1); s2 = wsum(s2);
        float m = s1 * (1.f / PIN);
        float var = s2 * (1.f / PIN) - m * m;
        float r = rsqrtf(var + EPS);
        float sc[NPE];
#pragma unroll
        for (int e = 0; e < NPE; e++) {
            float d = 0.f;
#pragma unroll
            for (int j = 0; j < 4; j++) {
                float4 q = qp4[e * (PIN / 4) + lane + 64 * j];
                d += (x[j].x - m) * q.x + (x[j].y - m) * q.y +
                     (x[j].z - m) * q.z + (x[j].w - m) * q.w;
            }
            sc[e] = wsum(d) * r;
        }
#pragma unroll
        for (int j = 0; j < 4; j++) {
            sxn[j].x += (x[j].x - m) * r;
            sxn[j].y += (x[j].y - m) * r;
            sxn[j].z += (x[j].z - m) * r;
            sxn[j].w += (x[j].w - m) * r;
        }
        if (lane == 0) {
            ws[WS_MEAN + b * NTOK + n] = m;
            ws[WS_RSTD + b * NTOK + n] = r;
#pragma unroll
            for (int e = 0; e < NPE; e++) ws[WS_S + (e * BB + b) * NTOK + n] = sc[e];
        }
    }
    float4* comb4 = (float4*)comb;
#pragma unroll
    for (int j = 0; j < 4; j++) comb4[w * (PIN / 4) + lane + 64 * j] = sxn[j];
    __syncthreads();
    {
        float4 a = comb4[t], bq = comb4[256 + t], c = comb4[512 + t], d = comb4[768 + t];
        atomicAdd(ws + WS_SUMXN + b * PIN + 4 * t + 0, a.x + bq.x + c.x + d.x);
        atomicAdd(ws + WS_SUMXN + b * PIN + 4 * t + 1, a.y + bq.y + c.y + d.y);
        atomicAdd(ws + WS_SUMXN + b * PIN + 4 * t + 2, a.z + bq.z + c.z + d.z);
        atomicAdd(ws + WS_SUMXN + b * PIN + 4 * t + 3, a.w + bq.w + c.w + d.w);
    }
}

// ============ K2: softmax over n for each (e,b) ============
__global__ __launch_bounds__(256) void k2_softmax(float* __restrict__ ws) {
    int row = blockIdx.x;
    float* s = ws + WS_S + (size_t)row * NTOK;
    int t = threadIdx.x, w = t >> 6, lane = t & 63;
    __shared__ float sc[4];
    float4 v[4];
    float mx = -1e30f;
#pragma unroll
    for (int j = 0; j < 4; j++) {
        v[j] = ((float4*)s)[t + j * 256];
        mx = fmaxf(mx, fmaxf(fmaxf(v[j].x, v[j].y), fmaxf(v[j].z, v[j].w)));
    }
    mx = wmax(mx);
    if (lane == 0) sc[w] = mx;
    __syncthreads();
    mx = fmaxf(fmaxf(sc[0], sc[1]), fmaxf(sc[2], sc[3]));
    __syncthreads();
    float sum = 0.f;
#pragma unroll
    for (int j = 0; j < 4; j++) {
        v[j].x = __expf(v[j].x - mx); v[j].y = __expf(v[j].y - mx);
        v[j].z = __expf(v[j].z - mx); v[j].w = __expf(v[j].w - mx);
        sum += v[j].x + v[j].y + v[j].z + v[j].w;
    }
    sum = wsum(sum);
    if (lane == 0) sc[w] = sum;
    __syncthreads();
    float inv = 1.f / (sc[0] + sc[1] + sc[2] + sc[3]);
#pragma unroll
    for (int j = 0; j < 4; j++) {
        v[j].x *= inv; v[j].y *= inv; v[j].z *= inv; v[j].w *= inv;
        ((float4*)s)[t + j * 256] = v[j];
    }
}

// ============ K3: F_path pass2 (z = attn-weighted sum of xn) + gene GEMM ============
// R6: wave-per-DIM-SLICE decomposition. Wave w owns dims [w*256, w*256+256) for
// ALL 4 experts over ALL 64 tokens of the chunk. Each row is read exactly ONCE
// per block (R4/R5's wave-per-expert read every row 4x -> 1GB of L1/L2 traffic;
// now 256MB). Per-lane accumulator = 4 experts x 1 float4 = 16 floats in NAMED
// z0..z3 (static indices only). m/ar staged in LDS; token loop unrolled x4 so
// 4 independent 1KB wave-loads are in flight.
#define K3_ACC_TOK(XK, IDX) do {                                                  \
    float m_ = lds[IDX];                                                          \
    float dx_ = XK.x - m_, dy_ = XK.y - m_, dz_ = XK.z - m_, dw_ = XK.w - m_;     \
    float a0_ = lds[64 + 0 * 64 + (IDX)];                                         \
    float a1_ = lds[64 + 1 * 64 + (IDX)];                                         \
    float a2_ = lds[64 + 2 * 64 + (IDX)];                                         \
    float a3_ = lds[64 + 3 * 64 + (IDX)];                                         \
    z0.x += a0_ * dx_; z0.y += a0_ * dy_; z0.z += a0_ * dz_; z0.w += a0_ * dw_;   \
    z1.x += a1_ * dx_; z1.y += a1_ * dy_; z1.z += a1_ * dz_; z1.w += a1_ * dw_;   \
    z2.x += a2_ * dx_; z2.y += a2_ * dy_; z2.z += a2_ * dz_; z2.w += a2_ * dw_;   \
    z3.x += a3_ * dx_; z3.y += a3_ * dy_; z3.z += a3_ * dz_; z3.w += a3_ * dw_;   \
} while (0)

__global__ __launch_bounds__(256) void k3_pass2(const float* __restrict__ F_path,
                                                const float* __restrict__ F_gene,
                                                const float* __restrict__ gene_W,
                                                const float* __restrict__ gene_ln_g,
                                                const float* __restrict__ gene_ln_b,
                                                float* __restrict__ ws) {
    __shared__ __align__(16) float lds[4096];
    int t = threadIdx.x, blk = blockIdx.x;
    if (blk < 1024) {
        int b = blk >> 6, chunk = blk & 63;
        int w = t >> 6, lane = t & 63;   // w = dim-slice index (4 slices of 256)
        int n0 = chunk * 64;
        // stage m and ar = s*rstd into LDS:
        //   lds[0..63]      = m[i]
        //   lds[64+e*64+i]  = ar[e][i]
        {
            int e = t >> 6, i = t & 63;
            float rv = ws[WS_RSTD + (size_t)b * NTOK + n0 + i];
            lds[64 + e * 64 + i] = ws[WS_S + ((size_t)(e * BB + b)) * NTOK + n0 + i] * rv;
            if (t < 64) lds[t] = ws[WS_MEAN + (size_t)b * NTOK + n0 + t];
        }
        __syncthreads();
        float4 z0 = make_float4(0.f, 0.f, 0.f, 0.f);
        float4 z1 = make_float4(0.f, 0.f, 0.f, 0.f);
        float4 z2 = make_float4(0.f, 0.f, 0.f, 0.f);
        float4 z3 = make_float4(0.f, 0.f, 0.f, 0.f);
        const float4* row4 = (const float4*)(F_path + ((size_t)(b * NTOK + n0)) * PIN);
        int off = w * 64 + lane;        // this wave/lane's float4 within each row
        for (int i = 0; i < 64; i += 4) {
            float4 x0 = row4[(size_t)(i + 0) * 256 + off];
            float4 x1 = row4[(size_t)(i + 1) * 256 + off];
            float4 x2 = row4[(size_t)(i + 2) * 256 + off];
            float4 x3 = row4[(size_t)(i + 3) * 256 + off];
            K3_ACC_TOK(x0, i + 0);
            K3_ACC_TOK(x1, i + 1);
            K3_ACC_TOK(x2, i + 2);
            K3_ACC_TOK(x3, i + 3);
        }
        int k0 = w * 256 + 4 * lane;
        float* zp0 = ws + WS_Z + ((size_t)(0 * BB + b)) * PIN + k0;
        float* zp1 = ws + WS_Z + ((size_t)(1 * BB + b)) * PIN + k0;
        float* zp2 = ws + WS_Z + ((size_t)(2 * BB + b)) * PIN + k0;
        float* zp3 = ws + WS_Z + ((size_t)(3 * BB + b)) * PIN + k0;
        atomicAdd(zp0 + 0, z0.x); atomicAdd(zp0 + 1, z0.y);
        atomicAdd(zp0 + 2, z0.z); atomicAdd(zp0 + 3, z0.w);
        atomicAdd(zp1 + 0, z1.x); atomicAdd(zp1 + 1, z1.y);
        atomicAdd(zp1 + 2, z1.z); atomicAdd(zp1 + 3, z1.w);
        atomicAdd(zp2 + 0, z2.x); atomicAdd(zp2 + 1, z2.y);
        atomicAdd(zp2 + 2, z2.z); atomicAdd(zp2 + 3, z2.w);
        atomicAdd(zp3 + 0, z3.x); atomicAdd(zp3 + 1, z3.y);
        atomicAdd(zp3 + 2, z3.z); atomicAdd(zp3 + 3, z3.w);
    } else {
        // gene projection k-chunk of 256
        int k0 = (blk - 1024) * 256;
        for (int b = 0; b < BB; b++) {
            float x = F_gene[(size_t)b * GIN + k0 + t];
            float m = ws[WS_GMEAN + b], r = ws[WS_GRSTD + b];
            lds[b * 256 + t] = (x - m) * r * gene_ln_g[k0 + t] + gene_ln_b[k0 + t];
        }
        __syncthreads();
        float acc0[BB], acc1[BB];
#pragma unroll
        for (int b = 0; b < BB; b++) { acc0[b] = 0.f; acc1[b] = 0.f; }
        int d0 = t, d1 = t + 256;
#pragma unroll 8
        for (int kk = 0; kk < 256; kk++) {
            float w0 = gene_W[(size_t)(k0 + kk) * DIM + d0];
            float w1 = gene_W[(size_t)(k0 + kk) * DIM + d1];
#pragma unroll
            for (int b = 0; b < BB; b++) {
                float y = lds[b * 256 + kk];
                acc0[b] += y * w0; acc1[b] += y * w1;
            }
        }
#pragma unroll
        for (int b = 0; b < BB; b++) {
            atomicAdd(ws + WS_XG + b * DIM + d0, acc0[b]);
            atomicAdd(ws + WS_XG + b * DIM + d1, acc1[b]);
        }
    }
}

// ============ skinny GEMM: out[M,512] += A[M,1024] @ W[1024,512], k-split ============
// pool=1: A rows from Z/SUMXN with path affine (M=80, grid 80); pool=0: A = tl (M=16, grid 16)
__global__ __launch_bounds__(256) void k_skinny(const float* __restrict__ A,
                                                const float* __restrict__ W,
                                                float* __restrict__ out,
                                                const float* __restrict__ lng,
                                                const float* __restrict__ lnb,
                                                const float* __restrict__ ws,
                                                int pool) {
    __shared__ __align__(16) float a[16 * 64];
    int blk = blockIdx.x, t = threadIdx.x;
    int rg = blk >> 4, kc = blk & 15;
    for (int i = t; i < 1024; i += 256) {
        int r = rg * 16 + (i >> 6);
        int k = kc * 64 + (i & 63);
        float v;
        if (pool) {
            v = (r < 64) ? ws[WS_Z + (size_t)r * PIN + k]
                         : ws[WS_SUMXN + (size_t)(r - 64) * PIN + k] * (1.f / NTOK);
            v = v * lng[k] + lnb[k];
        } else {
            v = A[(size_t)r * PIN + k];
        }
        a[i] = v;
    }
    __syncthreads();
    float2 acc[16];
#pragma unroll
    for (int r = 0; r < 16; r++) acc[r] = make_float2(0.f, 0.f);
    int d2 = 2 * t;
#pragma unroll 4
    for (int k = 0; k < 64; k++) {
        float2 wv = *(const float2*)&W[(size_t)(kc * 64 + k) * DIM + d2];
#pragma unroll
        for (int r = 0; r < 16; r++) {
            float av = a[r * 64 + k];
            acc[r].x += av * wv.x;
            acc[r].y += av * wv.y;
        }
    }
#pragma unroll
    for (int r = 0; r < 16; r++) {
        int rr = rg * 16 + r;
        atomicAdd(out + (size_t)rr * DIM + d2 + 0, acc[r].x);
        atomicAdd(out + (size_t)rr * DIM + d2 + 1, acc[r].y);
    }
}

// ============ K5: row LN + gating + expert-input affine ============
__global__ __launch_bounds__(256) void k5_rows(const float* __restrict__ gene_b,
    const float* __restrict__ path_b,
    const float* __restrict__ gg_ln_g, const float* __restrict__ gg_ln_b,
    const float* __restrict__ gg_W, const float* __restrict__ gg_b,
    const float* __restrict__ pg_ln_g, const float* __restrict__ pg_ln_b,
    const float* __restrict__ pg_W, const float* __restrict__ pg_b,
    const float* __restrict__ g_ln_g, const float* __restrict__ g_ln_b,
    const float* __restrict__ p_ln_g, const float* __restrict__ p_ln_b,
    float* __restrict__ ws) {
    int blk = blockIdx.x, t = threadIdx.x;
    __shared__ float sc[8];
    __shared__ float sc2[16];
    int c0 = t, c1 = t + 256;
    int w = t >> 6, lane = t & 63;
    float v0, v1;
    int type, b = 0, r = 0;
    if (blk < 16) {
        type = 0; b = blk;
        v0 = ws[WS_XG + b * DIM + c0] + gene_b[c0];
        v1 = ws[WS_XG + b * DIM + c1] + gene_b[c1];
    } else if (blk < 32) {
        type = 1; b = blk - 16;
        v0 = ws[WS_XPMEAN + b * DIM + c0] + path_b[c0];
        v1 = ws[WS_XPMEAN + b * DIM + c1] + path_b[c1];
    } else {
        type = 2; r = blk - 32;
        v0 = ws[WS_POOLED + r * DIM + c0] + path_b[c0];
        v1 = ws[WS_POOLED + r * DIM + c1] + path_b[c1];
    }
    float s1 = wsum(v0 + v1), s2 = wsum(v0 * v0 + v1 * v1);
    if (lane == 0) { sc[w] = s1; sc[4 + w] = s2; }
    __syncthreads();
    s1 = sc[0] + sc[1] + sc[2] + sc[3];
    s2 = sc[4] + sc[5] + sc[6] + sc[7];
    float m = s1 / DIM, var = s2 / DIM - m * m, rs = rsqrtf(var + EPS);
    float xn0 = (v0 - m) * rs, xn1 = (v1 - m) * rs;
    if (type == 0) {
#pragma unroll
        for (int e = 0; e < NGE; e++) {
            ws[WS_UG + (e * BB + b) * DIM + c0] = xn0 * g_ln_g[e * DIM + c0] + g_ln_b[e * DIM + c0];
            ws[WS_UG + (e * BB + b) * DIM + c1] = xn1 * g_ln_g[e * DIM + c1] + g_ln_b[e * DIM + c1];
        }
        float t0 = xn0 * gg_ln_g[c0] + gg_ln_b[c0];
        float t1 = xn1 * gg_ln_g[c1] + gg_ln_b[c1];
        float l[4];
#pragma unroll
        for (int e = 0; e < 4; e++) l[e] = wsum(t0 * gg_W[c0 * 4 + e] + t1 * gg_W[c1 * 4 + e]);
        if (lane == 0)
#pragma unroll
            for (int e = 0; e < 4; e++) sc2[w * 4 + e] = l[e];
        __syncthreads();
        if (t == 0) {
            float lg[4], mx = -1e30f;
#pragma unroll
            for (int e = 0; e < 4; e++) {
                lg[e] = sc2[e] + sc2[4 + e] + sc2[8 + e] + sc2[12 + e] + gg_b[e];
                mx = fmaxf(mx, lg[e]);
            }
            float sum = 0.f;
#pragma unroll
            for (int e = 0; e < 4; e++) { lg[e] = __expf(lg[e] - mx); sum += lg[e]; }
#pragma unroll
            for (int e = 0; e < 4; e++) ws[WS_WG + b * NGE + e] = lg[e] / sum;
        }
    } else if (type == 1) {
        float t0 = xn0 * pg_ln_g[c0] + pg_ln_b[c0];
        float t1 = xn1 * pg_ln_g[c1] + pg_ln_b[c1];
        float l[4];
#pragma unroll
        for (int e = 0; e < 4; e++) l[e] = wsum(t0 * pg_W[c0 * 4 + e] + t1 * pg_W[c1 * 4 + e]);
        if (lane == 0)
#pragma unroll
            for (int e = 0; e < 4; e++) sc2[w * 4 + e] = l[e];
        __syncthreads();
        if (t == 0) {
            float lg[4], mx = -1e30f;
#pragma unroll
            for (int e = 0; e < 4; e++) {
                lg[e] = sc2[e] + sc2[4 + e] + sc2[8 + e] + sc2[12 + e] + pg_b[e];
                mx = fmaxf(mx, lg[e]);
            }
            float sum = 0.f;
#pragma unroll
            for (int e = 0; e < 4; e++) { lg[e] = __expf(lg[e] - mx); sum += lg[e]; }
#pragma unroll
            for (int e = 0; e < 4; e++) ws[WS_WP + b * NPE + e] = lg[e] / sum;
        }
    } else {
        int e = r >> 4;
        ws[WS_UP + r * DIM + c0] = xn0 * p_ln_g[e * DIM + c0] + p_ln_b[e * DIM + c0];
        ws[WS_UP + r * DIM + c1] = xn1 * p_ln_g[e * DIM + c1] + p_ln_b[e * DIM + c1];
    }
}

// ============ MLP layer1 pre-act: Hacc[e,b,h] += sum_k U[e,b,k] W1[e,k,h] ============
// per set: e x ht(4, 512h) x kc(8, 64k). thread owns 2 h (float2).
__global__ __launch_bounds__(256) void k_mlp1(const float* __restrict__ U0, const float* __restrict__ W10,
                                              float* __restrict__ H0,
                                              const float* __restrict__ U1, const float* __restrict__ W11,
                                              float* __restrict__ H1,
                                              int halfBlk) {
    __shared__ float a[16 * 64];
    int blk = blockIdx.x, t = threadIdx.x;
    const float* U; const float* W1; float* H;
    int lb;
    if (blk < halfBlk) { U = U0; W1 = W10; H = H0; lb = blk; }
    else               { U = U1; W1 = W11; H = H1; lb = blk - halfBlk; }
    int e = lb >> 5, ht = (lb >> 3) & 3, kc = lb & 7;
    const float* Ue = U + (size_t)e * BB * DIM;
    for (int i = t; i < 1024; i += 256) {
        int b = i >> 6, kk = i & 63;
        a[i] = Ue[b * DIM + kc * 64 + kk];
    }
    __syncthreads();
    float2 acc[BB];
#pragma unroll
    for (int b = 0; b < BB; b++) acc[b] = make_float2(0.f, 0.f);
    int h2 = ht * 512 + 2 * t;
#pragma unroll 4
    for (int kk = 0; kk < 64; kk++) {
        float2 wv = *(const float2*)&W1[((size_t)e * DIM + kc * 64 + kk) * HID + h2];
#pragma unroll
        for (int b = 0; b < BB; b++) {
            float av = a[b * 64 + kk];
            acc[b].x += av * wv.x;
            acc[b].y += av * wv.y;
        }
    }
#pragma unroll
    for (int b = 0; b < BB; b++) {
        atomicAdd(H + (size_t)(e * BB + b) * HID + h2 + 0, acc[b].x);
        atomicAdd(H + (size_t)(e * BB + b) * HID + h2 + 1, acc[b].y);
    }
}

// ============ GELU+bias in place: H = gelu(H + b1) ============
__global__ __launch_bounds__(256) void k_gelu(float* __restrict__ H,
                                              const float* __restrict__ b1a,
                                              const float* __restrict__ b1b,
                                              int eSplit) {
    int idx4 = (blockIdx.x * 256 + threadIdx.x) * 4;
    int e = idx4 >> 15;           // per-e block is 16*2048 = 32768
    int h = idx4 & (HID - 1);
    const float* bp = (e < eSplit) ? (b1a + (size_t)e * HID) : (b1b + (size_t)(e - eSplit) * HID);
    float4 v = *(float4*)&H[idx4];
    float4 bv = *(const float4*)&bp[h];
    v.x = gelu_exact(v.x + bv.x);
    v.y = gelu_exact(v.y + bv.y);
    v.z = gelu_exact(v.z + bv.z);
    v.w = gelu_exact(v.w + bv.w);
    *(float4*)&H[idx4] = v;
}

// ============ MLP layer2 + gate-weighted accumulate (bias b2 folded downstream) ============
// per set: e x kc(16, 128k). thread owns 2 d (float2).
__global__ __launch_bounds__(256) void k_mlp2(const float* __restrict__ H0, const float* __restrict__ W20,
                                              const float* __restrict__ gate0, int ng0, float* __restrict__ out0,
                                              const float* __restrict__ H1, const float* __restrict__ W21,
                                              const float* __restrict__ gate1, int ng1, float* __restrict__ out1,
                                              int halfBlk) {
    __shared__ float a[16 * 128];
    int blk = blockIdx.x, t = threadIdx.x;
    const float* H; const float* W2; const float* gate; float* outp;
    int ng, lb;
    if (blk < halfBlk) { H = H0; W2 = W20; gate = gate0; ng = ng0; outp = out0; lb = blk; }
    else               { H = H1; W2 = W21; gate = gate1; ng = ng1; outp = out1; lb = blk - halfBlk; }
    int e = lb >> 4, kc = lb & 15;
    for (int i = t; i < 2048; i += 256) {
        int b = i >> 7, kk = i & 127;
        a[i] = H[(size_t)(e * BB + b) * HID + kc * 128 + kk];
    }
    __syncthreads();
    float2 acc[BB];
#pragma unroll
    for (int b = 0; b < BB; b++) acc[b] = make_float2(0.f, 0.f);
    int d2 = 2 * t;
#pragma unroll 4
    for (int kk = 0; kk < 128; kk++) {
        float2 wv = *(const float2*)&W2[((size_t)e * HID + kc * 128 + kk) * DIM + d2];
#pragma unroll
        for (int b = 0; b < BB; b++) {
            float av = a[b * 128 + kk];
            acc[b].x += av * wv.x;
            acc[b].y += av * wv.y;
        }
    }
#pragma unroll
    for (int b = 0; b < BB; b++) {
        float g = gate[b * ng + e];
        atomicAdd(outp + (size_t)b * DIM + d2 + 0, g * acc[b].x);
        atomicAdd(outp + (size_t)b * DIM + d2 + 1, g * acc[b].y);
    }
}

// ============ K8a: fused = [FG+bias | FP+bias]; LN; wf gates; tl = affine(fin_ln) ============
__global__ __launch_bounds__(256) void k8a(const float* __restrict__ fg_ln_g, const float* __restrict__ fg_ln_b,
                                           const float* __restrict__ fg_W, const float* __restrict__ fg_b,
                                           const float* __restrict__ fin_ln_g, const float* __restrict__ fin_ln_b,
                                           const float* __restrict__ g_b2, const float* __restrict__ p_b2,
                                           float* __restrict__ ws) {
    __shared__ float sc[8];
    __shared__ float sc2[8];
    int b = blockIdx.x, t = threadIdx.x;
    int w = t >> 6, lane = t & 63;
    float wg[4], wp[4];
#pragma unroll
    for (int e = 0; e < 4; e++) { wg[e] = ws[WS_WG + b * 4 + e]; wp[e] = ws[WS_WP + b * 4 + e]; }
    float v[4];
    v[0] = ws[WS_FG + b * DIM + t]
         + wg[0] * g_b2[t] + wg[1] * g_b2[DIM + t] + wg[2] * g_b2[2 * DIM + t] + wg[3] * g_b2[3 * DIM + t];
    v[1] = ws[WS_FG + b * DIM + t + 256]
         + wg[0] * g_b2[t + 256] + wg[1] * g_b2[DIM + t + 256] + wg[2] * g_b2[2 * DIM + t + 256] + wg[3] * g_b2[3 * DIM + t + 256];
    v[2] = ws[WS_FP + b * DIM + t]
         + wp[0] * p_b2[t] + wp[1] * p_b2[DIM + t] + wp[2] * p_b2[2 * DIM + t] + wp[3] * p_b2[3 * DIM + t];
    v[3] = ws[WS_FP + b * DIM + t + 256]
         + wp[0] * p_b2[t + 256] + wp[1] * p_b2[DIM + t + 256] + wp[2] * p_b2[2 * DIM + t + 256] + wp[3] * p_b2[3 * DIM + t + 256];
    float s1 = wsum(v[0] + v[1] + v[2] + v[3]);
    float s2 = wsum(v[0] * v[0] + v[1] * v[1] + v[2] * v[2] + v[3] * v[3]);
    if (lane == 0) { sc[w] = s1; sc[4 + w] = s2; }
    __syncthreads();
    s1 = sc[0] + sc[1] + sc[2] + sc[3];
    s2 = sc[4] + sc[5] + sc[6] + sc[7];
    float m = s1 / (2 * DIM), var = s2 / (2 * DIM) - m * m, rs = rsqrtf(var + EPS);
    float l0 = 0.f, l1 = 0.f;
    int cols[4] = {t, t + 256, t + 512, t + 768};
#pragma unroll
    for (int j = 0; j < 4; j++) {
        int c = cols[j];
        float xn = (v[j] - m) * rs;
        float tf = xn * fg_ln_g[c] + fg_ln_b[c];
        l0 += tf * fg_W[c * 2 + 0];
        l1 += tf * fg_W[c * 2 + 1];
        ws[WS_TL + b * 1024 + c] = xn * fin_ln_g[c] + fin_ln_b[c];
    }
    l0 = wsum(l0); l1 = wsum(l1);
    if (lane == 0) { sc2[w] = l0; sc2[4 + w] = l1; }
    __syncthreads();
    if (t == 0) {
        float L0 = sc2[0] + sc2[1] + sc2[2] + sc2[3] + fg_b[0];
        float L1 = sc2[4] + sc2[5] + sc2[6] + sc2[7] + fg_b[1];
        float mx = fmaxf(L0, L1);
        float p0 = __expf(L0 - mx), p1 = __expf(L1 - mx);
        float inv = 1.f / (p0 + p1);
        ws[WS_WF + b * NFE + 0] = p0 * inv;
        ws[WS_WF + b * NFE + 1] = p1 * inv;
    }
}

// ============ K8b: LN(FIN + fin_b) -> UF (f-expert affine) ============
__global__ __launch_bounds__(256) void k8b(const float* __restrict__ fin_b,
                                           const float* __restrict__ f_ln_g, const float* __restrict__ f_ln_b,
                                           float* __restrict__ ws) {
    __shared__ float sc[8];
    int b = blockIdx.x, t = threadIdx.x;
    int w = t >> 6, lane = t & 63;
    int c0 = t, c1 = t + 256;
    float a0 = ws[WS_FIN + b * DIM + c0] + fin_b[c0];
    float a1 = ws[WS_FIN + b * DIM + c1] + fin_b[c1];
    float s1 = wsum(a0 + a1), s2 = wsum(a0 * a0 + a1 * a1);
    if (lane == 0) { sc[w] = s1; sc[4 + w] = s2; }
    __syncthreads();
    s1 = sc[0] + sc[1] + sc[2] + sc[3];
    s2 = sc[4] + sc[5] + sc[6] + sc[7];
    float m = s1 / DIM, var = s2 / DIM - m * m, rs = rsqrtf(var + EPS);
    float x0 = (a0 - m) * rs, x1 = (a1 - m) * rs;
#pragma unroll
    for (int e = 0; e < NFE; e++) {
        ws[WS_UF + (e * BB + b) * DIM + c0] = x0 * f_ln_g[e * DIM + c0] + f_ln_b[e * DIM + c0];
        ws[WS_UF + (e * BB + b) * DIM + c1] = x1 * f_ln_g[e * DIM + c1] + f_ln_b[e * DIM + c1];
    }
}

// ============ K11: classifier (+gate-weighted f_b2 bias) + sigmoid + cumprod ============
__global__ __launch_bounds__(256) void k11_out(const float* __restrict__ cls_W, const float* __restrict__ cls_b,
                                               const float* __restrict__ f_b2,
                                               const float* __restrict__ ws, float* __restrict__ out) {
    __shared__ float4 red[256];
    __shared__ float hz[64];
    int t = threadIdx.x;
    int b = t >> 4, g = t & 15;
    float wf0 = ws[WS_WF + b * 2 + 0], wf1 = ws[WS_WF + b * 2 + 1];
    float4 acc = make_float4(0.f, 0.f, 0.f, 0.f);
#pragma unroll 8
    for (int k = g; k < DIM; k += 16) {
        float x = ws[WS_FIMMF + b * DIM + k] + wf0 * f_b2[k] + wf1 * f_b2[DIM + k];
        float4 wv = *(const float4*)&cls_W[k * 4];
        acc.x += x * wv.x; acc.y += x * wv.y; acc.z += x * wv.z; acc.w += x * wv.w;
    }
    red[t] = acc;
    __syncthreads();
    if (t < 64) {
        int bb = t >> 2, c = t & 3;
        float s = cls_b[c];
#pragma unroll
        for (int j = 0; j < 16; j++) s += ((const float*)&red[bb * 16 + j])[c];
        hz[t] = 1.f / (1.f + __expf(-s));
    }
    __syncthreads();
    if (t < 64) {
        int bb = t >> 2, c = t & 3;
        float S = 1.f;
        for (int j = 0; j <= c; j++) S *= (1.f - hz[bb * 4 + j]);
        out[t] = hz[t];
        out[64 + t] = S;
    }
}

extern "C" void kernel_launch(void* const* d_in, const int* in_sizes, int n_in,
                              void* d_out, int out_size, void* d_ws, size_t ws_size,
                              hipStream_t stream) {
    (void)in_sizes; (void)n_in; (void)out_size; (void)ws_size;
    const float* F_gene    = (const float*)d_in[0];
    const float* F_path    = (const float*)d_in[1];
    const float* gene_ln_g = (const float*)d_in[2];
    const float* gene_ln_b = (const float*)d_in[3];
    const float* gene_W    = (const float*)d_in[4];
    const float* gene_b    = (const float*)d_in[5];
    const float* path_ln_g = (const float*)d_in[6];
    const float* path_ln_b = (const float*)d_in[7];
    const float* path_W    = (const float*)d_in[8];
    const float* path_b    = (const float*)d_in[9];
    const float* g_ln_g    = (const float*)d_in[10];
    const float* g_ln_b    = (const float*)d_in[11];
    const float* g_W1      = (const float*)d_in[12];
    const float* g_b1      = (const float*)d_in[13];
    const float* g_W2      = (const float*)d_in[14];
    const float* g_b2      = (const float*)d_in[15];
    const float* p_q       = (const float*)d_in[16];
    const float* p_ln_g    = (const float*)d_in[17];
    const float* p_ln_b    = (const float*)d_in[18];
    const float* p_W1      = (const float*)d_in[19];
    const float* p_b1      = (const float*)d_in[20];
    const float* p_W2      = (const float*)d_in[21];
    const float* p_b2      = (const float*)d_in[22];
    const float* f_ln_g    = (const float*)d_in[23];
    const float* f_ln_b    = (const float*)d_in[24];
    const float* f_W1      = (const float*)d_in[25];
    const float* f_b1      = (const float*)d_in[26];
    const float* f_W2      = (const float*)d_in[27];
    const float* f_b2      = (const float*)d_in[28];
    const float* gg_ln_g   = (const float*)d_in[29];
    const float* gg_ln_b   = (const float*)d_in[30];
    const float* gg_W      = (const float*)d_in[31];
    const float* gg_b      = (const float*)d_in[32];
    const float* pg_ln_g   = (const float*)d_in[33];
    const float* pg_ln_b   = (const float*)d_in[34];
    const float* pg_W      = (const float*)d_in[35];
    const float* pg_b      = (const float*)d_in[36];
    const float* fg_ln_g   = (const float*)d_in[37];
    const float* fg_ln_b   = (const float*)d_in[38];
    const float* fg_W      = (const float*)d_in[39];
    const float* fg_b      = (const float*)d_in[40];
    const float* fin_ln_g  = (const float*)d_in[41];
    const float* fin_ln_b  = (const float*)d_in[42];
    const float* fin_W     = (const float*)d_in[43];
    const float* fin_b     = (const float*)d_in[44];
    const float* cls_W     = (const float*)d_in[45];
    const float* cls_b     = (const float*)d_in[46];
    float* ws  = (float*)d_ws;
    float* out = (float*)d_out;

    k0_init<<<512, 256, 0, stream>>>(F_gene, path_W, p_q, path_ln_g, ws);
    k1_pass1<<<1024, 256, 0, stream>>>(F_path, ws);
    k2_softmax<<<64, 256, 0, stream>>>(ws);
    k3_pass2<<<1040, 256, 0, stream>>>(F_path, F_gene, gene_W, gene_ln_g, gene_ln_b, ws);
    k_skinny<<<80, 256, 0, stream>>>(nullptr, path_W, ws + WS_POOLED, path_ln_g, path_ln_b, ws, 1);
    k5_rows<<<96, 256, 0, stream>>>(gene_b, path_b, gg_ln_g, gg_ln_b, gg_W, gg_b,
                                    pg_ln_g, pg_ln_b, pg_W, pg_b,
                                    g_ln_g, g_ln_b, p_ln_g, p_ln_b, ws);
    k_mlp1<<<256, 256, 0, stream>>>(ws + WS_UG, g_W1, ws + WS_HG,
                                    ws + WS_UP, p_W1, ws + WS_HP, 128);
    k_gelu<<<256, 256, 0, stream>>>(ws + WS_HG, g_b1, p_b1, 4);
    k_mlp2<<<128, 256, 0, stream>>>(ws + WS_HG, g_W2, ws + WS_WG, NGE, ws + WS_FG,
                                    ws + WS_HP, p_W2, ws + WS_WP, NPE, ws + WS_FP, 64);
    k8a<<<16, 256, 0, stream>>>(fg_ln_g, fg_ln_b, fg_W, fg_b, fin_ln_g, fin_ln_b, g_b2, p_b2, ws);
    k_skinny<<<16, 256, 0, stream>>>(ws + WS_TL, fin_W, ws + WS_FIN, nullptr, nullptr, ws, 0);
    k8b<<<16, 256, 0, stream>>>(fin_b, f_ln_g, f_ln_b, ws);
    k_mlp1<<<64, 256, 0, stream>>>(ws + WS_UF, f_W1, ws + WS_HF,
                                   ws + WS_UF, f_W1, ws + WS_HF, 64);
    k_gelu<<<64, 256, 0, stream>>>(ws + WS_HF, f_b1, f_b1, 2);
    k_mlp2<<<32, 256, 0, stream>>>(ws + WS_HF, f_W2, ws + WS_WF, NFE, ws + WS_FIMMF,
                                   ws + WS_HF, f_W2, ws + WS_WF, NFE, ws + WS_FIMMF, 32);
    k11_out<<<1, 256, 0, stream>>>(cls_W, cls_b, f_b2, ws, out);
}